// Round 1
// baseline (1618.412 us; speedup 1.0000x reference)
//
#include <hip/hip_runtime.h>
#include <hip/hip_bf16.h>
#include <math.h>

#define EMBED 512
#define HEADS 8
#define HD    64
#define FFN_  2048
#define NB    4
#define LSEQ  2048
#define MROWS (NB*LSEQ)    // 8192
#define BHN   (NB*HEADS)   // 32

__device__ __forceinline__ float gelu_f(float v) {
    return 0.5f * v * (1.0f + erff(v * 0.70710678118654752f));
}

// C[M,N] = A[M,K] @ W[K,N] + bias, with fused epilogues.
// MODE 0: scatter qkv into head-major q/k/v buffers (out = q base, 3x 4194304 floats)
// MODE 1: += res (x), write
// MODE 2: gelu, write
// MODE 3: += res (xln), write
template<int MODE>
__global__ __launch_bounds__(256) void gemm_f32(
    const float* __restrict__ A, const float* __restrict__ W,
    const float* __restrict__ bias, const float* __restrict__ res,
    float* __restrict__ out, int M, int N, int K)
{
    __shared__ float As[16][68];   // transposed: As[k][m]
    __shared__ float Bs[16][68];   // Bs[k][n]
    const int t = threadIdx.x;
    const int tx = t & 15, ty = t >> 4;
    const int m0 = blockIdx.y * 64, n0 = blockIdx.x * 64;

    float acc[4][4] = {};

    for (int k0 = 0; k0 < K; k0 += 16) {
        {
            const int r = t >> 2, kk = (t & 3) * 4;
            const float4 av = *reinterpret_cast<const float4*>(&A[(size_t)(m0 + r) * K + k0 + kk]);
            As[kk + 0][r] = av.x; As[kk + 1][r] = av.y; As[kk + 2][r] = av.z; As[kk + 3][r] = av.w;
            const int rk = t >> 4, nn = (t & 15) * 4;
            *reinterpret_cast<float4*>(&Bs[rk][nn]) =
                *reinterpret_cast<const float4*>(&W[(size_t)(k0 + rk) * N + n0 + nn]);
        }
        __syncthreads();
        #pragma unroll
        for (int kk = 0; kk < 16; ++kk) {
            float4 a = *reinterpret_cast<const float4*>(&As[kk][ty * 4]);
            float4 b = *reinterpret_cast<const float4*>(&Bs[kk][tx * 4]);
            float av[4] = {a.x, a.y, a.z, a.w};
            float bv[4] = {b.x, b.y, b.z, b.w};
            #pragma unroll
            for (int i = 0; i < 4; ++i)
                #pragma unroll
                for (int j = 0; j < 4; ++j)
                    acc[i][j] += av[i] * bv[j];
        }
        __syncthreads();
    }

    #pragma unroll
    for (int i = 0; i < 4; ++i) {
        const int m = m0 + ty * 4 + i;
        const int n = n0 + tx * 4;
        float4 bv = *reinterpret_cast<const float4*>(&bias[n]);
        float4 vv = make_float4(acc[i][0] + bv.x, acc[i][1] + bv.y,
                                acc[i][2] + bv.z, acc[i][3] + bv.w);
        if (MODE == 0) {
            const int which = n >> 9, nn = n & 511, hs = nn >> 6, d = nn & 63;
            const int bb = m >> 11, l = m & 2047;
            size_t dst = (size_t)which * 4194304u +
                         (((size_t)(bb * 8 + hs) * LSEQ + l) * HD + d);
            *reinterpret_cast<float4*>(&out[dst]) = vv;
        } else if (MODE == 1 || MODE == 3) {
            size_t idx = (size_t)m * N + n;
            float4 rv = *reinterpret_cast<const float4*>(&res[idx]);
            vv.x += rv.x; vv.y += rv.y; vv.z += rv.z; vv.w += rv.w;
            *reinterpret_cast<float4*>(&out[idx]) = vv;
        } else {
            size_t idx = (size_t)m * N + n;
            vv.x = gelu_f(vv.x); vv.y = gelu_f(vv.y);
            vv.z = gelu_f(vv.z); vv.w = gelu_f(vv.w);
            *reinterpret_cast<float4*>(&out[idx]) = vv;
        }
    }
}

// Flash-style local-window attention.
// grid (BHN, LSEQ/64), block 256.  Q/K/V head-major [BHN][LSEQ][HD].
// Writes merged layout out[(b*LSEQ + l)*EMBED + h*HD + d].
__global__ __launch_bounds__(256) void attn_kernel(
    const float* __restrict__ Q, const float* __restrict__ K,
    const float* __restrict__ V, const int* __restrict__ mask,
    float* __restrict__ out)
{
    __shared__ float Qs[64][68];
    __shared__ float Ks[32][68];
    __shared__ float Vs[32][68];
    __shared__ float Ps[64][36];
    __shared__ float fac[64];
    __shared__ float kbias[32];

    const int bh = blockIdx.x;
    const int qt = blockIdx.y;
    const int b = bh >> 3, hd = bh & 7;
    const int t = threadIdx.x;
    const int qr0 = qt * 64;
    const int c = qr0 >> 9;                       // chunk index (S=512)
    const int ks = max(0, (c - 1) * 512);
    const int ke = min(LSEQ, (c + 2) * 512);

    const float scale = 0.125f;                   // 1/sqrt(64)
    #pragma unroll
    for (int u = 0; u < 4; ++u) {
        int idx = t + u * 256;                    // 0..1023 -> 64 rows x 16 float4
        int r = idx >> 4, c4 = (idx & 15) * 4;
        float4 qv = *reinterpret_cast<const float4*>(
            &Q[((size_t)bh * LSEQ + qr0 + r) * HD + c4]);
        qv.x *= scale; qv.y *= scale; qv.z *= scale; qv.w *= scale;
        *reinterpret_cast<float4*>(&Qs[r][c4]) = qv;
    }

    const int tx = t & 7, ty = t >> 3;            // score mapping: rows 2*ty+i, keys tx*4+j
    float m_r[2] = {-INFINITY, -INFINITY};
    float l_r[2] = {0.f, 0.f};
    const int pr = t >> 2, pd = (t & 3) * 16;     // PV mapping: row pr, d-slice [pd,pd+16)
    float acc[16] = {};

    const int nkb = (ke - ks) >> 5;
    for (int kb = 0; kb < nkb; ++kb) {
        const int kg0 = ks + kb * 32;
        __syncthreads();                           // prior PV done with Ks/Vs/Ps
        #pragma unroll
        for (int u = 0; u < 2; ++u) {
            int idx = t + u * 256;                 // 0..511 -> 32 rows x 16 float4
            int r = idx >> 4, c4 = (idx & 15) * 4;
            *reinterpret_cast<float4*>(&Ks[r][c4]) = *reinterpret_cast<const float4*>(
                &K[((size_t)bh * LSEQ + kg0 + r) * HD + c4]);
            *reinterpret_cast<float4*>(&Vs[r][c4]) = *reinterpret_cast<const float4*>(
                &V[((size_t)bh * LSEQ + kg0 + r) * HD + c4]);
        }
        if (t < 32) kbias[t] = mask[b * LSEQ + kg0 + t] ? -1e30f : 0.0f;
        __syncthreads();

        // scores: 2 q-rows x 4 keys per thread
        float s[2][4];
        #pragma unroll
        for (int i = 0; i < 2; ++i)
            #pragma unroll
            for (int j = 0; j < 4; ++j) s[i][j] = kbias[tx * 4 + j];
        for (int d = 0; d < HD; d += 4) {
            float4 q0 = *reinterpret_cast<const float4*>(&Qs[ty * 2 + 0][d]);
            float4 q1 = *reinterpret_cast<const float4*>(&Qs[ty * 2 + 1][d]);
            #pragma unroll
            for (int j = 0; j < 4; ++j) {
                float4 kv = *reinterpret_cast<const float4*>(&Ks[tx * 4 + j][d]);
                s[0][j] += q0.x * kv.x + q0.y * kv.y + q0.z * kv.z + q0.w * kv.w;
                s[1][j] += q1.x * kv.x + q1.y * kv.y + q1.z * kv.z + q1.w * kv.w;
            }
        }
        // online softmax per row (8 lanes per row)
        #pragma unroll
        for (int i = 0; i < 2; ++i) {
            float mx = fmaxf(fmaxf(s[i][0], s[i][1]), fmaxf(s[i][2], s[i][3]));
            mx = fmaxf(mx, __shfl_xor(mx, 1, 8));
            mx = fmaxf(mx, __shfl_xor(mx, 2, 8));
            mx = fmaxf(mx, __shfl_xor(mx, 4, 8));
            float nm = fmaxf(m_r[i], mx);
            float f  = __expf(m_r[i] - nm);
            float p[4], sum = 0.f;
            #pragma unroll
            for (int j = 0; j < 4; ++j) { p[j] = __expf(s[i][j] - nm); sum += p[j]; }
            *reinterpret_cast<float4*>(&Ps[ty * 2 + i][tx * 4]) =
                make_float4(p[0], p[1], p[2], p[3]);
            sum += __shfl_xor(sum, 1, 8);
            sum += __shfl_xor(sum, 2, 8);
            sum += __shfl_xor(sum, 4, 8);
            l_r[i] = l_r[i] * f + sum;
            m_r[i] = nm;
            if (tx == 0) fac[ty * 2 + i] = f;
        }
        __syncthreads();

        // PV: acc = acc*f + P @ V
        float f = fac[pr];
        #pragma unroll
        for (int dd = 0; dd < 16; ++dd) acc[dd] *= f;
        for (int k2 = 0; k2 < 32; ++k2) {
            float p = Ps[pr][k2];
            #pragma unroll
            for (int dd = 0; dd < 16; dd += 4) {
                float4 vv = *reinterpret_cast<const float4*>(&Vs[k2][pd + dd]);
                acc[dd + 0] += p * vv.x; acc[dd + 1] += p * vv.y;
                acc[dd + 2] += p * vv.z; acc[dd + 3] += p * vv.w;
            }
        }
    }
    __syncthreads();
    if (tx == 0) { fac[ty * 2] = 1.0f / l_r[0]; fac[ty * 2 + 1] = 1.0f / l_r[1]; }
    __syncthreads();
    const float linv = fac[pr];
    size_t base = ((size_t)(b * LSEQ + qr0 + pr)) * EMBED + hd * HD + pd;
    #pragma unroll
    for (int dd = 0; dd < 16; dd += 4) {
        float4 o = make_float4(acc[dd] * linv, acc[dd + 1] * linv,
                               acc[dd + 2] * linv, acc[dd + 3] * linv);
        *reinterpret_cast<float4*>(&out[base + dd]) = o;
    }
}

// Row layernorm over EMBED=512.  grid = MROWS, block = 256.
__global__ __launch_bounds__(256) void ln_kernel(
    const float* __restrict__ in, const float* __restrict__ g,
    const float* __restrict__ bt, float* __restrict__ out)
{
    const int row = blockIdx.x;
    const int t = threadIdx.x;
    const float* x = in + (size_t)row * EMBED;
    float2 v = *reinterpret_cast<const float2*>(&x[t * 2]);
    float s = v.x + v.y, ss = v.x * v.x + v.y * v.y;
    #pragma unroll
    for (int off = 1; off < 64; off <<= 1) {
        s  += __shfl_xor(s, off);
        ss += __shfl_xor(ss, off);
    }
    __shared__ float red[8];
    const int w = t >> 6;
    if ((t & 63) == 0) { red[w * 2] = s; red[w * 2 + 1] = ss; }
    __syncthreads();
    s  = red[0] + red[2] + red[4] + red[6];
    ss = red[1] + red[3] + red[5] + red[7];
    const float mu = s * (1.0f / EMBED);
    const float var = ss * (1.0f / EMBED) - mu * mu;
    const float rs = rsqrtf(var + 1e-5f);
    float2 gg = *reinterpret_cast<const float2*>(&g[t * 2]);
    float2 bb = *reinterpret_cast<const float2*>(&bt[t * 2]);
    float2 o;
    o.x = (v.x - mu) * rs * gg.x + bb.x;
    o.y = (v.y - mu) * rs * gg.y + bb.y;
    *reinterpret_cast<float2*>(&out[(size_t)row * EMBED + t * 2]) = o;
}

extern "C" void kernel_launch(void* const* d_in, const int* in_sizes, int n_in,
                              void* d_out, int out_size, void* d_ws, size_t ws_size,
                              hipStream_t stream) {
    const float* x      = (const float*)d_in[0];
    const int*   mask   = (const int*)  d_in[1];
    const float* qkv_w  = (const float*)d_in[2];
    const float* qkv_b  = (const float*)d_in[3];
    const float* out_w  = (const float*)d_in[4];
    const float* out_b  = (const float*)d_in[5];
    const float* ffn_w1 = (const float*)d_in[6];
    const float* ffn_b1 = (const float*)d_in[7];
    const float* ffn_w2 = (const float*)d_in[8];
    const float* ffn_b2 = (const float*)d_in[9];
    const float* ln1_g  = (const float*)d_in[10];
    const float* ln1_b  = (const float*)d_in[11];
    const float* ln2_g  = (const float*)d_in[12];
    const float* ln2_b  = (const float*)d_in[13];

    float* ws = (float*)d_ws;
    const size_t SEG = 4194304;        // 16 MB / 4M floats per [8192,512] buffer
    float* q   = ws;                   // [0, SEG)
    float* k   = ws + SEG;             // [SEG, 2SEG)
    float* v   = ws + 2 * SEG;         // [2SEG, 3SEG)
    float* am  = ws + 3 * SEG;         // [3SEG, 4SEG)  attention merged
    float* h   = ws + 2 * SEG;         // [2SEG, 6SEG)  FFN hidden (reuses v & am, both dead)
    float* y   = v;                    // post-attn residual sum (v dead after attn)... careful: see order
    float* xln = k;                    // post-LN1 (k dead after attn)
    float* z   = q;                    // FFN2 output (q dead after attn)

    // 1) QKV projection, scattered to head-major q/k/v
    gemm_f32<0><<<dim3(1536 / 64, MROWS / 64), 256, 0, stream>>>(
        x, qkv_w, qkv_b, nullptr, q, MROWS, 3 * EMBED, EMBED);
    // 2) chunked local attention
    attn_kernel<<<dim3(BHN, LSEQ / 64), 256, 0, stream>>>(q, k, v, mask, am);
    // 3) out projection + residual (reads am + x, writes y=v region; am untouched)
    gemm_f32<1><<<dim3(EMBED / 64, MROWS / 64), 256, 0, stream>>>(
        am, out_w, out_b, x, y, MROWS, EMBED, EMBED);
    // 4) LN1 -> xln (k region)
    ln_kernel<<<MROWS, 256, 0, stream>>>(y, ln1_g, ln1_b, xln);
    // 5) FFN1 + gelu -> h (overwrites v/am regions; y dead now)
    gemm_f32<2><<<dim3(FFN_ / 64, MROWS / 64), 256, 0, stream>>>(
        xln, ffn_w1, ffn_b1, nullptr, h, MROWS, FFN_, EMBED);
    // 6) FFN2 + residual(xln) -> z (q region)
    gemm_f32<3><<<dim3(EMBED / 64, MROWS / 64), 256, 0, stream>>>(
        h, ffn_w2, ffn_b2, xln, z, MROWS, EMBED, FFN_);
    // 7) LN2 -> d_out
    ln_kernel<<<MROWS, 256, 0, stream>>>(z, ln2_g, ln2_b, (float*)d_out);
}

// Round 2
// 324.213 us; speedup vs baseline: 4.9918x; 4.9918x over previous
//
#include <hip/hip_runtime.h>
#include <hip/hip_bf16.h>
#include <math.h>

#define EMBED 512
#define HEADS 8
#define HD    64
#define FFN_  2048
#define NB    4
#define LSEQ  2048
#define MROWS (NB*LSEQ)    // 8192
#define BHN   (NB*HEADS)   // 32

typedef __attribute__((ext_vector_type(8))) short bf16x8;
typedef __attribute__((ext_vector_type(4))) float f32x4;
#define MFMA16(a,b,c) __builtin_amdgcn_mfma_f32_16x16x32_bf16(a,b,c,0,0,0)

__device__ __forceinline__ unsigned short f2bf(float f) {
    unsigned int u = __float_as_uint(f);
    u += 0x7fff + ((u >> 16) & 1);          // round-to-nearest-even
    return (unsigned short)(u >> 16);
}
__device__ __forceinline__ float gelu_f(float v) {
    return 0.5f * v * (1.0f + erff(v * 0.70710678118654752f));
}

// ---------------- prep kernels ----------------

// fp32 -> bf16, n multiple of 8
__global__ __launch_bounds__(256) void cvt_bf16(const float* __restrict__ in,
                                                unsigned short* __restrict__ out, int n) {
    int i = (blockIdx.x * 256 + threadIdx.x) * 8;
    if (i >= n) return;
    float4 a = *reinterpret_cast<const float4*>(&in[i]);
    float4 b = *reinterpret_cast<const float4*>(&in[i + 4]);
    unsigned short t[8] = {f2bf(a.x), f2bf(a.y), f2bf(a.z), f2bf(a.w),
                           f2bf(b.x), f2bf(b.y), f2bf(b.z), f2bf(b.w)};
    *reinterpret_cast<uint4*>(&out[i]) = *reinterpret_cast<uint4*>(t);
}

// fp32 W[K][N] -> bf16 WT[N][K].  grid (N/32, K/32), block 256.
__global__ __launch_bounds__(256) void wtrans(const float* __restrict__ in,
                                              unsigned short* __restrict__ out,
                                              int K, int N) {
    __shared__ float tile[32][33];
    const int k0 = blockIdx.y * 32, n0 = blockIdx.x * 32;
    const int t = threadIdx.x;
    const int r = t >> 3, c = (t & 7) * 4;
    float4 v = *reinterpret_cast<const float4*>(&in[(size_t)(k0 + r) * N + n0 + c]);
    tile[r][c] = v.x; tile[r][c + 1] = v.y; tile[r][c + 2] = v.z; tile[r][c + 3] = v.w;
    __syncthreads();
    unsigned short tmp[4] = {f2bf(tile[c + 0][r]), f2bf(tile[c + 1][r]),
                             f2bf(tile[c + 2][r]), f2bf(tile[c + 3][r])};
    *reinterpret_cast<uint2*>(&out[(size_t)(n0 + r) * K + k0 + c]) =
        *reinterpret_cast<uint2*>(tmp);
}

// v bf16 [BH][L][HD] -> vT bf16 [BH][HD][L].  grid (L/64, BH), block 256.
__global__ __launch_bounds__(256) void vtrans(const unsigned short* __restrict__ v,
                                              unsigned short* __restrict__ vT) {
    __shared__ unsigned short tile[64][72];
    const int bh = blockIdx.y, l0 = blockIdx.x * 64;
    const int t = threadIdx.x;
    #pragma unroll
    for (int u = 0; u < 2; ++u) {
        int id = t + u * 256; int r = id >> 3, c = (id & 7) * 8;
        *reinterpret_cast<uint4*>(&tile[r][c]) = *reinterpret_cast<const uint4*>(
            &v[((size_t)bh * LSEQ + l0 + r) * HD + c]);
    }
    __syncthreads();
    #pragma unroll
    for (int u = 0; u < 2; ++u) {
        int id = t + u * 256; int d = id >> 3, lc = (id & 7) * 8;
        unsigned short tmp[8];
        #pragma unroll
        for (int j = 0; j < 8; ++j) tmp[j] = tile[lc + j][d];
        *reinterpret_cast<uint4*>(&vT[((size_t)bh * HD + d) * LSEQ + l0 + lc]) =
            *reinterpret_cast<uint4*>(tmp);
    }
}

// ---------------- bf16 MFMA GEMM ----------------
// C[M,N] = A[M,K] @ W[K,N] + bias, W given transposed (WT[N][K]).
// MODE 0: scatter to q/k/v head-major bf16 (o0,o1,o2)
// MODE 1: fp32 out = val + res (fp32)
// MODE 2: bf16 out = gelu(val)
template<int MODE>
__global__ __launch_bounds__(256) void gemm_bf16(
    const unsigned short* __restrict__ A, const unsigned short* __restrict__ WT,
    const float* __restrict__ bias, const float* __restrict__ res,
    void* __restrict__ o0, void* __restrict__ o1, void* __restrict__ o2,
    int M, int N, int K)
{
    __shared__ unsigned short As[128][72];
    __shared__ unsigned short Bs[128][72];
    const int t = threadIdx.x;
    const int m0 = blockIdx.y * 128, n0 = blockIdx.x * 128;
    const int w = t >> 6, lane = t & 63;
    const int wm = (w >> 1) * 64, wn = (w & 1) * 64;
    const int lr = lane & 15, lk = (lane >> 4) * 8;
    const int rb = (lane >> 4) * 4;

    f32x4 zero = {0.f, 0.f, 0.f, 0.f};
    f32x4 acc[4][4];
    #pragma unroll
    for (int i = 0; i < 4; ++i)
        #pragma unroll
        for (int j = 0; j < 4; ++j) acc[i][j] = zero;

    for (int k0 = 0; k0 < K; k0 += 64) {
        __syncthreads();
        #pragma unroll
        for (int u = 0; u < 4; ++u) {
            int id = t + u * 256;
            int r = id >> 3, kc = (id & 7) * 8;
            *reinterpret_cast<uint4*>(&As[r][kc]) =
                *reinterpret_cast<const uint4*>(&A[(size_t)(m0 + r) * K + k0 + kc]);
            *reinterpret_cast<uint4*>(&Bs[r][kc]) =
                *reinterpret_cast<const uint4*>(&WT[(size_t)(n0 + r) * K + k0 + kc]);
        }
        __syncthreads();
        #pragma unroll
        for (int kk = 0; kk < 2; ++kk) {
            bf16x8 a[4], b[4];
            #pragma unroll
            for (int i = 0; i < 4; ++i)
                a[i] = *reinterpret_cast<const bf16x8*>(&As[wm + i * 16 + lr][kk * 32 + lk]);
            #pragma unroll
            for (int j = 0; j < 4; ++j)
                b[j] = *reinterpret_cast<const bf16x8*>(&Bs[wn + j * 16 + lr][kk * 32 + lk]);
            #pragma unroll
            for (int i = 0; i < 4; ++i)
                #pragma unroll
                for (int j = 0; j < 4; ++j)
                    acc[i][j] = MFMA16(a[i], b[j], acc[i][j]);
        }
    }

    #pragma unroll
    for (int i = 0; i < 4; ++i) {
        #pragma unroll
        for (int j = 0; j < 4; ++j) {
            const int n = n0 + wn + j * 16 + lr;
            const float bv = bias[n];
            #pragma unroll
            for (int r = 0; r < 4; ++r) {
                const int m = m0 + wm + i * 16 + rb + r;
                float val = acc[i][j][r] + bv;
                if (MODE == 0) {
                    const int which = n >> 9, nn = n & 511, hs = nn >> 6, d = nn & 63;
                    const int bh = (m >> 11) * 8 + hs, l = m & 2047;
                    unsigned short* p = (which == 0) ? (unsigned short*)o0
                                      : (which == 1) ? (unsigned short*)o1
                                                     : (unsigned short*)o2;
                    p[((size_t)bh * LSEQ + l) * HD + d] = f2bf(val);
                } else if (MODE == 1) {
                    size_t idx = (size_t)m * N + n;
                    ((float*)o0)[idx] = val + res[idx];
                } else {
                    size_t idx = (size_t)m * N + n;
                    ((unsigned short*)o0)[idx] = f2bf(gelu_f(val));
                }
            }
        }
    }
}

// ---------------- MFMA flash attention ----------------
// grid (BHN, LSEQ/64), block 256 (4 waves, 16 q-rows each).
__global__ __launch_bounds__(256) void attn_mfma(
    const unsigned short* __restrict__ Q, const unsigned short* __restrict__ K,
    const unsigned short* __restrict__ VT, const int* __restrict__ mask,
    unsigned short* __restrict__ out)
{
    __shared__ unsigned short Qs[64][72];
    __shared__ unsigned short Ks[64][72];
    __shared__ unsigned short Vs[64][72];   // transposed V tile: [d][key]
    __shared__ unsigned short Ps[64][72];
    __shared__ float kb[64];

    const int bh = blockIdx.x, qt = blockIdx.y;
    const int b = bh >> 3, hh = bh & 7;
    const int t = threadIdx.x, w = t >> 6, lane = t & 63;
    const int lr = lane & 15, lk = (lane >> 4) * 8;
    const int rb = (lane >> 4) * 4;
    const int qr0 = qt * 64;
    const int c = qr0 >> 9;
    const int kstart = max(0, (c - 1) * 512), kend = min(LSEQ, (c + 2) * 512);

    #pragma unroll
    for (int u = 0; u < 2; ++u) {
        int id = t + u * 256; int r = id >> 3, kc = (id & 7) * 8;
        *reinterpret_cast<uint4*>(&Qs[r][kc]) = *reinterpret_cast<const uint4*>(
            &Q[((size_t)bh * LSEQ + qr0 + r) * HD + kc]);
    }
    __syncthreads();
    bf16x8 qf[2];
    qf[0] = *reinterpret_cast<const bf16x8*>(&Qs[w * 16 + lr][lk]);
    qf[1] = *reinterpret_cast<const bf16x8*>(&Qs[w * 16 + lr][32 + lk]);

    f32x4 zero = {0.f, 0.f, 0.f, 0.f};
    float m_r[4] = {-1e30f, -1e30f, -1e30f, -1e30f};
    float l_r[4] = {0.f, 0.f, 0.f, 0.f};
    f32x4 acc[4];
    #pragma unroll
    for (int j = 0; j < 4; ++j) acc[j] = zero;

    for (int kg = kstart; kg < kend; kg += 64) {
        __syncthreads();   // prior PV done reading Vs/Ps
        #pragma unroll
        for (int u = 0; u < 2; ++u) {
            int id = t + u * 256; int r = id >> 3, kc = (id & 7) * 8;
            *reinterpret_cast<uint4*>(&Ks[r][kc]) = *reinterpret_cast<const uint4*>(
                &K[((size_t)bh * LSEQ + kg + r) * HD + kc]);
            *reinterpret_cast<uint4*>(&Vs[r][kc]) = *reinterpret_cast<const uint4*>(
                &VT[((size_t)bh * HD + r) * LSEQ + kg + kc]);
        }
        if (t < 64) kb[t] = mask[b * LSEQ + kg + t] ? -1e30f : 0.0f;
        __syncthreads();

        // S = Q K^T  (rows=q, cols=key)
        f32x4 s[4];
        #pragma unroll
        for (int j = 0; j < 4; ++j) s[j] = zero;
        #pragma unroll
        for (int kk = 0; kk < 2; ++kk) {
            #pragma unroll
            for (int j = 0; j < 4; ++j) {
                bf16x8 bk = *reinterpret_cast<const bf16x8*>(&Ks[j * 16 + lr][kk * 32 + lk]);
                s[j] = MFMA16(qf[kk], bk, s[j]);
            }
        }
        // online softmax; row = w*16 + rb + r, owned by the 16 lanes with same (lane>>4)
        float f_r[4];
        #pragma unroll
        for (int r = 0; r < 4; ++r) {
            float sc[4];
            #pragma unroll
            for (int j = 0; j < 4; ++j) sc[j] = s[j][r] * 0.125f + kb[j * 16 + lr];
            float mx = fmaxf(fmaxf(sc[0], sc[1]), fmaxf(sc[2], sc[3]));
            mx = fmaxf(mx, __shfl_xor(mx, 1, 16));
            mx = fmaxf(mx, __shfl_xor(mx, 2, 16));
            mx = fmaxf(mx, __shfl_xor(mx, 4, 16));
            mx = fmaxf(mx, __shfl_xor(mx, 8, 16));
            float nm = fmaxf(m_r[r], mx);
            float f = __expf(m_r[r] - nm);
            float p[4], sum = 0.f;
            #pragma unroll
            for (int j = 0; j < 4; ++j) { p[j] = __expf(sc[j] - nm); sum += p[j]; }
            #pragma unroll
            for (int j = 0; j < 4; ++j) Ps[w * 16 + rb + r][j * 16 + lr] = f2bf(p[j]);
            sum += __shfl_xor(sum, 1, 16);
            sum += __shfl_xor(sum, 2, 16);
            sum += __shfl_xor(sum, 4, 16);
            sum += __shfl_xor(sum, 8, 16);
            l_r[r] = l_r[r] * f + sum;
            m_r[r] = nm;
            f_r[r] = f;
        }
        #pragma unroll
        for (int j = 0; j < 4; ++j)
            #pragma unroll
            for (int r = 0; r < 4; ++r) acc[j][r] *= f_r[r];
        __syncthreads();   // Ps/Vs staged + written before PV reads

        // O += P V   (A = P rows=q cols=key, B = V[key][d] read from Vs[d][key])
        #pragma unroll
        for (int kk = 0; kk < 2; ++kk) {
            bf16x8 pa = *reinterpret_cast<const bf16x8*>(&Ps[w * 16 + lr][kk * 32 + lk]);
            #pragma unroll
            for (int j = 0; j < 4; ++j) {
                bf16x8 bv = *reinterpret_cast<const bf16x8*>(&Vs[j * 16 + lr][kk * 32 + lk]);
                acc[j] = MFMA16(pa, bv, acc[j]);
            }
        }
    }

    float linv[4];
    #pragma unroll
    for (int r = 0; r < 4; ++r) linv[r] = 1.0f / l_r[r];
    #pragma unroll
    for (int j = 0; j < 4; ++j) {
        #pragma unroll
        for (int r = 0; r < 4; ++r) {
            const int l = qr0 + w * 16 + rb + r;
            const int d = j * 16 + lr;
            out[((size_t)(b * LSEQ + l)) * EMBED + hh * HD + d] = f2bf(acc[j][r] * linv[r]);
        }
    }
}

// ---------------- layernorm ----------------
// grid MROWS, block 256.  DUAL: also write bf16 copy.
template<int DUAL>
__global__ __launch_bounds__(256) void ln_kernel(
    const float* __restrict__ in, const float* __restrict__ g,
    const float* __restrict__ bt, float* __restrict__ outf,
    unsigned short* __restrict__ outb)
{
    const int row = blockIdx.x;
    const int t = threadIdx.x;
    const float* x = in + (size_t)row * EMBED;
    float2 v = *reinterpret_cast<const float2*>(&x[t * 2]);
    float s = v.x + v.y, ss = v.x * v.x + v.y * v.y;
    #pragma unroll
    for (int off = 1; off < 64; off <<= 1) {
        s  += __shfl_xor(s, off);
        ss += __shfl_xor(ss, off);
    }
    __shared__ float red[8];
    const int w = t >> 6;
    if ((t & 63) == 0) { red[w * 2] = s; red[w * 2 + 1] = ss; }
    __syncthreads();
    s  = red[0] + red[2] + red[4] + red[6];
    ss = red[1] + red[3] + red[5] + red[7];
    const float mu = s * (1.0f / EMBED);
    const float var = ss * (1.0f / EMBED) - mu * mu;
    const float rs = rsqrtf(var + 1e-5f);
    float2 gg = *reinterpret_cast<const float2*>(&g[t * 2]);
    float2 bb = *reinterpret_cast<const float2*>(&bt[t * 2]);
    float ox = (v.x - mu) * rs * gg.x + bb.x;
    float oy = (v.y - mu) * rs * gg.y + bb.y;
    *reinterpret_cast<float2*>(&outf[(size_t)row * EMBED + t * 2]) = make_float2(ox, oy);
    if (DUAL) {
        unsigned short tmp[2] = {f2bf(ox), f2bf(oy)};
        *reinterpret_cast<unsigned int*>(&outb[(size_t)row * EMBED + t * 2]) =
            *reinterpret_cast<unsigned int*>(tmp);
    }
}

extern "C" void kernel_launch(void* const* d_in, const int* in_sizes, int n_in,
                              void* d_out, int out_size, void* d_ws, size_t ws_size,
                              hipStream_t stream) {
    const float* x      = (const float*)d_in[0];
    const int*   mask   = (const int*)  d_in[1];
    const float* qkv_w  = (const float*)d_in[2];
    const float* qkv_b  = (const float*)d_in[3];
    const float* out_w  = (const float*)d_in[4];
    const float* out_b  = (const float*)d_in[5];
    const float* ffn_w1 = (const float*)d_in[6];
    const float* ffn_b1 = (const float*)d_in[7];
    const float* ffn_w2 = (const float*)d_in[8];
    const float* ffn_b2 = (const float*)d_in[9];
    const float* ln1_g  = (const float*)d_in[10];
    const float* ln1_b  = (const float*)d_in[11];
    const float* ln2_g  = (const float*)d_in[12];
    const float* ln2_b  = (const float*)d_in[13];

    char* wsb = (char*)d_ws;
    unsigned short* qkv_wT = (unsigned short*)(wsb + 0);          // 1.5 MB
    unsigned short* out_wT = (unsigned short*)(wsb + 1572864);    // 0.5 MB
    unsigned short* w1T    = (unsigned short*)(wsb + 2097152);    // 2 MB
    unsigned short* w2T    = (unsigned short*)(wsb + 4194304);    // 2 MB
    unsigned short* xb     = (unsigned short*)(wsb + 6291456);    // A: 8 MB
    unsigned short* qb     = (unsigned short*)(wsb + 14680064);   // B: 8 MB
    unsigned short* kbuf   = (unsigned short*)(wsb + 23068672);   // C: 8 MB
    unsigned short* vb     = (unsigned short*)(wsb + 31457280);   // D: 8 MB
    float*          y      = (float*)(wsb + 39845888);            // E: 16 MB
    unsigned short* vT     = xb;     // A reused (xb dead after QKV gemm)
    unsigned short* am     = vb;     // D reused (v row-major dead after vtrans)
    unsigned short* xlnb   = xb;     // A reused (vT dead after attn)
    float*          xlnf   = (float*)(wsb + 14680064);            // B+C reused, 16 MB
    unsigned short* h      = (unsigned short*)(wsb + 31457280);   // D+E+F: 32 MB [30,62)
    float*          z      = (float*)(wsb + 65011712);            // [62,78)

    // prep
    cvt_bf16<<<MROWS * EMBED / 8 / 256, 256, 0, stream>>>(x, xb, MROWS * EMBED);
    wtrans<<<dim3(1536 / 32, 512 / 32),  256, 0, stream>>>(qkv_w,  qkv_wT, 512, 1536);
    wtrans<<<dim3(512 / 32,  512 / 32),  256, 0, stream>>>(out_w,  out_wT, 512, 512);
    wtrans<<<dim3(2048 / 32, 512 / 32),  256, 0, stream>>>(ffn_w1, w1T,    512, 2048);
    wtrans<<<dim3(512 / 32,  2048 / 32), 256, 0, stream>>>(ffn_w2, w2T,    2048, 512);

    // 1) QKV projection -> q,k,v head-major bf16
    gemm_bf16<0><<<dim3(1536 / 128, MROWS / 128), 256, 0, stream>>>(
        xb, qkv_wT, qkv_b, nullptr, qb, kbuf, vb, MROWS, 1536, 512);
    // 2) V transpose per head
    vtrans<<<dim3(LSEQ / 64, BHN), 256, 0, stream>>>(vb, vT);
    // 3) attention -> am (merged bf16)
    attn_mfma<<<dim3(BHN, LSEQ / 64), 256, 0, stream>>>(qb, kbuf, vT, mask, am);
    // 4) out projection + residual(x) -> y fp32
    gemm_bf16<1><<<dim3(EMBED / 128, MROWS / 128), 256, 0, stream>>>(
        am, out_wT, out_b, x, y, nullptr, nullptr, MROWS, EMBED, 512);
    // 5) LN1 -> xlnf + xlnb
    ln_kernel<1><<<MROWS, 256, 0, stream>>>(y, ln1_g, ln1_b, xlnf, xlnb);
    // 6) FFN1 + GELU -> h bf16
    gemm_bf16<2><<<dim3(FFN_ / 128, MROWS / 128), 256, 0, stream>>>(
        xlnb, w1T, ffn_b1, nullptr, h, nullptr, nullptr, MROWS, FFN_, 512);
    // 7) FFN2 + residual(xlnf) -> z fp32
    gemm_bf16<1><<<dim3(EMBED / 128, MROWS / 128), 256, 0, stream>>>(
        h, w2T, ffn_b2, xlnf, z, nullptr, nullptr, MROWS, EMBED, FFN_);
    // 8) LN2 -> out
    ln_kernel<0><<<MROWS, 256, 0, stream>>>(z, ln2_g, ln2_b, (float*)d_out, nullptr);
}

// Round 3
// 300.559 us; speedup vs baseline: 5.3847x; 1.0787x over previous
//
#include <hip/hip_runtime.h>
#include <hip/hip_bf16.h>
#include <math.h>

#define EMBED 512
#define HEADS 8
#define HD    64
#define FFN_  2048
#define NB    4
#define LSEQ  2048
#define MROWS (NB*LSEQ)    // 8192
#define BHN   (NB*HEADS)   // 32

typedef __attribute__((ext_vector_type(8))) short bf16x8;
typedef __attribute__((ext_vector_type(4))) float f32x4;
#define MFMA16(a,b,c) __builtin_amdgcn_mfma_f32_16x16x32_bf16(a,b,c,0,0,0)

__device__ __forceinline__ unsigned short f2bf(float f) {
    unsigned int u = __float_as_uint(f);
    u += 0x7fff + ((u >> 16) & 1);          // round-to-nearest-even
    return (unsigned short)(u >> 16);
}
__device__ __forceinline__ unsigned int cvt_pk_bf16(float lo, float hi) {
    unsigned int r;
    asm("v_cvt_pk_bf16_f32 %0, %1, %2" : "=v"(r) : "v"(lo), "v"(hi));
    return r;
}
__device__ __forceinline__ void gl_lds16(const unsigned short* g, unsigned short* l) {
    __builtin_amdgcn_global_load_lds(
        (const __attribute__((address_space(1))) unsigned int*)g,
        (__attribute__((address_space(3))) unsigned int*)l, 16, 0, 0);
}
__device__ __forceinline__ float gelu_f(float v) {
    return 0.5f * v * (1.0f + erff(v * 0.70710678118654752f));
}

// ---------------- prep kernels ----------------

__global__ __launch_bounds__(256) void cvt_bf16(const float* __restrict__ in,
                                                unsigned short* __restrict__ out, int n) {
    int i = (blockIdx.x * 256 + threadIdx.x) * 8;
    if (i >= n) return;
    float4 a = *reinterpret_cast<const float4*>(&in[i]);
    float4 b = *reinterpret_cast<const float4*>(&in[i + 4]);
    unsigned short t[8] = {f2bf(a.x), f2bf(a.y), f2bf(a.z), f2bf(a.w),
                           f2bf(b.x), f2bf(b.y), f2bf(b.z), f2bf(b.w)};
    *reinterpret_cast<uint4*>(&out[i]) = *reinterpret_cast<uint4*>(t);
}

// fp32 W[K][N] -> bf16 WT[N][K].  grid (N/32, K/32), block 256.
__global__ __launch_bounds__(256) void wtrans(const float* __restrict__ in,
                                              unsigned short* __restrict__ out,
                                              int K, int N) {
    __shared__ float tile[32][33];
    const int k0 = blockIdx.y * 32, n0 = blockIdx.x * 32;
    const int t = threadIdx.x;
    const int r = t >> 3, c = (t & 7) * 4;
    float4 v = *reinterpret_cast<const float4*>(&in[(size_t)(k0 + r) * N + n0 + c]);
    tile[r][c] = v.x; tile[r][c + 1] = v.y; tile[r][c + 2] = v.z; tile[r][c + 3] = v.w;
    __syncthreads();
    unsigned short tmp[4] = {f2bf(tile[c + 0][r]), f2bf(tile[c + 1][r]),
                             f2bf(tile[c + 2][r]), f2bf(tile[c + 3][r])};
    *reinterpret_cast<uint2*>(&out[(size_t)(n0 + r) * K + k0 + c]) =
        *reinterpret_cast<uint2*>(tmp);
}

// v bf16 [BH][L][HD] -> vTp [BH][HD][L], key-permuted within each 64-tile:
// vTp[bh][d][tile*64 + kap] = v[bh][tile*64 + (kap&3)*16 + (kap>>2)][d]
__global__ __launch_bounds__(256) void vtransp(const unsigned short* __restrict__ v,
                                               unsigned short* __restrict__ vT) {
    __shared__ unsigned short tile[64][72];
    const int bh = blockIdx.y, l0 = blockIdx.x * 64;
    const int t = threadIdx.x;
    #pragma unroll
    for (int u = 0; u < 2; ++u) {
        int id = t + u * 256; int r = id >> 3, c = (id & 7) * 8;
        *reinterpret_cast<uint4*>(&tile[r][c]) = *reinterpret_cast<const uint4*>(
            &v[((size_t)bh * LSEQ + l0 + r) * HD + c]);
    }
    __syncthreads();
    #pragma unroll
    for (int u = 0; u < 2; ++u) {
        int id = t + u * 256; int d = id >> 3, kc = (id & 7) * 8;
        unsigned short tmp[8];
        #pragma unroll
        for (int jj = 0; jj < 8; ++jj) {
            int kap = kc + jj;
            tmp[jj] = tile[(kap & 3) * 16 + (kap >> 2)][d];
        }
        *reinterpret_cast<uint4*>(&vT[((size_t)bh * HD + d) * LSEQ + l0 + kc]) =
            *reinterpret_cast<uint4*>(tmp);
    }
}

// ---------------- bf16 MFMA GEMM (m97 structure: global_load_lds + linear LDS) ----
// MODE 0: scatter to q/k/v head-major bf16 (o0,o1,o2)
// MODE 1: fp32 out = val + res (fp32)
// MODE 2: bf16 out = gelu(val)
template<int MODE>
__global__ __launch_bounds__(256) void gemm_bf16(
    const unsigned short* __restrict__ A, const unsigned short* __restrict__ WT,
    const float* __restrict__ bias, const float* __restrict__ res,
    void* __restrict__ o0, void* __restrict__ o1, void* __restrict__ o2,
    int M, int N, int K)
{
    __shared__ unsigned short As[128 * 64];
    __shared__ unsigned short Bs[128 * 64];
    const int t = threadIdx.x;
    const int m0 = blockIdx.y * 128, n0 = blockIdx.x * 128;
    const int w = t >> 6, lane = t & 63;
    const int wm = (w >> 1) * 64, wn = (w & 1) * 64;
    const int lr = lane & 15, lk = (lane >> 4) * 8;
    const int rb = (lane >> 4) * 4;
    const int srow = lane >> 3, scol = (lane & 7) * 8;

    f32x4 zero = {0.f, 0.f, 0.f, 0.f};
    f32x4 acc[4][4];
    #pragma unroll
    for (int i = 0; i < 4; ++i)
        #pragma unroll
        for (int j = 0; j < 4; ++j) acc[i][j] = zero;

    for (int k0 = 0; k0 < K; k0 += 64) {
        __syncthreads();                      // previous tile's reads complete
        #pragma unroll
        for (int i = 0; i < 4; ++i) {
            const int seg = w * 4 + i;        // 0..15, 8 rows each
            const int r = seg * 8 + srow;
            gl_lds16(A  + (size_t)(m0 + r) * K + k0 + scol, &As[seg * 512 + lane * 8]);
            gl_lds16(WT + (size_t)(n0 + r) * K + k0 + scol, &Bs[seg * 512 + lane * 8]);
        }
        __syncthreads();                      // vmcnt drained -> LDS valid
        #pragma unroll
        for (int kk = 0; kk < 2; ++kk) {
            bf16x8 a[4], b[4];
            #pragma unroll
            for (int i = 0; i < 4; ++i)
                a[i] = *reinterpret_cast<const bf16x8*>(&As[(wm + i * 16 + lr) * 64 + kk * 32 + lk]);
            #pragma unroll
            for (int j = 0; j < 4; ++j)
                b[j] = *reinterpret_cast<const bf16x8*>(&Bs[(wn + j * 16 + lr) * 64 + kk * 32 + lk]);
            #pragma unroll
            for (int i = 0; i < 4; ++i)
                #pragma unroll
                for (int j = 0; j < 4; ++j)
                    acc[i][j] = MFMA16(a[i], b[j], acc[i][j]);
        }
    }

    #pragma unroll
    for (int i = 0; i < 4; ++i) {
        #pragma unroll
        for (int j = 0; j < 4; ++j) {
            const int n = n0 + wn + j * 16 + lr;
            const float bv = bias[n];
            #pragma unroll
            for (int r = 0; r < 4; ++r) {
                const int m = m0 + wm + i * 16 + rb + r;
                float val = acc[i][j][r] + bv;
                if (MODE == 0) {
                    const int which = n >> 9, nn = n & 511, hs = nn >> 6, d = nn & 63;
                    const int bh = (m >> 11) * 8 + hs, l = m & 2047;
                    unsigned short* p = (which == 0) ? (unsigned short*)o0
                                      : (which == 1) ? (unsigned short*)o1
                                                     : (unsigned short*)o2;
                    p[((size_t)bh * LSEQ + l) * HD + d] = f2bf(val);
                } else if (MODE == 1) {
                    size_t idx = (size_t)m * N + n;
                    ((float*)o0)[idx] = val + res[idx];
                } else {
                    size_t idx = (size_t)m * N + n;
                    ((unsigned short*)o0)[idx] = f2bf(gelu_f(val));
                }
            }
        }
    }
}

// ---------------- MFMA flash attention (fixed-max softmax, MFMA row-sums) -------
// grid (BHN, LSEQ/64), block 256 (4 waves, 16 q-rows each).
__global__ __launch_bounds__(256) void attn_mfma(
    const unsigned short* __restrict__ Q, const unsigned short* __restrict__ K,
    const unsigned short* __restrict__ VTp, const int* __restrict__ mask,
    unsigned short* __restrict__ out)
{
    __shared__ unsigned short Qs[64][72];   // reused as Ps after qf extraction
    __shared__ unsigned short Ks[64][72];
    __shared__ unsigned short Vs[64][72];   // permuted-transposed V tile: [d][kap]
    __shared__ float kbl[64];
    unsigned short (*Ps)[72] = Qs;

    const int bh = blockIdx.x, qt = blockIdx.y;
    const int b = bh >> 3, hh = bh & 7;
    const int t = threadIdx.x, w = t >> 6, lane = t & 63;
    const int lr = lane & 15, lk = (lane >> 4) * 8;
    const int rb = (lane >> 4) * 4;
    const int qr0 = qt * 64;
    const int c = qr0 >> 9;
    const int kstart = max(0, (c - 1) * 512), kend = min(LSEQ, (c + 2) * 512);

    const float C1  = 0.18033688f;   // 0.125 * log2(e)
    const float KB0 = -14.4269504f;  // -MFIX(=10) * log2(e)

    #pragma unroll
    for (int u = 0; u < 2; ++u) {
        int id = t + u * 256; int r = id >> 3, kc = (id & 7) * 8;
        *reinterpret_cast<uint4*>(&Qs[r][kc]) = *reinterpret_cast<const uint4*>(
            &Q[((size_t)bh * LSEQ + qr0 + r) * HD + kc]);
    }
    __syncthreads();
    bf16x8 qf[2];
    qf[0] = *reinterpret_cast<const bf16x8*>(&Qs[w * 16 + lr][lk]);
    qf[1] = *reinterpret_cast<const bf16x8*>(&Qs[w * 16 + lr][32 + lk]);
    bf16x8 vone;
    #pragma unroll
    for (int i = 0; i < 8; ++i) vone[i] = (short)0x3f80;   // bf16 1.0

    f32x4 zero = {0.f, 0.f, 0.f, 0.f};
    f32x4 acc[4], accl = zero;
    #pragma unroll
    for (int j = 0; j < 4; ++j) acc[j] = zero;

    for (int kg = kstart; kg < kend; kg += 64) {
        __syncthreads();   // prior PV reads of Ks/Vs/Ps done; qf reads done (1st iter)
        #pragma unroll
        for (int u = 0; u < 2; ++u) {
            int id = t + u * 256; int r = id >> 3, kc = (id & 7) * 8;
            *reinterpret_cast<uint4*>(&Ks[r][kc]) = *reinterpret_cast<const uint4*>(
                &K[((size_t)bh * LSEQ + kg + r) * HD + kc]);
            *reinterpret_cast<uint4*>(&Vs[r][kc]) = *reinterpret_cast<const uint4*>(
                &VTp[((size_t)bh * HD + r) * LSEQ + kg + kc]);
        }
        if (t < 64) kbl[t] = mask[b * LSEQ + kg + t] ? -1e30f : KB0;
        __syncthreads();

        // S = Q K^T
        f32x4 s[4];
        #pragma unroll
        for (int j = 0; j < 4; ++j) s[j] = zero;
        #pragma unroll
        for (int kk = 0; kk < 2; ++kk) {
            #pragma unroll
            for (int j = 0; j < 4; ++j) {
                bf16x8 bk = *reinterpret_cast<const bf16x8*>(&Ks[j * 16 + lr][kk * 32 + lk]);
                s[j] = MFMA16(qf[kk], bk, s[j]);
            }
        }
        // fixed-max softmax: p = exp2(s*C1 + kbl[key]); write permuted-contiguous
        #pragma unroll
        for (int r = 0; r < 4; ++r) {
            float p0 = __builtin_amdgcn_exp2f(fmaf(s[0][r], C1, kbl[0 * 16 + lr]));
            float p1 = __builtin_amdgcn_exp2f(fmaf(s[1][r], C1, kbl[1 * 16 + lr]));
            float p2 = __builtin_amdgcn_exp2f(fmaf(s[2][r], C1, kbl[2 * 16 + lr]));
            float p3 = __builtin_amdgcn_exp2f(fmaf(s[3][r], C1, kbl[3 * 16 + lr]));
            uint2 pw;
            pw.x = cvt_pk_bf16(p0, p1);   // kap = 4*lr + {0,1}
            pw.y = cvt_pk_bf16(p2, p3);   // kap = 4*lr + {2,3}
            *reinterpret_cast<uint2*>(&Ps[w * 16 + rb + r][lr * 4]) = pw;
        }
        // O += P V ; l += P @ ones  (Ps rows are wave-private: no barrier needed)
        #pragma unroll
        for (int kk = 0; kk < 2; ++kk) {
            bf16x8 pa = *reinterpret_cast<const bf16x8*>(&Ps[w * 16 + lr][kk * 32 + lk]);
            #pragma unroll
            for (int j = 0; j < 4; ++j) {
                bf16x8 bv = *reinterpret_cast<const bf16x8*>(&Vs[j * 16 + lr][kk * 32 + lk]);
                acc[j] = MFMA16(pa, bv, acc[j]);
            }
            accl = MFMA16(pa, vone, accl);
        }
    }

    float linv[4];
    #pragma unroll
    for (int r = 0; r < 4; ++r) linv[r] = 1.0f / accl[r];
    #pragma unroll
    for (int j = 0; j < 4; ++j) {
        #pragma unroll
        for (int r = 0; r < 4; ++r) {
            const int l = qr0 + w * 16 + rb + r;
            const int d = j * 16 + lr;
            out[((size_t)(b * LSEQ + l)) * EMBED + hh * HD + d] = f2bf(acc[j][r] * linv[r]);
        }
    }
}

// ---------------- layernorm ----------------
template<int DUAL>
__global__ __launch_bounds__(256) void ln_kernel(
    const float* __restrict__ in, const float* __restrict__ g,
    const float* __restrict__ bt, float* __restrict__ outf,
    unsigned short* __restrict__ outb)
{
    const int row = blockIdx.x;
    const int t = threadIdx.x;
    const float* x = in + (size_t)row * EMBED;
    float2 v = *reinterpret_cast<const float2*>(&x[t * 2]);
    float s = v.x + v.y, ss = v.x * v.x + v.y * v.y;
    #pragma unroll
    for (int off = 1; off < 64; off <<= 1) {
        s  += __shfl_xor(s, off);
        ss += __shfl_xor(ss, off);
    }
    __shared__ float red[8];
    const int w = t >> 6;
    if ((t & 63) == 0) { red[w * 2] = s; red[w * 2 + 1] = ss; }
    __syncthreads();
    s  = red[0] + red[2] + red[4] + red[6];
    ss = red[1] + red[3] + red[5] + red[7];
    const float mu = s * (1.0f / EMBED);
    const float var = ss * (1.0f / EMBED) - mu * mu;
    const float rs = rsqrtf(var + 1e-5f);
    float2 gg = *reinterpret_cast<const float2*>(&g[t * 2]);
    float2 bb = *reinterpret_cast<const float2*>(&bt[t * 2]);
    float ox = (v.x - mu) * rs * gg.x + bb.x;
    float oy = (v.y - mu) * rs * gg.y + bb.y;
    *reinterpret_cast<float2*>(&outf[(size_t)row * EMBED + t * 2]) = make_float2(ox, oy);
    if (DUAL) {
        unsigned short tmp[2] = {f2bf(ox), f2bf(oy)};
        *reinterpret_cast<unsigned int*>(&outb[(size_t)row * EMBED + t * 2]) =
            *reinterpret_cast<unsigned int*>(tmp);
    }
}

extern "C" void kernel_launch(void* const* d_in, const int* in_sizes, int n_in,
                              void* d_out, int out_size, void* d_ws, size_t ws_size,
                              hipStream_t stream) {
    const float* x      = (const float*)d_in[0];
    const int*   mask   = (const int*)  d_in[1];
    const float* qkv_w  = (const float*)d_in[2];
    const float* qkv_b  = (const float*)d_in[3];
    const float* out_w  = (const float*)d_in[4];
    const float* out_b  = (const float*)d_in[5];
    const float* ffn_w1 = (const float*)d_in[6];
    const float* ffn_b1 = (const float*)d_in[7];
    const float* ffn_w2 = (const float*)d_in[8];
    const float* ffn_b2 = (const float*)d_in[9];
    const float* ln1_g  = (const float*)d_in[10];
    const float* ln1_b  = (const float*)d_in[11];
    const float* ln2_g  = (const float*)d_in[12];
    const float* ln2_b  = (const float*)d_in[13];

    char* wsb = (char*)d_ws;
    unsigned short* qkv_wT = (unsigned short*)(wsb + 0);          // 1.5 MB
    unsigned short* out_wT = (unsigned short*)(wsb + 1572864);    // 0.5 MB
    unsigned short* w1T    = (unsigned short*)(wsb + 2097152);    // 2 MB
    unsigned short* w2T    = (unsigned short*)(wsb + 4194304);    // 2 MB
    unsigned short* xb     = (unsigned short*)(wsb + 6291456);    // A: 8 MB
    unsigned short* qb     = (unsigned short*)(wsb + 14680064);   // B: 8 MB
    unsigned short* kbuf   = (unsigned short*)(wsb + 23068672);   // C: 8 MB
    unsigned short* vb     = (unsigned short*)(wsb + 31457280);   // D: 8 MB
    float*          y      = (float*)(wsb + 39845888);            // E: 16 MB
    unsigned short* vTp    = xb;     // A reused (xb dead after QKV gemm)
    unsigned short* am     = vb;     // D reused (v row-major dead after vtransp)
    unsigned short* xlnb   = xb;     // A reused (vTp dead after attn)
    float*          xlnf   = (float*)(wsb + 14680064);            // B+C reused, 16 MB
    unsigned short* h      = (unsigned short*)(wsb + 31457280);   // D+E: 32 MB
    float*          z      = (float*)(wsb + 65011712);            // 16 MB

    // prep
    cvt_bf16<<<MROWS * EMBED / 8 / 256, 256, 0, stream>>>(x, xb, MROWS * EMBED);
    wtrans<<<dim3(1536 / 32, 512 / 32),  256, 0, stream>>>(qkv_w,  qkv_wT, 512, 1536);
    wtrans<<<dim3(512 / 32,  512 / 32),  256, 0, stream>>>(out_w,  out_wT, 512, 512);
    wtrans<<<dim3(2048 / 32, 512 / 32),  256, 0, stream>>>(ffn_w1, w1T,    512, 2048);
    wtrans<<<dim3(512 / 32,  2048 / 32), 256, 0, stream>>>(ffn_w2, w2T,    2048, 512);

    // 1) QKV projection -> q,k,v head-major bf16
    gemm_bf16<0><<<dim3(1536 / 128, MROWS / 128), 256, 0, stream>>>(
        xb, qkv_wT, qkv_b, nullptr, qb, kbuf, vb, MROWS, 1536, 512);
    // 2) V transpose+permute per head
    vtransp<<<dim3(LSEQ / 64, BHN), 256, 0, stream>>>(vb, vTp);
    // 3) attention -> am (merged bf16)
    attn_mfma<<<dim3(BHN, LSEQ / 64), 256, 0, stream>>>(qb, kbuf, vTp, mask, am);
    // 4) out projection + residual(x) -> y fp32
    gemm_bf16<1><<<dim3(EMBED / 128, MROWS / 128), 256, 0, stream>>>(
        am, out_wT, out_b, x, y, nullptr, nullptr, MROWS, EMBED, 512);
    // 5) LN1 -> xlnf + xlnb
    ln_kernel<1><<<MROWS, 256, 0, stream>>>(y, ln1_g, ln1_b, xlnf, xlnb);
    // 6) FFN1 + GELU -> h bf16
    gemm_bf16<2><<<dim3(FFN_ / 128, MROWS / 128), 256, 0, stream>>>(
        xlnb, w1T, ffn_b1, nullptr, h, nullptr, nullptr, MROWS, FFN_, 512);
    // 7) FFN2 + residual(xlnf) -> z fp32
    gemm_bf16<1><<<dim3(EMBED / 128, MROWS / 128), 256, 0, stream>>>(
        h, w2T, ffn_b2, xlnf, z, nullptr, nullptr, MROWS, EMBED, FFN_);
    // 8) LN2 -> out
    ln_kernel<0><<<MROWS, 256, 0, stream>>>(z, ln2_g, ln2_b, (float*)d_out, nullptr);
}

// Round 4
// 296.128 us; speedup vs baseline: 5.4652x; 1.0150x over previous
//
#include <hip/hip_runtime.h>
#include <hip/hip_bf16.h>
#include <math.h>

#define EMBED 512
#define HEADS 8
#define HD    64
#define FFN_  2048
#define NB    4
#define LSEQ  2048
#define MROWS (NB*LSEQ)    // 8192
#define BHN   (NB*HEADS)   // 32

typedef __attribute__((ext_vector_type(8))) short bf16x8;
typedef __attribute__((ext_vector_type(4))) float f32x4;
#define MFMA16(a,b,c) __builtin_amdgcn_mfma_f32_16x16x32_bf16(a,b,c,0,0,0)

__device__ __forceinline__ unsigned short f2bf(float f) {
    unsigned int u = __float_as_uint(f);
    u += 0x7fff + ((u >> 16) & 1);          // round-to-nearest-even
    return (unsigned short)(u >> 16);
}
__device__ __forceinline__ unsigned int cvt_pk_bf16(float lo, float hi) {
    unsigned int r;
    asm("v_cvt_pk_bf16_f32 %0, %1, %2" : "=v"(r) : "v"(lo), "v"(hi));
    return r;
}
__device__ __forceinline__ void gl_lds16(const unsigned short* g, unsigned short* l) {
    __builtin_amdgcn_global_load_lds(
        (const __attribute__((address_space(1))) unsigned int*)g,
        (__attribute__((address_space(3))) unsigned int*)l, 16, 0, 0);
}
__device__ __forceinline__ float gelu_f(float v) {
    return 0.5f * v * (1.0f + erff(v * 0.70710678118654752f));
}

// ---------------- prep kernels ----------------

__global__ __launch_bounds__(256) void cvt_bf16(const float* __restrict__ in,
                                                unsigned short* __restrict__ out, int n) {
    int i = (blockIdx.x * 256 + threadIdx.x) * 8;
    if (i >= n) return;
    float4 a = *reinterpret_cast<const float4*>(&in[i]);
    float4 b = *reinterpret_cast<const float4*>(&in[i + 4]);
    unsigned short t[8] = {f2bf(a.x), f2bf(a.y), f2bf(a.z), f2bf(a.w),
                           f2bf(b.x), f2bf(b.y), f2bf(b.z), f2bf(b.w)};
    *reinterpret_cast<uint4*>(&out[i]) = *reinterpret_cast<uint4*>(t);
}

// fp32 W[K][N] -> bf16 WT[N][K].  grid (N/32, K/32), block 256.
__global__ __launch_bounds__(256) void wtrans(const float* __restrict__ in,
                                              unsigned short* __restrict__ out,
                                              int K, int N) {
    __shared__ float tile[32][33];
    const int k0 = blockIdx.y * 32, n0 = blockIdx.x * 32;
    const int t = threadIdx.x;
    const int r = t >> 3, c = (t & 7) * 4;
    float4 v = *reinterpret_cast<const float4*>(&in[(size_t)(k0 + r) * N + n0 + c]);
    tile[r][c] = v.x; tile[r][c + 1] = v.y; tile[r][c + 2] = v.z; tile[r][c + 3] = v.w;
    __syncthreads();
    unsigned short tmp[4] = {f2bf(tile[c + 0][r]), f2bf(tile[c + 1][r]),
                             f2bf(tile[c + 2][r]), f2bf(tile[c + 3][r])};
    *reinterpret_cast<uint2*>(&out[(size_t)(n0 + r) * K + k0 + c]) =
        *reinterpret_cast<uint2*>(tmp);
}

// v bf16 [BH][L][HD] -> vTp [BH][HD][L], key-permuted within each 64-tile:
// vTp[bh][d][tile*64 + kap] = v[bh][tile*64 + (kap&3)*16 + (kap>>2)][d]
__global__ __launch_bounds__(256) void vtransp(const unsigned short* __restrict__ v,
                                               unsigned short* __restrict__ vT) {
    __shared__ unsigned short tile[64][72];
    const int bh = blockIdx.y, l0 = blockIdx.x * 64;
    const int t = threadIdx.x;
    #pragma unroll
    for (int u = 0; u < 2; ++u) {
        int id = t + u * 256; int r = id >> 3, c = (id & 7) * 8;
        *reinterpret_cast<uint4*>(&tile[r][c]) = *reinterpret_cast<const uint4*>(
            &v[((size_t)bh * LSEQ + l0 + r) * HD + c]);
    }
    __syncthreads();
    #pragma unroll
    for (int u = 0; u < 2; ++u) {
        int id = t + u * 256; int d = id >> 3, kc = (id & 7) * 8;
        unsigned short tmp[8];
        #pragma unroll
        for (int jj = 0; jj < 8; ++jj) {
            int kap = kc + jj;
            tmp[jj] = tile[(kap & 3) * 16 + (kap >> 2)][d];
        }
        *reinterpret_cast<uint4*>(&vT[((size_t)bh * HD + d) * LSEQ + l0 + kc]) =
            *reinterpret_cast<uint4*>(tmp);
    }
}

// ---------------- bf16 MFMA GEMM, 128x128 tile (m97 structure) ----
// MODE 0: scatter to q/k/v head-major bf16 (o0,o1,o2)
// MODE 2: bf16 out = gelu(val)
template<int MODE>
__global__ __launch_bounds__(256) void gemm_bf16(
    const unsigned short* __restrict__ A, const unsigned short* __restrict__ WT,
    const float* __restrict__ bias, const float* __restrict__ res,
    void* __restrict__ o0, void* __restrict__ o1, void* __restrict__ o2,
    int M, int N, int K)
{
    __shared__ unsigned short As[128 * 64];
    __shared__ unsigned short Bs[128 * 64];
    const int t = threadIdx.x;
    const int m0 = blockIdx.y * 128, n0 = blockIdx.x * 128;
    const int w = t >> 6, lane = t & 63;
    const int wm = (w >> 1) * 64, wn = (w & 1) * 64;
    const int lr = lane & 15, lk = (lane >> 4) * 8;
    const int rb = (lane >> 4) * 4;
    const int srow = lane >> 3, scol = (lane & 7) * 8;

    f32x4 zero = {0.f, 0.f, 0.f, 0.f};
    f32x4 acc[4][4];
    #pragma unroll
    for (int i = 0; i < 4; ++i)
        #pragma unroll
        for (int j = 0; j < 4; ++j) acc[i][j] = zero;

    for (int k0 = 0; k0 < K; k0 += 64) {
        __syncthreads();                      // previous tile's reads complete
        #pragma unroll
        for (int i = 0; i < 4; ++i) {
            const int seg = w * 4 + i;        // 0..15, 8 rows each
            const int r = seg * 8 + srow;
            gl_lds16(A  + (size_t)(m0 + r) * K + k0 + scol, &As[seg * 512 + lane * 8]);
            gl_lds16(WT + (size_t)(n0 + r) * K + k0 + scol, &Bs[seg * 512 + lane * 8]);
        }
        __syncthreads();                      // vmcnt drained -> LDS valid
        #pragma unroll
        for (int kk = 0; kk < 2; ++kk) {
            bf16x8 a[4], b[4];
            #pragma unroll
            for (int i = 0; i < 4; ++i)
                a[i] = *reinterpret_cast<const bf16x8*>(&As[(wm + i * 16 + lr) * 64 + kk * 32 + lk]);
            #pragma unroll
            for (int j = 0; j < 4; ++j)
                b[j] = *reinterpret_cast<const bf16x8*>(&Bs[(wn + j * 16 + lr) * 64 + kk * 32 + lk]);
            #pragma unroll
            for (int i = 0; i < 4; ++i)
                #pragma unroll
                for (int j = 0; j < 4; ++j)
                    acc[i][j] = MFMA16(a[i], b[j], acc[i][j]);
        }
    }

    #pragma unroll
    for (int i = 0; i < 4; ++i) {
        #pragma unroll
        for (int j = 0; j < 4; ++j) {
            const int n = n0 + wn + j * 16 + lr;
            const float bv = bias[n];
            #pragma unroll
            for (int r = 0; r < 4; ++r) {
                const int m = m0 + wm + i * 16 + rb + r;
                float val = acc[i][j][r] + bv;
                if (MODE == 0) {
                    const int which = n >> 9, nn = n & 511, hs = nn >> 6, d = nn & 63;
                    const int bh = (m >> 11) * 8 + hs, l = m & 2047;
                    unsigned short* p = (which == 0) ? (unsigned short*)o0
                                      : (which == 1) ? (unsigned short*)o1
                                                     : (unsigned short*)o2;
                    p[((size_t)bh * LSEQ + l) * HD + d] = f2bf(val);
                } else {
                    size_t idx = (size_t)m * N + n;
                    ((unsigned short*)o0)[idx] = f2bf(gelu_f(val));
                }
            }
        }
    }
}

// ---------------- bf16 MFMA GEMM, 64x64 tile, fp32 out = val+bias+res ----
// For small-N GEMMs (N=512): grid (N/64, M/64) = 1024 blocks -> 4+ blocks/CU.
__global__ __launch_bounds__(256) void gemm64(
    const unsigned short* __restrict__ A, const unsigned short* __restrict__ WT,
    const float* __restrict__ bias, const float* __restrict__ res,
    float* __restrict__ out, int M, int N, int K)
{
    __shared__ unsigned short As[64 * 64];
    __shared__ unsigned short Bs[64 * 64];
    const int t = threadIdx.x;
    const int m0 = blockIdx.y * 64, n0 = blockIdx.x * 64;
    const int w = t >> 6, lane = t & 63;
    const int wm = (w >> 1) * 32, wn = (w & 1) * 32;
    const int lr = lane & 15, lk = (lane >> 4) * 8;
    const int rb = (lane >> 4) * 4;
    const int srow = t >> 3, scol = (t & 7) * 8;   // 32 rows per issue

    f32x4 zero = {0.f, 0.f, 0.f, 0.f};
    f32x4 acc[2][2];
    #pragma unroll
    for (int i = 0; i < 2; ++i)
        #pragma unroll
        for (int j = 0; j < 2; ++j) acc[i][j] = zero;

    for (int k0 = 0; k0 < K; k0 += 64) {
        __syncthreads();
        gl_lds16(A  + (size_t)(m0 + srow)      * K + k0 + scol, &As[t * 8]);
        gl_lds16(A  + (size_t)(m0 + 32 + srow) * K + k0 + scol, &As[2048 + t * 8]);
        gl_lds16(WT + (size_t)(n0 + srow)      * K + k0 + scol, &Bs[t * 8]);
        gl_lds16(WT + (size_t)(n0 + 32 + srow) * K + k0 + scol, &Bs[2048 + t * 8]);
        __syncthreads();
        #pragma unroll
        for (int kk = 0; kk < 2; ++kk) {
            bf16x8 a[2], b[2];
            #pragma unroll
            for (int i = 0; i < 2; ++i)
                a[i] = *reinterpret_cast<const bf16x8*>(&As[(wm + i * 16 + lr) * 64 + kk * 32 + lk]);
            #pragma unroll
            for (int j = 0; j < 2; ++j)
                b[j] = *reinterpret_cast<const bf16x8*>(&Bs[(wn + j * 16 + lr) * 64 + kk * 32 + lk]);
            #pragma unroll
            for (int i = 0; i < 2; ++i)
                #pragma unroll
                for (int j = 0; j < 2; ++j)
                    acc[i][j] = MFMA16(a[i], b[j], acc[i][j]);
        }
    }

    #pragma unroll
    for (int i = 0; i < 2; ++i) {
        #pragma unroll
        for (int j = 0; j < 2; ++j) {
            const int n = n0 + wn + j * 16 + lr;
            const float bv = bias[n];
            #pragma unroll
            for (int r = 0; r < 4; ++r) {
                const int m = m0 + wm + i * 16 + rb + r;
                size_t idx = (size_t)m * N + n;
                out[idx] = acc[i][j][r] + bv + res[idx];
            }
        }
    }
}

// ---------------- MFMA flash attention (fixed-max softmax, MFMA row-sums) -------
// grid (BHN, LSEQ/64), block 256 (4 waves, 16 q-rows each).
__global__ __launch_bounds__(256) void attn_mfma(
    const unsigned short* __restrict__ Q, const unsigned short* __restrict__ K,
    const unsigned short* __restrict__ VTp, const int* __restrict__ mask,
    unsigned short* __restrict__ out)
{
    __shared__ unsigned short Qs[64][72];   // reused as Ps after qf extraction
    __shared__ unsigned short Ks[64][72];
    __shared__ unsigned short Vs[64][72];   // permuted-transposed V tile: [d][kap]
    __shared__ float kbl[64];
    unsigned short (*Ps)[72] = Qs;

    const int bh = blockIdx.x, qt = blockIdx.y;
    const int b = bh >> 3, hh = bh & 7;
    const int t = threadIdx.x, w = t >> 6, lane = t & 63;
    const int lr = lane & 15, lk = (lane >> 4) * 8;
    const int rb = (lane >> 4) * 4;
    const int qr0 = qt * 64;
    const int c = qr0 >> 9;
    const int kstart = max(0, (c - 1) * 512), kend = min(LSEQ, (c + 2) * 512);

    const float C1  = 0.18033688f;   // 0.125 * log2(e)
    const float KB0 = -14.4269504f;  // -MFIX(=10) * log2(e)

    #pragma unroll
    for (int u = 0; u < 2; ++u) {
        int id = t + u * 256; int r = id >> 3, kc = (id & 7) * 8;
        *reinterpret_cast<uint4*>(&Qs[r][kc]) = *reinterpret_cast<const uint4*>(
            &Q[((size_t)bh * LSEQ + qr0 + r) * HD + kc]);
    }
    __syncthreads();
    bf16x8 qf[2];
    qf[0] = *reinterpret_cast<const bf16x8*>(&Qs[w * 16 + lr][lk]);
    qf[1] = *reinterpret_cast<const bf16x8*>(&Qs[w * 16 + lr][32 + lk]);
    bf16x8 vone;
    #pragma unroll
    for (int i = 0; i < 8; ++i) vone[i] = (short)0x3f80;   // bf16 1.0

    f32x4 zero = {0.f, 0.f, 0.f, 0.f};
    f32x4 acc[4], accl = zero;
    #pragma unroll
    for (int j = 0; j < 4; ++j) acc[j] = zero;

    for (int kg = kstart; kg < kend; kg += 64) {
        __syncthreads();   // prior PV reads of Ks/Vs/Ps done; qf reads done (1st iter)
        #pragma unroll
        for (int u = 0; u < 2; ++u) {
            int id = t + u * 256; int r = id >> 3, kc = (id & 7) * 8;
            *reinterpret_cast<uint4*>(&Ks[r][kc]) = *reinterpret_cast<const uint4*>(
                &K[((size_t)bh * LSEQ + kg + r) * HD + kc]);
            *reinterpret_cast<uint4*>(&Vs[r][kc]) = *reinterpret_cast<const uint4*>(
                &VTp[((size_t)bh * HD + r) * LSEQ + kg + kc]);
        }
        if (t < 64) kbl[t] = mask[b * LSEQ + kg + t] ? -1e30f : KB0;
        __syncthreads();

        // S = Q K^T
        f32x4 s[4];
        #pragma unroll
        for (int j = 0; j < 4; ++j) s[j] = zero;
        #pragma unroll
        for (int kk = 0; kk < 2; ++kk) {
            #pragma unroll
            for (int j = 0; j < 4; ++j) {
                bf16x8 bk = *reinterpret_cast<const bf16x8*>(&Ks[j * 16 + lr][kk * 32 + lk]);
                s[j] = MFMA16(qf[kk], bk, s[j]);
            }
        }
        // fixed-max softmax: p = exp2(s*C1 + kbl[key]); write permuted-contiguous
        #pragma unroll
        for (int r = 0; r < 4; ++r) {
            float p0 = __builtin_amdgcn_exp2f(fmaf(s[0][r], C1, kbl[0 * 16 + lr]));
            float p1 = __builtin_amdgcn_exp2f(fmaf(s[1][r], C1, kbl[1 * 16 + lr]));
            float p2 = __builtin_amdgcn_exp2f(fmaf(s[2][r], C1, kbl[2 * 16 + lr]));
            float p3 = __builtin_amdgcn_exp2f(fmaf(s[3][r], C1, kbl[3 * 16 + lr]));
            uint2 pw;
            pw.x = cvt_pk_bf16(p0, p1);   // kap = 4*lr + {0,1}
            pw.y = cvt_pk_bf16(p2, p3);   // kap = 4*lr + {2,3}
            *reinterpret_cast<uint2*>(&Ps[w * 16 + rb + r][lr * 4]) = pw;
        }
        // O += P V ; l += P @ ones  (Ps rows are wave-private: no barrier needed)
        #pragma unroll
        for (int kk = 0; kk < 2; ++kk) {
            bf16x8 pa = *reinterpret_cast<const bf16x8*>(&Ps[w * 16 + lr][kk * 32 + lk]);
            #pragma unroll
            for (int j = 0; j < 4; ++j) {
                bf16x8 bv = *reinterpret_cast<const bf16x8*>(&Vs[j * 16 + lr][kk * 32 + lk]);
                acc[j] = MFMA16(pa, bv, acc[j]);
            }
            accl = MFMA16(pa, vone, accl);
        }
    }

    float linv[4];
    #pragma unroll
    for (int r = 0; r < 4; ++r) linv[r] = 1.0f / accl[r];
    #pragma unroll
    for (int j = 0; j < 4; ++j) {
        #pragma unroll
        for (int r = 0; r < 4; ++r) {
            const int l = qr0 + w * 16 + rb + r;
            const int d = j * 16 + lr;
            out[((size_t)(b * LSEQ + l)) * EMBED + hh * HD + d] = f2bf(acc[j][r] * linv[r]);
        }
    }
}

// ---------------- layernorm ----------------
template<int DUAL>
__global__ __launch_bounds__(256) void ln_kernel(
    const float* __restrict__ in, const float* __restrict__ g,
    const float* __restrict__ bt, float* __restrict__ outf,
    unsigned short* __restrict__ outb)
{
    const int row = blockIdx.x;
    const int t = threadIdx.x;
    const float* x = in + (size_t)row * EMBED;
    float2 v = *reinterpret_cast<const float2*>(&x[t * 2]);
    float s = v.x + v.y, ss = v.x * v.x + v.y * v.y;
    #pragma unroll
    for (int off = 1; off < 64; off <<= 1) {
        s  += __shfl_xor(s, off);
        ss += __shfl_xor(ss, off);
    }
    __shared__ float red[8];
    const int w = t >> 6;
    if ((t & 63) == 0) { red[w * 2] = s; red[w * 2 + 1] = ss; }
    __syncthreads();
    s  = red[0] + red[2] + red[4] + red[6];
    ss = red[1] + red[3] + red[5] + red[7];
    const float mu = s * (1.0f / EMBED);
    const float var = ss * (1.0f / EMBED) - mu * mu;
    const float rs = rsqrtf(var + 1e-5f);
    float2 gg = *reinterpret_cast<const float2*>(&g[t * 2]);
    float2 bb = *reinterpret_cast<const float2*>(&bt[t * 2]);
    float ox = (v.x - mu) * rs * gg.x + bb.x;
    float oy = (v.y - mu) * rs * gg.y + bb.y;
    *reinterpret_cast<float2*>(&outf[(size_t)row * EMBED + t * 2]) = make_float2(ox, oy);
    if (DUAL) {
        unsigned short tmp[2] = {f2bf(ox), f2bf(oy)};
        *reinterpret_cast<unsigned int*>(&outb[(size_t)row * EMBED + t * 2]) =
            *reinterpret_cast<unsigned int*>(tmp);
    }
}

extern "C" void kernel_launch(void* const* d_in, const int* in_sizes, int n_in,
                              void* d_out, int out_size, void* d_ws, size_t ws_size,
                              hipStream_t stream) {
    const float* x      = (const float*)d_in[0];
    const int*   mask   = (const int*)  d_in[1];
    const float* qkv_w  = (const float*)d_in[2];
    const float* qkv_b  = (const float*)d_in[3];
    const float* out_w  = (const float*)d_in[4];
    const float* out_b  = (const float*)d_in[5];
    const float* ffn_w1 = (const float*)d_in[6];
    const float* ffn_b1 = (const float*)d_in[7];
    const float* ffn_w2 = (const float*)d_in[8];
    const float* ffn_b2 = (const float*)d_in[9];
    const float* ln1_g  = (const float*)d_in[10];
    const float* ln1_b  = (const float*)d_in[11];
    const float* ln2_g  = (const float*)d_in[12];
    const float* ln2_b  = (const float*)d_in[13];

    char* wsb = (char*)d_ws;
    unsigned short* qkv_wT = (unsigned short*)(wsb + 0);          // 1.5 MB
    unsigned short* out_wT = (unsigned short*)(wsb + 1572864);    // 0.5 MB
    unsigned short* w1T    = (unsigned short*)(wsb + 2097152);    // 2 MB
    unsigned short* w2T    = (unsigned short*)(wsb + 4194304);    // 2 MB
    unsigned short* xb     = (unsigned short*)(wsb + 6291456);    // A: 8 MB
    unsigned short* qb     = (unsigned short*)(wsb + 14680064);   // B: 8 MB
    unsigned short* kbuf   = (unsigned short*)(wsb + 23068672);   // C: 8 MB
    unsigned short* vb     = (unsigned short*)(wsb + 31457280);   // D: 8 MB
    float*          y      = (float*)(wsb + 39845888);            // E: 16 MB
    unsigned short* vTp    = xb;     // A reused (xb dead after QKV gemm)
    unsigned short* am     = vb;     // D reused (v row-major dead after vtransp)
    unsigned short* xlnb   = xb;     // A reused (vTp dead after attn)
    float*          xlnf   = (float*)(wsb + 14680064);            // B+C reused, 16 MB
    unsigned short* h      = (unsigned short*)(wsb + 31457280);   // D+E: 32 MB
    float*          z      = (float*)(wsb + 65011712);            // 16 MB

    // prep
    cvt_bf16<<<MROWS * EMBED / 8 / 256, 256, 0, stream>>>(x, xb, MROWS * EMBED);
    wtrans<<<dim3(1536 / 32, 512 / 32),  256, 0, stream>>>(qkv_w,  qkv_wT, 512, 1536);
    wtrans<<<dim3(512 / 32,  512 / 32),  256, 0, stream>>>(out_w,  out_wT, 512, 512);
    wtrans<<<dim3(2048 / 32, 512 / 32),  256, 0, stream>>>(ffn_w1, w1T,    512, 2048);
    wtrans<<<dim3(512 / 32,  2048 / 32), 256, 0, stream>>>(ffn_w2, w2T,    2048, 512);

    // 1) QKV projection -> q,k,v head-major bf16
    gemm_bf16<0><<<dim3(1536 / 128, MROWS / 128), 256, 0, stream>>>(
        xb, qkv_wT, qkv_b, nullptr, qb, kbuf, vb, MROWS, 1536, 512);
    // 2) V transpose+permute per head
    vtransp<<<dim3(LSEQ / 64, BHN), 256, 0, stream>>>(vb, vTp);
    // 3) attention -> am (merged bf16)
    attn_mfma<<<dim3(BHN, LSEQ / 64), 256, 0, stream>>>(qb, kbuf, vTp, mask, am);
    // 4) out projection + residual(x) -> y fp32   (64x64 tiles: 1024 blocks)
    gemm64<<<dim3(EMBED / 64, MROWS / 64), 256, 0, stream>>>(
        am, out_wT, out_b, x, y, MROWS, EMBED, 512);
    // 5) LN1 -> xlnf + xlnb
    ln_kernel<1><<<MROWS, 256, 0, stream>>>(y, ln1_g, ln1_b, xlnf, xlnb);
    // 6) FFN1 + GELU -> h bf16
    gemm_bf16<2><<<dim3(FFN_ / 128, MROWS / 128), 256, 0, stream>>>(
        xlnb, w1T, ffn_b1, nullptr, h, nullptr, nullptr, MROWS, FFN_, 512);
    // 7) FFN2 + residual(xlnf) -> z fp32   (64x64 tiles: 1024 blocks)
    gemm64<<<dim3(EMBED / 64, MROWS / 64), 256, 0, stream>>>(
        h, w2T, ffn_b2, xlnf, z, MROWS, EMBED, FFN_);
    // 8) LN2 -> out
    ln_kernel<0><<<MROWS, 256, 0, stream>>>(z, ln2_g, ln2_b, (float*)d_out, nullptr);
}

// Round 5
// 286.094 us; speedup vs baseline: 5.6569x; 1.0351x over previous
//
#include <hip/hip_runtime.h>
#include <hip/hip_bf16.h>
#include <math.h>

#define EMBED 512
#define HEADS 8
#define HD    64
#define FFN_  2048
#define NB    4
#define LSEQ  2048
#define MROWS (NB*LSEQ)    // 8192
#define BHN   (NB*HEADS)   // 32

typedef __attribute__((ext_vector_type(8))) short bf16x8;
typedef __attribute__((ext_vector_type(4))) float f32x4;
#define MFMA16(a,b,c) __builtin_amdgcn_mfma_f32_16x16x32_bf16(a,b,c,0,0,0)

__device__ __forceinline__ unsigned short f2bf(float f) {
    unsigned int u = __float_as_uint(f);
    u += 0x7fff + ((u >> 16) & 1);          // round-to-nearest-even
    return (unsigned short)(u >> 16);
}
__device__ __forceinline__ float bf2f(unsigned short u) {
    return __uint_as_float(((unsigned int)u) << 16);
}
__device__ __forceinline__ unsigned int cvt_pk_bf16(float lo, float hi) {
    unsigned int r;
    asm("v_cvt_pk_bf16_f32 %0, %1, %2" : "=v"(r) : "v"(lo), "v"(hi));
    return r;
}
__device__ __forceinline__ void gl_lds16(const unsigned short* g, unsigned short* l) {
    __builtin_amdgcn_global_load_lds(
        (const __attribute__((address_space(1))) unsigned int*)g,
        (__attribute__((address_space(3))) unsigned int*)l, 16, 0, 0);
}
// fast tanh-gelu: 0.5x(1+tanh(0.79788456(x+0.044715x^3))) = x*t/(t+1), t=e^{2u}
__device__ __forceinline__ float gelu_f(float x) {
    float u = x * fmaf(x * x, 0.044715f, 1.0f) * 0.7978845608f;
    float a = fminf(fmaxf(u * 2.885390082f, -30.f), 30.f);   // 2*log2e*u
    float t = __builtin_amdgcn_exp2f(a);
    return x * t * __builtin_amdgcn_rcpf(t + 1.0f);
}
// bijective XCD swizzle (nwg % 8 == 0 everywhere here)
__device__ __forceinline__ void xcd_swz(int& bx, int& by, int gx, int gy) {
    int nwg = gx * gy;
    int lid = by * gx + bx;
    int cpx = nwg >> 3;
    int swz = (lid & 7) * cpx + (lid >> 3);
    bx = swz % gx;
    by = swz / gx;
}

// ---------------- prep kernels ----------------

__global__ __launch_bounds__(256) void cvt_bf16(const float* __restrict__ in,
                                                unsigned short* __restrict__ out, int n) {
    int i = (blockIdx.x * 256 + threadIdx.x) * 8;
    if (i >= n) return;
    float4 a = *reinterpret_cast<const float4*>(&in[i]);
    float4 b = *reinterpret_cast<const float4*>(&in[i + 4]);
    unsigned short t[8] = {f2bf(a.x), f2bf(a.y), f2bf(a.z), f2bf(a.w),
                           f2bf(b.x), f2bf(b.y), f2bf(b.z), f2bf(b.w)};
    *reinterpret_cast<uint4*>(&out[i]) = *reinterpret_cast<uint4*>(t);
}

// fp32 W[K][N] -> bf16 WT[N][K].  grid (N/32, K/32), block 256.
__global__ __launch_bounds__(256) void wtrans(const float* __restrict__ in,
                                              unsigned short* __restrict__ out,
                                              int K, int N) {
    __shared__ float tile[32][33];
    const int k0 = blockIdx.y * 32, n0 = blockIdx.x * 32;
    const int t = threadIdx.x;
    const int r = t >> 3, c = (t & 7) * 4;
    float4 v = *reinterpret_cast<const float4*>(&in[(size_t)(k0 + r) * N + n0 + c]);
    tile[r][c] = v.x; tile[r][c + 1] = v.y; tile[r][c + 2] = v.z; tile[r][c + 3] = v.w;
    __syncthreads();
    unsigned short tmp[4] = {f2bf(tile[c + 0][r]), f2bf(tile[c + 1][r]),
                             f2bf(tile[c + 2][r]), f2bf(tile[c + 3][r])};
    *reinterpret_cast<uint2*>(&out[(size_t)(n0 + r) * K + k0 + c]) =
        *reinterpret_cast<uint2*>(tmp);
}

// v bf16 [BH][L][HD] -> vTp [BH][HD][L], key-permuted within each 64-tile:
// vTp[bh][d][tile*64 + kap] = v[bh][tile*64 + (kap&3)*16 + (kap>>2)][d]
__global__ __launch_bounds__(256) void vtransp(const unsigned short* __restrict__ v,
                                               unsigned short* __restrict__ vT) {
    __shared__ unsigned short tile[64][72];
    const int bh = blockIdx.y, l0 = blockIdx.x * 64;
    const int t = threadIdx.x;
    #pragma unroll
    for (int u = 0; u < 2; ++u) {
        int id = t + u * 256; int r = id >> 3, c = (id & 7) * 8;
        *reinterpret_cast<uint4*>(&tile[r][c]) = *reinterpret_cast<const uint4*>(
            &v[((size_t)bh * LSEQ + l0 + r) * HD + c]);
    }
    __syncthreads();
    #pragma unroll
    for (int u = 0; u < 2; ++u) {
        int id = t + u * 256; int d = id >> 3, kc = (id & 7) * 8;
        unsigned short tmp[8];
        #pragma unroll
        for (int jj = 0; jj < 8; ++jj) {
            int kap = kc + jj;
            tmp[jj] = tile[(kap & 3) * 16 + (kap >> 2)][d];
        }
        *reinterpret_cast<uint4*>(&vT[((size_t)bh * HD + d) * LSEQ + l0 + kc]) =
            *reinterpret_cast<uint4*>(tmp);
    }
}

// ---------------- bf16 MFMA GEMM, 128x128 tile (m97 structure + XCD swizzle) ----
// MODE 0: scatter to q/k/v head-major bf16 (o0,o1,o2)
// MODE 2: bf16 out = gelu(val)
template<int MODE>
__global__ __launch_bounds__(256) void gemm_bf16(
    const unsigned short* __restrict__ A, const unsigned short* __restrict__ WT,
    const float* __restrict__ bias,
    void* __restrict__ o0, void* __restrict__ o1, void* __restrict__ o2,
    int M, int N, int K)
{
    __shared__ unsigned short As[128 * 64];
    __shared__ unsigned short Bs[128 * 64];
    int bx = blockIdx.x, by = blockIdx.y;
    xcd_swz(bx, by, gridDim.x, gridDim.y);
    const int t = threadIdx.x;
    const int m0 = by * 128, n0 = bx * 128;
    const int w = t >> 6, lane = t & 63;
    const int wm = (w >> 1) * 64, wn = (w & 1) * 64;
    const int lr = lane & 15, lk = (lane >> 4) * 8;
    const int rb = (lane >> 4) * 4;
    const int srow = lane >> 3, scol = (lane & 7) * 8;

    f32x4 zero = {0.f, 0.f, 0.f, 0.f};
    f32x4 acc[4][4];
    #pragma unroll
    for (int i = 0; i < 4; ++i)
        #pragma unroll
        for (int j = 0; j < 4; ++j) acc[i][j] = zero;

    for (int k0 = 0; k0 < K; k0 += 64) {
        __syncthreads();
        #pragma unroll
        for (int i = 0; i < 4; ++i) {
            const int seg = w * 4 + i;        // 0..15, 8 rows each
            const int r = seg * 8 + srow;
            gl_lds16(A  + (size_t)(m0 + r) * K + k0 + scol, &As[seg * 512 + lane * 8]);
            gl_lds16(WT + (size_t)(n0 + r) * K + k0 + scol, &Bs[seg * 512 + lane * 8]);
        }
        __syncthreads();
        #pragma unroll
        for (int kk = 0; kk < 2; ++kk) {
            bf16x8 a[4], b[4];
            #pragma unroll
            for (int i = 0; i < 4; ++i)
                a[i] = *reinterpret_cast<const bf16x8*>(&As[(wm + i * 16 + lr) * 64 + kk * 32 + lk]);
            #pragma unroll
            for (int j = 0; j < 4; ++j)
                b[j] = *reinterpret_cast<const bf16x8*>(&Bs[(wn + j * 16 + lr) * 64 + kk * 32 + lk]);
            #pragma unroll
            for (int i = 0; i < 4; ++i)
                #pragma unroll
                for (int j = 0; j < 4; ++j)
                    acc[i][j] = MFMA16(a[i], b[j], acc[i][j]);
        }
    }

    #pragma unroll
    for (int i = 0; i < 4; ++i) {
        #pragma unroll
        for (int j = 0; j < 4; ++j) {
            const int n = n0 + wn + j * 16 + lr;
            const float bv = bias[n];
            #pragma unroll
            for (int r = 0; r < 4; ++r) {
                const int m = m0 + wm + i * 16 + rb + r;
                float val = acc[i][j][r] + bv;
                if (MODE == 0) {
                    const int which = n >> 9, nn = n & 511, hs = nn >> 6, d = nn & 63;
                    const int bh = (m >> 11) * 8 + hs, l = m & 2047;
                    unsigned short* p = (which == 0) ? (unsigned short*)o0
                                      : (which == 1) ? (unsigned short*)o1
                                                     : (unsigned short*)o2;
                    p[((size_t)bh * LSEQ + l) * HD + d] = f2bf(val);
                } else {
                    size_t idx = (size_t)m * N + n;
                    ((unsigned short*)o0)[idx] = f2bf(gelu_f(val));
                }
            }
        }
    }
}

// ---------------- bf16 MFMA GEMM, 64x64 tile, for N=512 GEMMs ----
// MODE 0: res fp32, out bf16          (out-proj + residual x)
// MODE 1: res bf16, out fp32          (FFN2 + residual xln)
template<int MODE>
__global__ __launch_bounds__(256) void gemm64(
    const unsigned short* __restrict__ A, const unsigned short* __restrict__ WT,
    const float* __restrict__ bias, const void* __restrict__ res,
    void* __restrict__ out, int M, int N, int K)
{
    __shared__ unsigned short As[64 * 64];
    __shared__ unsigned short Bs[64 * 64];
    int bx = blockIdx.x, by = blockIdx.y;
    xcd_swz(bx, by, gridDim.x, gridDim.y);
    const int t = threadIdx.x;
    const int m0 = by * 64, n0 = bx * 64;
    const int w = t >> 6, lane = t & 63;
    const int wm = (w >> 1) * 32, wn = (w & 1) * 32;
    const int lr = lane & 15, lk = (lane >> 4) * 8;
    const int rb = (lane >> 4) * 4;
    const int srow = t >> 3, scol = (t & 7) * 8;   // 32 rows per issue

    f32x4 zero = {0.f, 0.f, 0.f, 0.f};
    f32x4 acc[2][2];
    #pragma unroll
    for (int i = 0; i < 2; ++i)
        #pragma unroll
        for (int j = 0; j < 2; ++j) acc[i][j] = zero;

    for (int k0 = 0; k0 < K; k0 += 64) {
        __syncthreads();
        gl_lds16(A  + (size_t)(m0 + srow)      * K + k0 + scol, &As[t * 8]);
        gl_lds16(A  + (size_t)(m0 + 32 + srow) * K + k0 + scol, &As[2048 + t * 8]);
        gl_lds16(WT + (size_t)(n0 + srow)      * K + k0 + scol, &Bs[t * 8]);
        gl_lds16(WT + (size_t)(n0 + 32 + srow) * K + k0 + scol, &Bs[2048 + t * 8]);
        __syncthreads();
        #pragma unroll
        for (int kk = 0; kk < 2; ++kk) {
            bf16x8 a[2], b[2];
            #pragma unroll
            for (int i = 0; i < 2; ++i)
                a[i] = *reinterpret_cast<const bf16x8*>(&As[(wm + i * 16 + lr) * 64 + kk * 32 + lk]);
            #pragma unroll
            for (int j = 0; j < 2; ++j)
                b[j] = *reinterpret_cast<const bf16x8*>(&Bs[(wn + j * 16 + lr) * 64 + kk * 32 + lk]);
            #pragma unroll
            for (int i = 0; i < 2; ++i)
                #pragma unroll
                for (int j = 0; j < 2; ++j)
                    acc[i][j] = MFMA16(a[i], b[j], acc[i][j]);
        }
    }

    #pragma unroll
    for (int i = 0; i < 2; ++i) {
        #pragma unroll
        for (int j = 0; j < 2; ++j) {
            const int n = n0 + wn + j * 16 + lr;
            const float bv = bias[n];
            #pragma unroll
            for (int r = 0; r < 4; ++r) {
                const int m = m0 + wm + i * 16 + rb + r;
                size_t idx = (size_t)m * N + n;
                float val = acc[i][j][r] + bv;
                if (MODE == 0) {
                    val += ((const float*)res)[idx];
                    ((unsigned short*)out)[idx] = f2bf(val);
                } else {
                    val += bf2f(((const unsigned short*)res)[idx]);
                    ((float*)out)[idx] = val;
                }
            }
        }
    }
}

// ---------------- MFMA flash attention: 128 q-rows/block, 32 rows/wave ----------
// grid (LSEQ/128, BHN), block 256 (4 waves).
__global__ __launch_bounds__(256) void attn_mfma(
    const unsigned short* __restrict__ Q, const unsigned short* __restrict__ K,
    const unsigned short* __restrict__ VTp, const int* __restrict__ mask,
    unsigned short* __restrict__ out)
{
    __shared__ unsigned short Ks[64][72];
    __shared__ unsigned short Vs[64][72];   // permuted-transposed V tile: [d][kap]
    __shared__ unsigned short Ps[128][72];
    __shared__ float kbl[64];

    int bx = blockIdx.x, by = blockIdx.y;
    xcd_swz(bx, by, 16, 32);
    const int qt = bx, bh = by;
    const int b = bh >> 3, hh = bh & 7;
    const int t = threadIdx.x, w = t >> 6, lane = t & 63;
    const int lr = lane & 15, hi = lane >> 4;
    const int lk = hi * 8, rb = hi * 4;
    const int qr0 = qt * 128;
    const int c = qr0 >> 9;
    const int kstart = max(0, (c - 1) * 512), kend = min(LSEQ, (c + 2) * 512);

    const float C1  = 0.18033688f;   // 0.125 * log2(e)
    const float KB0 = -14.4269504f;  // -MFIX(=10) * log2(e)

    // Q fragments straight from global (L2-resident)
    bf16x8 qf[2][2];
    #pragma unroll
    for (int fi = 0; fi < 2; ++fi)
        #pragma unroll
        for (int kk = 0; kk < 2; ++kk)
            qf[fi][kk] = *reinterpret_cast<const bf16x8*>(
                &Q[((size_t)bh * LSEQ + qr0 + w * 32 + fi * 16 + lr) * HD + kk * 32 + lk]);

    f32x4 zero = {0.f, 0.f, 0.f, 0.f};
    f32x4 acc[2][4];
    float lsum[2][4];
    #pragma unroll
    for (int fi = 0; fi < 2; ++fi) {
        #pragma unroll
        for (int j = 0; j < 4; ++j) acc[fi][j] = zero;
        #pragma unroll
        for (int r = 0; r < 4; ++r) lsum[fi][r] = 0.f;
    }

    for (int kg = kstart; kg < kend; kg += 64) {
        __syncthreads();   // prior tile's Ks/Vs reads done
        #pragma unroll
        for (int u = 0; u < 2; ++u) {
            int id = t + u * 256; int r = id >> 3, kc = (id & 7) * 8;
            *reinterpret_cast<uint4*>(&Ks[r][kc]) = *reinterpret_cast<const uint4*>(
                &K[((size_t)bh * LSEQ + kg + r) * HD + kc]);
            *reinterpret_cast<uint4*>(&Vs[r][kc]) = *reinterpret_cast<const uint4*>(
                &VTp[((size_t)bh * HD + r) * LSEQ + kg + kc]);
        }
        if (t < 64) kbl[t] = mask[b * LSEQ + kg + t] ? -1e30f : KB0;
        __syncthreads();

        // S = Q K^T  (two 16-row fragments share each K fragment read)
        f32x4 s[2][4];
        #pragma unroll
        for (int fi = 0; fi < 2; ++fi)
            #pragma unroll
            for (int j = 0; j < 4; ++j) s[fi][j] = zero;
        #pragma unroll
        for (int kk = 0; kk < 2; ++kk) {
            #pragma unroll
            for (int j = 0; j < 4; ++j) {
                bf16x8 bk = *reinterpret_cast<const bf16x8*>(&Ks[j * 16 + lr][kk * 32 + lk]);
                s[0][j] = MFMA16(qf[0][kk], bk, s[0][j]);
                s[1][j] = MFMA16(qf[1][kk], bk, s[1][j]);
            }
        }
        // fixed-max softmax, permuted-contiguous P writes, per-lane partial sums
        #pragma unroll
        for (int fi = 0; fi < 2; ++fi) {
            #pragma unroll
            for (int r = 0; r < 4; ++r) {
                float p0 = __builtin_amdgcn_exp2f(fmaf(s[fi][0][r], C1, kbl[0 * 16 + lr]));
                float p1 = __builtin_amdgcn_exp2f(fmaf(s[fi][1][r], C1, kbl[1 * 16 + lr]));
                float p2 = __builtin_amdgcn_exp2f(fmaf(s[fi][2][r], C1, kbl[2 * 16 + lr]));
                float p3 = __builtin_amdgcn_exp2f(fmaf(s[fi][3][r], C1, kbl[3 * 16 + lr]));
                lsum[fi][r] += (p0 + p1) + (p2 + p3);
                uint2 pw;
                pw.x = cvt_pk_bf16(p0, p1);   // kap = 4*lr + {0,1}
                pw.y = cvt_pk_bf16(p2, p3);   // kap = 4*lr + {2,3}
                *reinterpret_cast<uint2*>(&Ps[w * 32 + fi * 16 + rb + r][lr * 4]) = pw;
            }
        }
        // O += P V  (Ps rows are wave-private; in-wave LDS ordering suffices)
        #pragma unroll
        for (int kk = 0; kk < 2; ++kk) {
            bf16x8 pa0 = *reinterpret_cast<const bf16x8*>(&Ps[w * 32 + lr][kk * 32 + lk]);
            bf16x8 pa1 = *reinterpret_cast<const bf16x8*>(&Ps[w * 32 + 16 + lr][kk * 32 + lk]);
            #pragma unroll
            for (int j = 0; j < 4; ++j) {
                bf16x8 bv = *reinterpret_cast<const bf16x8*>(&Vs[j * 16 + lr][kk * 32 + lk]);
                acc[0][j] = MFMA16(pa0, bv, acc[0][j]);
                acc[1][j] = MFMA16(pa1, bv, acc[1][j]);
            }
        }
    }

    // row-sum reduce across the 16 lanes sharing a row group
    float linv[2][4];
    #pragma unroll
    for (int fi = 0; fi < 2; ++fi)
        #pragma unroll
        for (int r = 0; r < 4; ++r) {
            float v = lsum[fi][r];
            v += __shfl_xor(v, 1, 16);
            v += __shfl_xor(v, 2, 16);
            v += __shfl_xor(v, 4, 16);
            v += __shfl_xor(v, 8, 16);
            linv[fi][r] = 1.0f / v;
        }
    #pragma unroll
    for (int fi = 0; fi < 2; ++fi)
        #pragma unroll
        for (int j = 0; j < 4; ++j)
            #pragma unroll
            for (int r = 0; r < 4; ++r) {
                const int l = qr0 + w * 32 + fi * 16 + rb + r;
                const int d = j * 16 + lr;
                out[((size_t)(b * LSEQ + l)) * EMBED + hh * HD + d] =
                    f2bf(acc[fi][j][r] * linv[fi][r]);
            }
}

// ---------------- layernorm, one wave per row ----------------
// bf16 in -> bf16 out (LN1) ; grid MROWS/4, block 256
__global__ __launch_bounds__(256) void ln_b2b(
    const unsigned short* __restrict__ in, const float* __restrict__ g,
    const float* __restrict__ bt, unsigned short* __restrict__ out)
{
    const int t = threadIdx.x, lane = t & 63;
    const int row = blockIdx.x * 4 + (t >> 6);
    uint4 raw = *reinterpret_cast<const uint4*>(&in[(size_t)row * EMBED + lane * 8]);
    float v[8];
    const unsigned int* rw = reinterpret_cast<const unsigned int*>(&raw);
    #pragma unroll
    for (int i = 0; i < 4; ++i) {
        v[2 * i]     = __uint_as_float(rw[i] << 16);
        v[2 * i + 1] = __uint_as_float(rw[i] & 0xffff0000u);
    }
    float s = 0.f, ss = 0.f;
    #pragma unroll
    for (int i = 0; i < 8; ++i) { s += v[i]; ss += v[i] * v[i]; }
    #pragma unroll
    for (int off = 1; off < 64; off <<= 1) {
        s  += __shfl_xor(s, off);
        ss += __shfl_xor(ss, off);
    }
    const float mu = s * (1.0f / EMBED);
    const float var = ss * (1.0f / EMBED) - mu * mu;
    const float rs = rsqrtf(var + 1e-5f);
    float4 g0 = *reinterpret_cast<const float4*>(&g[lane * 8]);
    float4 g1 = *reinterpret_cast<const float4*>(&g[lane * 8 + 4]);
    float4 b0 = *reinterpret_cast<const float4*>(&bt[lane * 8]);
    float4 b1 = *reinterpret_cast<const float4*>(&bt[lane * 8 + 4]);
    float gg[8] = {g0.x, g0.y, g0.z, g0.w, g1.x, g1.y, g1.z, g1.w};
    float bb[8] = {b0.x, b0.y, b0.z, b0.w, b1.x, b1.y, b1.z, b1.w};
    unsigned short o[8];
    #pragma unroll
    for (int i = 0; i < 8; ++i) o[i] = f2bf((v[i] - mu) * rs * gg[i] + bb[i]);
    *reinterpret_cast<uint4*>(&out[(size_t)row * EMBED + lane * 8]) =
        *reinterpret_cast<uint4*>(o);
}

// fp32 in -> fp32 out (LN2 -> d_out) ; grid MROWS/4, block 256
__global__ __launch_bounds__(256) void ln_f2f(
    const float* __restrict__ in, const float* __restrict__ g,
    const float* __restrict__ bt, float* __restrict__ out)
{
    const int t = threadIdx.x, lane = t & 63;
    const int row = blockIdx.x * 4 + (t >> 6);
    const float* x = in + (size_t)row * EMBED + lane * 8;
    float4 a = *reinterpret_cast<const float4*>(x);
    float4 b2 = *reinterpret_cast<const float4*>(x + 4);
    float v[8] = {a.x, a.y, a.z, a.w, b2.x, b2.y, b2.z, b2.w};
    float s = 0.f, ss = 0.f;
    #pragma unroll
    for (int i = 0; i < 8; ++i) { s += v[i]; ss += v[i] * v[i]; }
    #pragma unroll
    for (int off = 1; off < 64; off <<= 1) {
        s  += __shfl_xor(s, off);
        ss += __shfl_xor(ss, off);
    }
    const float mu = s * (1.0f / EMBED);
    const float var = ss * (1.0f / EMBED) - mu * mu;
    const float rs = rsqrtf(var + 1e-5f);
    float4 g0 = *reinterpret_cast<const float4*>(&g[lane * 8]);
    float4 g1 = *reinterpret_cast<const float4*>(&g[lane * 8 + 4]);
    float4 b0 = *reinterpret_cast<const float4*>(&bt[lane * 8]);
    float4 b1 = *reinterpret_cast<const float4*>(&bt[lane * 8 + 4]);
    float gg[8] = {g0.x, g0.y, g0.z, g0.w, g1.x, g1.y, g1.z, g1.w};
    float bb[8] = {b0.x, b0.y, b0.z, b0.w, b1.x, b1.y, b1.z, b1.w};
    float o[8];
    #pragma unroll
    for (int i = 0; i < 8; ++i) o[i] = (v[i] - mu) * rs * gg[i] + bb[i];
    float* op = out + (size_t)row * EMBED + lane * 8;
    *reinterpret_cast<float4*>(op)     = make_float4(o[0], o[1], o[2], o[3]);
    *reinterpret_cast<float4*>(op + 4) = make_float4(o[4], o[5], o[6], o[7]);
}

extern "C" void kernel_launch(void* const* d_in, const int* in_sizes, int n_in,
                              void* d_out, int out_size, void* d_ws, size_t ws_size,
                              hipStream_t stream) {
    const float* x      = (const float*)d_in[0];
    const int*   mask   = (const int*)  d_in[1];
    const float* qkv_w  = (const float*)d_in[2];
    const float* qkv_b  = (const float*)d_in[3];
    const float* out_w  = (const float*)d_in[4];
    const float* out_b  = (const float*)d_in[5];
    const float* ffn_w1 = (const float*)d_in[6];
    const float* ffn_b1 = (const float*)d_in[7];
    const float* ffn_w2 = (const float*)d_in[8];
    const float* ffn_b2 = (const float*)d_in[9];
    const float* ln1_g  = (const float*)d_in[10];
    const float* ln1_b  = (const float*)d_in[11];
    const float* ln2_g  = (const float*)d_in[12];
    const float* ln2_b  = (const float*)d_in[13];

    char* wsb = (char*)d_ws;
    unsigned short* qkv_wT = (unsigned short*)(wsb + 0);          // 1.5 MB
    unsigned short* out_wT = (unsigned short*)(wsb + 1572864);    // 0.5 MB
    unsigned short* w1T    = (unsigned short*)(wsb + 2097152);    // 2 MB
    unsigned short* w2T    = (unsigned short*)(wsb + 4194304);    // 2 MB
    unsigned short* xb     = (unsigned short*)(wsb + 6291456);    // A: 8 MB
    unsigned short* qb     = (unsigned short*)(wsb + 14680064);   // B: 8 MB
    unsigned short* kbuf   = (unsigned short*)(wsb + 23068672);   // C: 8 MB
    unsigned short* vb     = (unsigned short*)(wsb + 31457280);   // D: 8 MB
    unsigned short* y      = (unsigned short*)(wsb + 39845888);   // E: 8 MB (bf16)
    unsigned short* vTp    = xb;     // A reused (xb dead after QKV gemm)
    unsigned short* am     = vb;     // D reused (v row-major dead after vtransp)
    unsigned short* xlnb   = xb;     // A reused (vTp dead after attn)
    unsigned short* h      = (unsigned short*)(wsb + 31457280);   // D+E: 32 MB (y dead post-LN1)
    float*          z      = (float*)(wsb + 65011712);            // 16 MB

    // prep
    cvt_bf16<<<MROWS * EMBED / 8 / 256, 256, 0, stream>>>(x, xb, MROWS * EMBED);
    wtrans<<<dim3(1536 / 32, 512 / 32),  256, 0, stream>>>(qkv_w,  qkv_wT, 512, 1536);
    wtrans<<<dim3(512 / 32,  512 / 32),  256, 0, stream>>>(out_w,  out_wT, 512, 512);
    wtrans<<<dim3(2048 / 32, 512 / 32),  256, 0, stream>>>(ffn_w1, w1T,    512, 2048);
    wtrans<<<dim3(512 / 32,  2048 / 32), 256, 0, stream>>>(ffn_w2, w2T,    2048, 512);

    // 1) QKV projection -> q,k,v head-major bf16
    gemm_bf16<0><<<dim3(1536 / 128, MROWS / 128), 256, 0, stream>>>(
        xb, qkv_wT, qkv_b, qb, kbuf, vb, MROWS, 1536, 512);
    // 2) V transpose+permute per head
    vtransp<<<dim3(LSEQ / 64, BHN), 256, 0, stream>>>(vb, vTp);
    // 3) attention -> am (merged bf16)
    attn_mfma<<<dim3(LSEQ / 128, BHN), 256, 0, stream>>>(qb, kbuf, vTp, mask, am);
    // 4) out projection + residual(x fp32) -> y bf16
    gemm64<0><<<dim3(EMBED / 64, MROWS / 64), 256, 0, stream>>>(
        am, out_wT, out_b, x, y, MROWS, EMBED, 512);
    // 5) LN1 -> xlnb bf16
    ln_b2b<<<MROWS / 4, 256, 0, stream>>>(y, ln1_g, ln1_b, xlnb);
    // 6) FFN1 + GELU -> h bf16
    gemm_bf16<2><<<dim3(FFN_ / 128, MROWS / 128), 256, 0, stream>>>(
        xlnb, w1T, ffn_b1, h, nullptr, nullptr, MROWS, FFN_, 512);
    // 7) FFN2 + residual(xlnb bf16) -> z fp32
    gemm64<1><<<dim3(EMBED / 64, MROWS / 64), 256, 0, stream>>>(
        h, w2T, ffn_b2, xlnb, z, MROWS, EMBED, FFN_);
    // 8) LN2 -> out fp32
    ln_f2f<<<MROWS / 4, 256, 0, stream>>>(z, ln2_g, ln2_b, (float*)d_out);
}

// Round 6
// 276.078 us; speedup vs baseline: 5.8622x; 1.0363x over previous
//
#include <hip/hip_runtime.h>
#include <hip/hip_bf16.h>
#include <math.h>

#define EMBED 512
#define HEADS 8
#define HD    64
#define FFN_  2048
#define NB    4
#define LSEQ  2048
#define MROWS (NB*LSEQ)    // 8192
#define BHN   (NB*HEADS)   // 32

typedef __attribute__((ext_vector_type(8))) short bf16x8;
typedef __attribute__((ext_vector_type(4))) float f32x4;
#define MFMA16(a,b,c) __builtin_amdgcn_mfma_f32_16x16x32_bf16(a,b,c,0,0,0)

__device__ __forceinline__ unsigned short f2bf(float f) {
    unsigned int u = __float_as_uint(f);
    u += 0x7fff + ((u >> 16) & 1);          // round-to-nearest-even
    return (unsigned short)(u >> 16);
}
__device__ __forceinline__ float bf2f(unsigned short u) {
    return __uint_as_float(((unsigned int)u) << 16);
}
__device__ __forceinline__ unsigned int cvt_pk_bf16(float lo, float hi) {
    unsigned int r;
    asm("v_cvt_pk_bf16_f32 %0, %1, %2" : "=v"(r) : "v"(lo), "v"(hi));
    return r;
}
__device__ __forceinline__ void gl_lds16(const unsigned short* g, unsigned short* l) {
    __builtin_amdgcn_global_load_lds(
        (const __attribute__((address_space(1))) unsigned int*)g,
        (__attribute__((address_space(3))) unsigned int*)l, 16, 0, 0);
}
// fast tanh-gelu
__device__ __forceinline__ float gelu_f(float x) {
    float u = x * fmaf(x * x, 0.044715f, 1.0f) * 0.7978845608f;
    float a = fminf(fmaxf(u * 2.885390082f, -30.f), 30.f);   // 2*log2e*u
    float t = __builtin_amdgcn_exp2f(a);
    return x * t * __builtin_amdgcn_rcpf(t + 1.0f);
}
// bijective XCD swizzle (nwg % 8 == 0 everywhere here)
__device__ __forceinline__ void xcd_swz(int& bx, int& by, int gx, int gy) {
    int nwg = gx * gy;
    int lid = by * gx + bx;
    int cpx = nwg >> 3;
    int swz = (lid & 7) * cpx + (lid >> 3);
    bx = swz % gx;
    by = swz / gx;
}

// ---------------- prep kernels ----------------

__global__ __launch_bounds__(256) void cvt_bf16(const float* __restrict__ in,
                                                unsigned short* __restrict__ out, int n) {
    int i = (blockIdx.x * 256 + threadIdx.x) * 8;
    if (i >= n) return;
    float4 a = *reinterpret_cast<const float4*>(&in[i]);
    float4 b = *reinterpret_cast<const float4*>(&in[i + 4]);
    unsigned short t[8] = {f2bf(a.x), f2bf(a.y), f2bf(a.z), f2bf(a.w),
                           f2bf(b.x), f2bf(b.y), f2bf(b.z), f2bf(b.w)};
    *reinterpret_cast<uint4*>(&out[i]) = *reinterpret_cast<uint4*>(t);
}

// fp32 W[K][N] -> bf16 WT[N][K].  grid (N/32, K/32), block 256.
__global__ __launch_bounds__(256) void wtrans(const float* __restrict__ in,
                                              unsigned short* __restrict__ out,
                                              int K, int N) {
    __shared__ float tile[32][33];
    const int k0 = blockIdx.y * 32, n0 = blockIdx.x * 32;
    const int t = threadIdx.x;
    const int r = t >> 3, c = (t & 7) * 4;
    float4 v = *reinterpret_cast<const float4*>(&in[(size_t)(k0 + r) * N + n0 + c]);
    tile[r][c] = v.x; tile[r][c + 1] = v.y; tile[r][c + 2] = v.z; tile[r][c + 3] = v.w;
    __syncthreads();
    unsigned short tmp[4] = {f2bf(tile[c + 0][r]), f2bf(tile[c + 1][r]),
                             f2bf(tile[c + 2][r]), f2bf(tile[c + 3][r])};
    *reinterpret_cast<uint2*>(&out[(size_t)(n0 + r) * K + k0 + c]) =
        *reinterpret_cast<uint2*>(tmp);
}

// v bf16 [BH][L][HD] -> vTp [BH][HD][L], key-permuted within each 64-tile:
// vTp[bh][d][tile*64 + kap] = v[bh][tile*64 + (kap&3)*16 + (kap>>2)][d]
__global__ __launch_bounds__(256) void vtransp(const unsigned short* __restrict__ v,
                                               unsigned short* __restrict__ vT) {
    __shared__ unsigned short tile[64][72];
    const int bh = blockIdx.y, l0 = blockIdx.x * 64;
    const int t = threadIdx.x;
    #pragma unroll
    for (int u = 0; u < 2; ++u) {
        int id = t + u * 256; int r = id >> 3, c = (id & 7) * 8;
        *reinterpret_cast<uint4*>(&tile[r][c]) = *reinterpret_cast<const uint4*>(
            &v[((size_t)bh * LSEQ + l0 + r) * HD + c]);
    }
    __syncthreads();
    #pragma unroll
    for (int u = 0; u < 2; ++u) {
        int id = t + u * 256; int d = id >> 3, kc = (id & 7) * 8;
        unsigned short tmp[8];
        #pragma unroll
        for (int jj = 0; jj < 8; ++jj) {
            int kap = kc + jj;
            tmp[jj] = tile[(kap & 3) * 16 + (kap >> 2)][d];
        }
        *reinterpret_cast<uint4*>(&vT[((size_t)bh * HD + d) * LSEQ + l0 + kc]) =
            *reinterpret_cast<uint4*>(tmp);
    }
}

// ---------------- bf16 MFMA GEMM, 128x128 tile, double-buffered counted-vmcnt ----
// MODE 0: scatter to q/k/v head-major bf16 (o0,o1,o2)
// MODE 2: bf16 out = gelu(val)
template<int MODE>
__global__ __launch_bounds__(256) void gemm_bf16(
    const unsigned short* __restrict__ A, const unsigned short* __restrict__ WT,
    const float* __restrict__ bias,
    void* __restrict__ o0, void* __restrict__ o1, void* __restrict__ o2,
    int M, int N, int K)
{
    __shared__ unsigned short As[2][128 * 64];
    __shared__ unsigned short Bs[2][128 * 64];
    int bx = blockIdx.x, by = blockIdx.y;
    xcd_swz(bx, by, gridDim.x, gridDim.y);
    const int t = threadIdx.x;
    const int m0 = by * 128, n0 = bx * 128;
    const int w = t >> 6, lane = t & 63;
    const int wm = (w >> 1) * 64, wn = (w & 1) * 64;
    const int lr = lane & 15, lk = (lane >> 4) * 8;
    const int rb = (lane >> 4) * 4;
    const int srow = lane >> 3, scol = (lane & 7) * 8;

    f32x4 zero = {0.f, 0.f, 0.f, 0.f};
    f32x4 acc[4][4];
    #pragma unroll
    for (int i = 0; i < 4; ++i)
        #pragma unroll
        for (int j = 0; j < 4; ++j) acc[i][j] = zero;

    // stage one 128x64 A-tile + B-tile into buffer buf (8 issues/thread)
    auto stage = [&](int buf, int k0) {
        #pragma unroll
        for (int i = 0; i < 4; ++i) {
            const int seg = w * 4 + i;        // 0..15, 8 rows each
            const int r = seg * 8 + srow;
            gl_lds16(A  + (size_t)(m0 + r) * K + k0 + scol, &As[buf][seg * 512 + lane * 8]);
            gl_lds16(WT + (size_t)(n0 + r) * K + k0 + scol, &Bs[buf][seg * 512 + lane * 8]);
        }
    };

    const int nk = K >> 6;
    stage(0, 0);
    for (int ti = 0; ti < nk; ++ti) {
        if (ti + 1 < nk) {
            stage((ti + 1) & 1, (ti + 1) << 6);
            asm volatile("s_waitcnt vmcnt(8)" ::: "memory");   // tile ti landed
        } else {
            asm volatile("s_waitcnt vmcnt(0)" ::: "memory");
        }
        __builtin_amdgcn_s_barrier();
        const unsigned short* as = As[ti & 1];
        const unsigned short* bs = Bs[ti & 1];
        #pragma unroll
        for (int kk = 0; kk < 2; ++kk) {
            bf16x8 a[4], b[4];
            #pragma unroll
            for (int i = 0; i < 4; ++i)
                a[i] = *reinterpret_cast<const bf16x8*>(&as[(wm + i * 16 + lr) * 64 + kk * 32 + lk]);
            #pragma unroll
            for (int j = 0; j < 4; ++j)
                b[j] = *reinterpret_cast<const bf16x8*>(&bs[(wn + j * 16 + lr) * 64 + kk * 32 + lk]);
            #pragma unroll
            for (int i = 0; i < 4; ++i)
                #pragma unroll
                for (int j = 0; j < 4; ++j)
                    acc[i][j] = MFMA16(a[i], b[j], acc[i][j]);
        }
        __builtin_amdgcn_s_barrier();
    }

    #pragma unroll
    for (int i = 0; i < 4; ++i) {
        #pragma unroll
        for (int j = 0; j < 4; ++j) {
            const int n = n0 + wn + j * 16 + lr;
            const float bv = bias[n];
            #pragma unroll
            for (int r = 0; r < 4; ++r) {
                const int m = m0 + wm + i * 16 + rb + r;
                float val = acc[i][j][r] + bv;
                if (MODE == 0) {
                    const int which = n >> 9, nn = n & 511, hs = nn >> 6, d = nn & 63;
                    const int bh = (m >> 11) * 8 + hs, l = m & 2047;
                    unsigned short* p = (which == 0) ? (unsigned short*)o0
                                      : (which == 1) ? (unsigned short*)o1
                                                     : (unsigned short*)o2;
                    p[((size_t)bh * LSEQ + l) * HD + d] = f2bf(val);
                } else {
                    size_t idx = (size_t)m * N + n;
                    ((unsigned short*)o0)[idx] = f2bf(gelu_f(val));
                }
            }
        }
    }
}

// ---------------- bf16 MFMA GEMM, 64x64 tile, dbuf, for N=512 GEMMs ----
// MODE 0: res fp32, out bf16          (out-proj + residual x)
// MODE 1: res bf16, out fp32          (FFN2 + residual xln)
template<int MODE>
__global__ __launch_bounds__(256) void gemm64(
    const unsigned short* __restrict__ A, const unsigned short* __restrict__ WT,
    const float* __restrict__ bias, const void* __restrict__ res,
    void* __restrict__ out, int M, int N, int K)
{
    __shared__ unsigned short As[2][64 * 64];
    __shared__ unsigned short Bs[2][64 * 64];
    int bx = blockIdx.x, by = blockIdx.y;
    xcd_swz(bx, by, gridDim.x, gridDim.y);
    const int t = threadIdx.x;
    const int m0 = by * 64, n0 = bx * 64;
    const int w = t >> 6, lane = t & 63;
    const int wm = (w >> 1) * 32, wn = (w & 1) * 32;
    const int lr = lane & 15, lk = (lane >> 4) * 8;
    const int rb = (lane >> 4) * 4;
    const int srow = t >> 3, scol = (t & 7) * 8;   // 32 rows per issue

    f32x4 zero = {0.f, 0.f, 0.f, 0.f};
    f32x4 acc[2][2];
    #pragma unroll
    for (int i = 0; i < 2; ++i)
        #pragma unroll
        for (int j = 0; j < 2; ++j) acc[i][j] = zero;

    auto stage = [&](int buf, int k0) {
        gl_lds16(A  + (size_t)(m0 + srow)      * K + k0 + scol, &As[buf][t * 8]);
        gl_lds16(A  + (size_t)(m0 + 32 + srow) * K + k0 + scol, &As[buf][2048 + t * 8]);
        gl_lds16(WT + (size_t)(n0 + srow)      * K + k0 + scol, &Bs[buf][t * 8]);
        gl_lds16(WT + (size_t)(n0 + 32 + srow) * K + k0 + scol, &Bs[buf][2048 + t * 8]);
    };

    const int nk = K >> 6;
    stage(0, 0);
    for (int ti = 0; ti < nk; ++ti) {
        if (ti + 1 < nk) {
            stage((ti + 1) & 1, (ti + 1) << 6);
            asm volatile("s_waitcnt vmcnt(4)" ::: "memory");
        } else {
            asm volatile("s_waitcnt vmcnt(0)" ::: "memory");
        }
        __builtin_amdgcn_s_barrier();
        const unsigned short* as = As[ti & 1];
        const unsigned short* bs = Bs[ti & 1];
        #pragma unroll
        for (int kk = 0; kk < 2; ++kk) {
            bf16x8 a[2], b[2];
            #pragma unroll
            for (int i = 0; i < 2; ++i)
                a[i] = *reinterpret_cast<const bf16x8*>(&as[(wm + i * 16 + lr) * 64 + kk * 32 + lk]);
            #pragma unroll
            for (int j = 0; j < 2; ++j)
                b[j] = *reinterpret_cast<const bf16x8*>(&bs[(wn + j * 16 + lr) * 64 + kk * 32 + lk]);
            #pragma unroll
            for (int i = 0; i < 2; ++i)
                #pragma unroll
                for (int j = 0; j < 2; ++j)
                    acc[i][j] = MFMA16(a[i], b[j], acc[i][j]);
        }
        __builtin_amdgcn_s_barrier();
    }

    #pragma unroll
    for (int i = 0; i < 2; ++i) {
        #pragma unroll
        for (int j = 0; j < 2; ++j) {
            const int n = n0 + wn + j * 16 + lr;
            const float bv = bias[n];
            #pragma unroll
            for (int r = 0; r < 4; ++r) {
                const int m = m0 + wm + i * 16 + rb + r;
                size_t idx = (size_t)m * N + n;
                float val = acc[i][j][r] + bv;
                if (MODE == 0) {
                    val += ((const float*)res)[idx];
                    ((unsigned short*)out)[idx] = f2bf(val);
                } else {
                    val += bf2f(((const unsigned short*)res)[idx]);
                    ((float*)out)[idx] = val;
                }
            }
        }
    }
}

// ---------------- MFMA flash attention: 128 q-rows/block, 8 waves x 16 rows ----
// grid (LSEQ/128, BHN), block 512.
__global__ __launch_bounds__(512) void attn_mfma(
    const unsigned short* __restrict__ Q, const unsigned short* __restrict__ K,
    const unsigned short* __restrict__ VTp, const int* __restrict__ mask,
    unsigned short* __restrict__ out)
{
    __shared__ unsigned short Ks[64][72];
    __shared__ unsigned short Vs[64][72];   // permuted-transposed V tile: [d][kap]
    __shared__ unsigned short Ps[128][72];
    __shared__ float kbl[64];

    int bx = blockIdx.x, by = blockIdx.y;
    xcd_swz(bx, by, 16, 32);
    const int qt = bx, bh = by;
    const int b = bh >> 3, hh = bh & 7;
    const int t = threadIdx.x, w = t >> 6, lane = t & 63;
    const int lr = lane & 15, hi = lane >> 4;
    const int lk = hi * 8, rb = hi * 4;
    const int qr0 = qt * 128;
    const int c = qr0 >> 9;
    const int kstart = max(0, (c - 1) * 512), kend = min(LSEQ, (c + 2) * 512);

    const float C1  = 0.18033688f;   // 0.125 * log2(e)
    const float KB0 = -14.4269504f;  // -MFIX(=10) * log2(e)

    // Q fragments straight from global (L2-resident); wave owns rows qr0+w*16..+15
    bf16x8 qf[2];
    #pragma unroll
    for (int kk = 0; kk < 2; ++kk)
        qf[kk] = *reinterpret_cast<const bf16x8*>(
            &Q[((size_t)bh * LSEQ + qr0 + w * 16 + lr) * HD + kk * 32 + lk]);

    f32x4 zero = {0.f, 0.f, 0.f, 0.f};
    f32x4 acc[4];
    float lsum[4] = {0.f, 0.f, 0.f, 0.f};
    #pragma unroll
    for (int j = 0; j < 4; ++j) acc[j] = zero;

    for (int kg = kstart; kg < kend; kg += 64) {
        __syncthreads();   // prior tile's Ks/Vs reads done
        {
            int r = t >> 3, kc = (t & 7) * 8;   // 512 threads: one uint4 each
            *reinterpret_cast<uint4*>(&Ks[r][kc]) = *reinterpret_cast<const uint4*>(
                &K[((size_t)bh * LSEQ + kg + r) * HD + kc]);
            *reinterpret_cast<uint4*>(&Vs[r][kc]) = *reinterpret_cast<const uint4*>(
                &VTp[((size_t)bh * HD + r) * LSEQ + kg + kc]);
            if (t < 64) kbl[t] = mask[b * LSEQ + kg + t] ? -1e30f : KB0;
        }
        __syncthreads();

        // S = Q K^T
        f32x4 s[4];
        #pragma unroll
        for (int j = 0; j < 4; ++j) s[j] = zero;
        #pragma unroll
        for (int kk = 0; kk < 2; ++kk) {
            #pragma unroll
            for (int j = 0; j < 4; ++j) {
                bf16x8 bk = *reinterpret_cast<const bf16x8*>(&Ks[j * 16 + lr][kk * 32 + lk]);
                s[j] = MFMA16(qf[kk], bk, s[j]);
            }
        }
        // fixed-max softmax, permuted-contiguous P writes, per-lane partial sums
        #pragma unroll
        for (int r = 0; r < 4; ++r) {
            float p0 = __builtin_amdgcn_exp2f(fmaf(s[0][r], C1, kbl[0 * 16 + lr]));
            float p1 = __builtin_amdgcn_exp2f(fmaf(s[1][r], C1, kbl[1 * 16 + lr]));
            float p2 = __builtin_amdgcn_exp2f(fmaf(s[2][r], C1, kbl[2 * 16 + lr]));
            float p3 = __builtin_amdgcn_exp2f(fmaf(s[3][r], C1, kbl[3 * 16 + lr]));
            lsum[r] += (p0 + p1) + (p2 + p3);
            uint2 pw;
            pw.x = cvt_pk_bf16(p0, p1);   // kap = 4*lr + {0,1}
            pw.y = cvt_pk_bf16(p2, p3);   // kap = 4*lr + {2,3}
            *reinterpret_cast<uint2*>(&Ps[w * 16 + rb + r][lr * 4]) = pw;
        }
        // O += P V  (Ps rows are wave-private; in-wave LDS ordering suffices)
        #pragma unroll
        for (int kk = 0; kk < 2; ++kk) {
            bf16x8 pa = *reinterpret_cast<const bf16x8*>(&Ps[w * 16 + lr][kk * 32 + lk]);
            #pragma unroll
            for (int j = 0; j < 4; ++j) {
                bf16x8 bv = *reinterpret_cast<const bf16x8*>(&Vs[j * 16 + lr][kk * 32 + lk]);
                acc[j] = MFMA16(pa, bv, acc[j]);
            }
        }
    }

    // row-sum reduce across the 16 lanes sharing a row group
    float linv[4];
    #pragma unroll
    for (int r = 0; r < 4; ++r) {
        float v = lsum[r];
        v += __shfl_xor(v, 1, 16);
        v += __shfl_xor(v, 2, 16);
        v += __shfl_xor(v, 4, 16);
        v += __shfl_xor(v, 8, 16);
        linv[r] = 1.0f / v;
    }
    #pragma unroll
    for (int j = 0; j < 4; ++j)
        #pragma unroll
        for (int r = 0; r < 4; ++r) {
            const int l = qr0 + w * 16 + rb + r;
            const int d = j * 16 + lr;
            out[((size_t)(b * LSEQ + l)) * EMBED + hh * HD + d] =
                f2bf(acc[j][r] * linv[r]);
        }
}

// ---------------- layernorm, one wave per row ----------------
// bf16 in -> bf16 out (LN1) ; grid MROWS/4, block 256
__global__ __launch_bounds__(256) void ln_b2b(
    const unsigned short* __restrict__ in, const float* __restrict__ g,
    const float* __restrict__ bt, unsigned short* __restrict__ out)
{
    const int t = threadIdx.x, lane = t & 63;
    const int row = blockIdx.x * 4 + (t >> 6);
    uint4 raw = *reinterpret_cast<const uint4*>(&in[(size_t)row * EMBED + lane * 8]);
    float v[8];
    const unsigned int* rw = reinterpret_cast<const unsigned int*>(&raw);
    #pragma unroll
    for (int i = 0; i < 4; ++i) {
        v[2 * i]     = __uint_as_float(rw[i] << 16);
        v[2 * i + 1] = __uint_as_float(rw[i] & 0xffff0000u);
    }
    float s = 0.f, ss = 0.f;
    #pragma unroll
    for (int i = 0; i < 8; ++i) { s += v[i]; ss += v[i] * v[i]; }
    #pragma unroll
    for (int off = 1; off < 64; off <<= 1) {
        s  += __shfl_xor(s, off);
        ss += __shfl_xor(ss, off);
    }
    const float mu = s * (1.0f / EMBED);
    const float var = ss * (1.0f / EMBED) - mu * mu;
    const float rs = rsqrtf(var + 1e-5f);
    float4 g0 = *reinterpret_cast<const float4*>(&g[lane * 8]);
    float4 g1 = *reinterpret_cast<const float4*>(&g[lane * 8 + 4]);
    float4 b0 = *reinterpret_cast<const float4*>(&bt[lane * 8]);
    float4 b1 = *reinterpret_cast<const float4*>(&bt[lane * 8 + 4]);
    float gg[8] = {g0.x, g0.y, g0.z, g0.w, g1.x, g1.y, g1.z, g1.w};
    float bb[8] = {b0.x, b0.y, b0.z, b0.w, b1.x, b1.y, b1.z, b1.w};
    unsigned short o[8];
    #pragma unroll
    for (int i = 0; i < 8; ++i) o[i] = f2bf((v[i] - mu) * rs * gg[i] + bb[i]);
    *reinterpret_cast<uint4*>(&out[(size_t)row * EMBED + lane * 8]) =
        *reinterpret_cast<uint4*>(o);
}

// fp32 in -> fp32 out (LN2 -> d_out) ; grid MROWS/4, block 256
__global__ __launch_bounds__(256) void ln_f2f(
    const float* __restrict__ in, const float* __restrict__ g,
    const float* __restrict__ bt, float* __restrict__ out)
{
    const int t = threadIdx.x, lane = t & 63;
    const int row = blockIdx.x * 4 + (t >> 6);
    const float* x = in + (size_t)row * EMBED + lane * 8;
    float4 a = *reinterpret_cast<const float4*>(x);
    float4 b2 = *reinterpret_cast<const float4*>(x + 4);
    float v[8] = {a.x, a.y, a.z, a.w, b2.x, b2.y, b2.z, b2.w};
    float s = 0.f, ss = 0.f;
    #pragma unroll
    for (int i = 0; i < 8; ++i) { s += v[i]; ss += v[i] * v[i]; }
    #pragma unroll
    for (int off = 1; off < 64; off <<= 1) {
        s  += __shfl_xor(s, off);
        ss += __shfl_xor(ss, off);
    }
    const float mu = s * (1.0f / EMBED);
    const float var = ss * (1.0f / EMBED) - mu * mu;
    const float rs = rsqrtf(var + 1e-5f);
    float4 g0 = *reinterpret_cast<const float4*>(&g[lane * 8]);
    float4 g1 = *reinterpret_cast<const float4*>(&g[lane * 8 + 4]);
    float4 b0 = *reinterpret_cast<const float4*>(&bt[lane * 8]);
    float4 b1 = *reinterpret_cast<const float4*>(&bt[lane * 8 + 4]);
    float gg[8] = {g0.x, g0.y, g0.z, g0.w, g1.x, g1.y, g1.z, g1.w};
    float bb[8] = {b0.x, b0.y, b0.z, b0.w, b1.x, b1.y, b1.z, b1.w};
    float o[8];
    #pragma unroll
    for (int i = 0; i < 8; ++i) o[i] = (v[i] - mu) * rs * gg[i] + bb[i];
    float* op = out + (size_t)row * EMBED + lane * 8;
    *reinterpret_cast<float4*>(op)     = make_float4(o[0], o[1], o[2], o[3]);
    *reinterpret_cast<float4*>(op + 4) = make_float4(o[4], o[5], o[6], o[7]);
}

extern "C" void kernel_launch(void* const* d_in, const int* in_sizes, int n_in,
                              void* d_out, int out_size, void* d_ws, size_t ws_size,
                              hipStream_t stream) {
    const float* x      = (const float*)d_in[0];
    const int*   mask   = (const int*)  d_in[1];
    const float* qkv_w  = (const float*)d_in[2];
    const float* qkv_b  = (const float*)d_in[3];
    const float* out_w  = (const float*)d_in[4];
    const float* out_b  = (const float*)d_in[5];
    const float* ffn_w1 = (const float*)d_in[6];
    const float* ffn_b1 = (const float*)d_in[7];
    const float* ffn_w2 = (const float*)d_in[8];
    const float* ffn_b2 = (const float*)d_in[9];
    const float* ln1_g  = (const float*)d_in[10];
    const float* ln1_b  = (const float*)d_in[11];
    const float* ln2_g  = (const float*)d_in[12];
    const float* ln2_b  = (const float*)d_in[13];

    char* wsb = (char*)d_ws;
    unsigned short* qkv_wT = (unsigned short*)(wsb + 0);          // 1.5 MB
    unsigned short* out_wT = (unsigned short*)(wsb + 1572864);    // 0.5 MB
    unsigned short* w1T    = (unsigned short*)(wsb + 2097152);    // 2 MB
    unsigned short* w2T    = (unsigned short*)(wsb + 4194304);    // 2 MB
    unsigned short* xb     = (unsigned short*)(wsb + 6291456);    // A: 8 MB
    unsigned short* qb     = (unsigned short*)(wsb + 14680064);   // B: 8 MB
    unsigned short* kbuf   = (unsigned short*)(wsb + 23068672);   // C: 8 MB
    unsigned short* vb     = (unsigned short*)(wsb + 31457280);   // D: 8 MB
    unsigned short* y      = (unsigned short*)(wsb + 39845888);   // E: 8 MB (bf16)
    unsigned short* vTp    = xb;     // A reused (xb dead after QKV gemm)
    unsigned short* am     = vb;     // D reused (v row-major dead after vtransp)
    unsigned short* xlnb   = xb;     // A reused (vTp dead after attn)
    unsigned short* h      = (unsigned short*)(wsb + 31457280);   // D+E: 32 MB (y dead post-LN1)
    float*          z      = (float*)(wsb + 65011712);            // 16 MB

    // prep
    cvt_bf16<<<MROWS * EMBED / 8 / 256, 256, 0, stream>>>(x, xb, MROWS * EMBED);
    wtrans<<<dim3(1536 / 32, 512 / 32),  256, 0, stream>>>(qkv_w,  qkv_wT, 512, 1536);
    wtrans<<<dim3(512 / 32,  512 / 32),  256, 0, stream>>>(out_w,  out_wT, 512, 512);
    wtrans<<<dim3(2048 / 32, 512 / 32),  256, 0, stream>>>(ffn_w1, w1T,    512, 2048);
    wtrans<<<dim3(512 / 32,  2048 / 32), 256, 0, stream>>>(ffn_w2, w2T,    2048, 512);

    // 1) QKV projection -> q,k,v head-major bf16
    gemm_bf16<0><<<dim3(1536 / 128, MROWS / 128), 256, 0, stream>>>(
        xb, qkv_wT, qkv_b, qb, kbuf, vb, MROWS, 1536, 512);
    // 2) V transpose+permute per head
    vtransp<<<dim3(LSEQ / 64, BHN), 256, 0, stream>>>(vb, vTp);
    // 3) attention -> am (merged bf16)
    attn_mfma<<<dim3(LSEQ / 128, BHN), 512, 0, stream>>>(qb, kbuf, vTp, mask, am);
    // 4) out projection + residual(x fp32) -> y bf16
    gemm64<0><<<dim3(EMBED / 64, MROWS / 64), 256, 0, stream>>>(
        am, out_wT, out_b, x, y, MROWS, EMBED, 512);
    // 5) LN1 -> xlnb bf16
    ln_b2b<<<MROWS / 4, 256, 0, stream>>>(y, ln1_g, ln1_b, xlnb);
    // 6) FFN1 + GELU -> h bf16
    gemm_bf16<2><<<dim3(FFN_ / 128, MROWS / 128), 256, 0, stream>>>(
        xlnb, w1T, ffn_b1, h, nullptr, nullptr, MROWS, FFN_, 512);
    // 7) FFN2 + residual(xlnb bf16) -> z fp32
    gemm64<1><<<dim3(EMBED / 64, MROWS / 64), 256, 0, stream>>>(
        h, w2T, ffn_b2, xlnb, z, MROWS, EMBED, FFN_);
    // 8) LN2 -> out fp32
    ln_f2f<<<MROWS / 4, 256, 0, stream>>>(z, ln2_g, ln2_b, (float*)d_out);
}

// Round 8
// 259.288 us; speedup vs baseline: 6.2418x; 1.0648x over previous
//
#include <hip/hip_runtime.h>
#include <hip/hip_bf16.h>
#include <math.h>

#define EMBED 512
#define HEADS 8
#define HD    64
#define FFN_  2048
#define NB    4
#define LSEQ  2048
#define MROWS (NB*LSEQ)    // 8192
#define BHN   (NB*HEADS)   // 32

typedef __attribute__((ext_vector_type(8))) short bf16x8;
typedef __attribute__((ext_vector_type(4))) float f32x4;
#define MFMA16(a,b,c) __builtin_amdgcn_mfma_f32_16x16x32_bf16(a,b,c,0,0,0)

__device__ __forceinline__ unsigned short f2bf(float f) {
    unsigned int u = __float_as_uint(f);
    u += 0x7fff + ((u >> 16) & 1);          // round-to-nearest-even
    return (unsigned short)(u >> 16);
}
__device__ __forceinline__ float bf2f(unsigned short u) {
    return __uint_as_float(((unsigned int)u) << 16);
}
__device__ __forceinline__ unsigned int cvt_pk_bf16(float lo, float hi) {
    unsigned int r;
    asm("v_cvt_pk_bf16_f32 %0, %1, %2" : "=v"(r) : "v"(lo), "v"(hi));
    return r;
}
__device__ __forceinline__ void gl_lds16(const unsigned short* g, unsigned short* l) {
    __builtin_amdgcn_global_load_lds(
        (const __attribute__((address_space(1))) unsigned int*)g,
        (__attribute__((address_space(3))) unsigned int*)l, 16, 0, 0);
}
// fast tanh-gelu
__device__ __forceinline__ float gelu_f(float x) {
    float u = x * fmaf(x * x, 0.044715f, 1.0f) * 0.7978845608f;
    float a = fminf(fmaxf(u * 2.885390082f, -30.f), 30.f);   // 2*log2e*u
    float t = __builtin_amdgcn_exp2f(a);
    return x * t * __builtin_amdgcn_rcpf(t + 1.0f);
}
// bijective XCD swizzle (nwg % 8 == 0 everywhere here)
__device__ __forceinline__ void xcd_swz(int& bx, int& by, int gx, int gy) {
    int nwg = gx * gy;
    int lid = by * gx + bx;
    int cpx = nwg >> 3;
    int swz = (lid & 7) * cpx + (lid >> 3);
    bx = swz % gx;
    by = swz / gx;
}

// ---------------- merged prep kernel ----------------
__device__ __forceinline__ void wtrans_body(const float* __restrict__ in,
                                            unsigned short* __restrict__ out,
                                            int K, int N, int bx, int by,
                                            float (*tile)[33]) {
    const int k0 = by * 32, n0 = bx * 32;
    const int t = threadIdx.x;
    const int r = t >> 3, c = (t & 7) * 4;
    float4 v = *reinterpret_cast<const float4*>(&in[(size_t)(k0 + r) * N + n0 + c]);
    tile[r][c] = v.x; tile[r][c + 1] = v.y; tile[r][c + 2] = v.z; tile[r][c + 3] = v.w;
    __syncthreads();
    unsigned short tmp[4] = {f2bf(tile[c + 0][r]), f2bf(tile[c + 1][r]),
                             f2bf(tile[c + 2][r]), f2bf(tile[c + 3][r])};
    *reinterpret_cast<uint2*>(&out[(size_t)(n0 + r) * K + k0 + c]) =
        *reinterpret_cast<uint2*>(tmp);
}

__global__ __launch_bounds__(256) void prep(
    const float* __restrict__ x, unsigned short* __restrict__ xb,
    const float* __restrict__ qkv_w, unsigned short* __restrict__ qkv_wT,
    const float* __restrict__ out_w, unsigned short* __restrict__ out_wT,
    const float* __restrict__ w1, unsigned short* __restrict__ w1T,
    const float* __restrict__ w2, unsigned short* __restrict__ w2T)
{
    __shared__ float tile[32][33];
    const int blk = blockIdx.x;
    if (blk < 2048) {
        int i = (blk * 256 + threadIdx.x) * 8;
        float4 a = *reinterpret_cast<const float4*>(&x[i]);
        float4 b = *reinterpret_cast<const float4*>(&x[i + 4]);
        unsigned short t8[8] = {f2bf(a.x), f2bf(a.y), f2bf(a.z), f2bf(a.w),
                                f2bf(b.x), f2bf(b.y), f2bf(b.z), f2bf(b.w)};
        *reinterpret_cast<uint4*>(&xb[i]) = *reinterpret_cast<uint4*>(t8);
    } else if (blk < 2816) {
        int i = blk - 2048; wtrans_body(qkv_w, qkv_wT, 512, 1536, i % 48, i / 48, tile);
    } else if (blk < 3072) {
        int i = blk - 2816; wtrans_body(out_w, out_wT, 512, 512, i % 16, i / 16, tile);
    } else if (blk < 4096) {
        int i = blk - 3072; wtrans_body(w1, w1T, 512, 2048, i % 64, i / 64, tile);
    } else {
        int i = blk - 4096; wtrans_body(w2, w2T, 2048, 512, i % 16, i / 16, tile);
    }
}

// v bf16 [BH][L][HD] -> vTp [BH][HD][L], pos-permuted within each 64-tile for
// the split-softmax P layout: pos' = kh*32+p  ->  src key = kh*32 + (p>>1) + (p&1)*16
__global__ __launch_bounds__(256) void vtransp(const unsigned short* __restrict__ v,
                                               unsigned short* __restrict__ vT) {
    __shared__ unsigned short tile[64][72];
    const int bh = blockIdx.y, l0 = blockIdx.x * 64;
    const int t = threadIdx.x;
    #pragma unroll
    for (int u = 0; u < 2; ++u) {
        int id = t + u * 256; int r = id >> 3, c = (id & 7) * 8;
        *reinterpret_cast<uint4*>(&tile[r][c]) = *reinterpret_cast<const uint4*>(
            &v[((size_t)bh * LSEQ + l0 + r) * HD + c]);
    }
    __syncthreads();
    #pragma unroll
    for (int u = 0; u < 2; ++u) {
        int id = t + u * 256; int d = id >> 3, kc = (id & 7) * 8;
        unsigned short tmp[8];
        #pragma unroll
        for (int jj = 0; jj < 8; ++jj) {
            int posp = kc + jj;
            int kh = posp >> 5, p = posp & 31;
            tmp[jj] = tile[kh * 32 + (p >> 1) + (p & 1) * 16][d];
        }
        *reinterpret_cast<uint4*>(&vT[((size_t)bh * HD + d) * LSEQ + l0 + kc]) =
            *reinterpret_cast<uint4*>(tmp);
    }
}

// ---------------- bf16 MFMA GEMM, 128x128 tile, dbuf counted-vmcnt ----
template<int MODE>
__global__ __launch_bounds__(256) void gemm_bf16(
    const unsigned short* __restrict__ A, const unsigned short* __restrict__ WT,
    const float* __restrict__ bias,
    void* __restrict__ o0, void* __restrict__ o1, void* __restrict__ o2,
    int M, int N, int K)
{
    __shared__ unsigned short As[2][128 * 64];
    __shared__ unsigned short Bs[2][128 * 64];
    int bx = blockIdx.x, by = blockIdx.y;
    xcd_swz(bx, by, gridDim.x, gridDim.y);
    const int t = threadIdx.x;
    const int m0 = by * 128, n0 = bx * 128;
    const int w = t >> 6, lane = t & 63;
    const int wm = (w >> 1) * 64, wn = (w & 1) * 64;
    const int lr = lane & 15, lk = (lane >> 4) * 8;
    const int rb = (lane >> 4) * 4;
    const int srow = lane >> 3, scol = (lane & 7) * 8;

    f32x4 zero = {0.f, 0.f, 0.f, 0.f};
    f32x4 acc[4][4];
    #pragma unroll
    for (int i = 0; i < 4; ++i)
        #pragma unroll
        for (int j = 0; j < 4; ++j) acc[i][j] = zero;

    auto stage = [&](int buf, int k0) {
        #pragma unroll
        for (int i = 0; i < 4; ++i) {
            const int seg = w * 4 + i;
            const int r = seg * 8 + srow;
            gl_lds16(A  + (size_t)(m0 + r) * K + k0 + scol, &As[buf][seg * 512 + lane * 8]);
            gl_lds16(WT + (size_t)(n0 + r) * K + k0 + scol, &Bs[buf][seg * 512 + lane * 8]);
        }
    };

    const int nk = K >> 6;
    stage(0, 0);
    for (int ti = 0; ti < nk; ++ti) {
        if (ti + 1 < nk) {
            stage((ti + 1) & 1, (ti + 1) << 6);
            asm volatile("s_waitcnt vmcnt(8)" ::: "memory");
        } else {
            asm volatile("s_waitcnt vmcnt(0)" ::: "memory");
        }
        __builtin_amdgcn_s_barrier();
        const unsigned short* as = As[ti & 1];
        const unsigned short* bs = Bs[ti & 1];
        #pragma unroll
        for (int kk = 0; kk < 2; ++kk) {
            bf16x8 a[4], b[4];
            #pragma unroll
            for (int i = 0; i < 4; ++i)
                a[i] = *reinterpret_cast<const bf16x8*>(&as[(wm + i * 16 + lr) * 64 + kk * 32 + lk]);
            #pragma unroll
            for (int j = 0; j < 4; ++j)
                b[j] = *reinterpret_cast<const bf16x8*>(&bs[(wn + j * 16 + lr) * 64 + kk * 32 + lk]);
            #pragma unroll
            for (int i = 0; i < 4; ++i)
                #pragma unroll
                for (int j = 0; j < 4; ++j)
                    acc[i][j] = MFMA16(a[i], b[j], acc[i][j]);
        }
        __builtin_amdgcn_s_barrier();
    }

    #pragma unroll
    for (int i = 0; i < 4; ++i) {
        #pragma unroll
        for (int j = 0; j < 4; ++j) {
            const int n = n0 + wn + j * 16 + lr;
            const float bv = bias[n];
            #pragma unroll
            for (int r = 0; r < 4; ++r) {
                const int m = m0 + wm + i * 16 + rb + r;
                float val = acc[i][j][r] + bv;
                if (MODE == 0) {
                    const int which = n >> 9, nn = n & 511, hs = nn >> 6, d = nn & 63;
                    const int bh = (m >> 11) * 8 + hs, l = m & 2047;
                    unsigned short* p = (which == 0) ? (unsigned short*)o0
                                      : (which == 1) ? (unsigned short*)o1
                                                     : (unsigned short*)o2;
                    p[((size_t)bh * LSEQ + l) * HD + d] = f2bf(val);
                } else {
                    size_t idx = (size_t)m * N + n;
                    ((unsigned short*)o0)[idx] = f2bf(gelu_f(val));
                }
            }
        }
    }
}

// ---------------- bf16 MFMA GEMM, 64x64 tile, dbuf, for N=512 GEMMs ----
template<int MODE>
__global__ __launch_bounds__(256) void gemm64(
    const unsigned short* __restrict__ A, const unsigned short* __restrict__ WT,
    const float* __restrict__ bias, const void* __restrict__ res,
    void* __restrict__ out, int M, int N, int K)
{
    __shared__ unsigned short As[2][64 * 64];
    __shared__ unsigned short Bs[2][64 * 64];
    int bx = blockIdx.x, by = blockIdx.y;
    xcd_swz(bx, by, gridDim.x, gridDim.y);
    const int t = threadIdx.x;
    const int m0 = by * 64, n0 = bx * 64;
    const int w = t >> 6, lane = t & 63;
    const int wm = (w >> 1) * 32, wn = (w & 1) * 32;
    const int lr = lane & 15, lk = (lane >> 4) * 8;
    const int rb = (lane >> 4) * 4;
    const int srow = t >> 3, scol = (t & 7) * 8;

    f32x4 zero = {0.f, 0.f, 0.f, 0.f};
    f32x4 acc[2][2];
    #pragma unroll
    for (int i = 0; i < 2; ++i)
        #pragma unroll
        for (int j = 0; j < 2; ++j) acc[i][j] = zero;

    auto stage = [&](int buf, int k0) {
        gl_lds16(A  + (size_t)(m0 + srow)      * K + k0 + scol, &As[buf][t * 8]);
        gl_lds16(A  + (size_t)(m0 + 32 + srow) * K + k0 + scol, &As[buf][2048 + t * 8]);
        gl_lds16(WT + (size_t)(n0 + srow)      * K + k0 + scol, &Bs[buf][t * 8]);
        gl_lds16(WT + (size_t)(n0 + 32 + srow) * K + k0 + scol, &Bs[buf][2048 + t * 8]);
    };

    const int nk = K >> 6;
    stage(0, 0);
    for (int ti = 0; ti < nk; ++ti) {
        if (ti + 1 < nk) {
            stage((ti + 1) & 1, (ti + 1) << 6);
            asm volatile("s_waitcnt vmcnt(4)" ::: "memory");
        } else {
            asm volatile("s_waitcnt vmcnt(0)" ::: "memory");
        }
        __builtin_amdgcn_s_barrier();
        const unsigned short* as = As[ti & 1];
        const unsigned short* bs = Bs[ti & 1];
        #pragma unroll
        for (int kk = 0; kk < 2; ++kk) {
            bf16x8 a[2], b[2];
            #pragma unroll
            for (int i = 0; i < 2; ++i)
                a[i] = *reinterpret_cast<const bf16x8*>(&as[(wm + i * 16 + lr) * 64 + kk * 32 + lk]);
            #pragma unroll
            for (int j = 0; j < 2; ++j)
                b[j] = *reinterpret_cast<const bf16x8*>(&bs[(wn + j * 16 + lr) * 64 + kk * 32 + lk]);
            #pragma unroll
            for (int i = 0; i < 2; ++i)
                #pragma unroll
                for (int j = 0; j < 2; ++j)
                    acc[i][j] = MFMA16(a[i], b[j], acc[i][j]);
        }
        __builtin_amdgcn_s_barrier();
    }

    #pragma unroll
    for (int i = 0; i < 2; ++i) {
        #pragma unroll
        for (int j = 0; j < 2; ++j) {
            const int n = n0 + wn + j * 16 + lr;
            const float bv = bias[n];
            #pragma unroll
            for (int r = 0; r < 4; ++r) {
                const int m = m0 + wm + i * 16 + rb + r;
                size_t idx = (size_t)m * N + n;
                float val = acc[i][j][r] + bv;
                if (MODE == 0) {
                    val += ((const float*)res)[idx];
                    ((unsigned short*)out)[idx] = f2bf(val);
                } else {
                    val += bf2f(((const unsigned short*)res)[idx]);
                    ((float*)out)[idx] = val;
                }
            }
        }
    }
}

// ---------------- MFMA flash attention: key-split, 8 waves, 32 rows/wave ----
// grid (LSEQ/128, BHN), block 512. Waves 0-3: keys 0-31 of each tile; 4-7: keys 32-63.
// Explicit LDS partition (single object) so the end reduction stays in-object.
__global__ __launch_bounds__(512) void attn_mfma(
    const unsigned short* __restrict__ Q, const unsigned short* __restrict__ K,
    const unsigned short* __restrict__ VTp, const int* __restrict__ mask,
    unsigned short* __restrict__ out)
{
    __shared__ __align__(16) char smem[54272];
    unsigned short* const KsS = (unsigned short*)smem;            // 2 x 4096 shorts (16KB)
    unsigned short* const VsS = (unsigned short*)(smem + 16384);  // 2 x 4096 shorts (16KB)
    unsigned short* const PsS = (unsigned short*)(smem + 32768);  // 128 x 72 shorts (18KB)
    unsigned short* const kbl = (unsigned short*)(smem + 51200);  // 1536 bf16 (3KB)
    float* const red = (float*)smem;                              // 40KB reduction (overlaps dead K/V/Ps)

    int bx = blockIdx.x, by = blockIdx.y;
    xcd_swz(bx, by, 16, 32);
    const int qt = bx, bh = by;
    const int b = bh >> 3, hh = bh & 7;
    const int t = threadIdx.x, w = t >> 6, lane = t & 63;
    const int lr = lane & 15, hi = lane >> 4;
    const int kh = w >> 2, wr = (w & 3) * 32;   // key-half, row offset
    const int qr0 = qt * 128;
    const int c = qr0 >> 9;
    const int kstart = max(0, (c - 1) * 512), kend = min(LSEQ, (c + 2) * 512);
    const int nk = kend - kstart, nkt = nk >> 6;

    const float C1  = 0.18033688f;   // 0.125 * log2(e)
    const float KB0 = -14.4269504f;  // -MFIX(=10) * log2(e)

    // staging addresses (16B per thread per buffer); source pre-swizzled so
    // linear LDS dest + XOR'd read form a consistent involution
    const int srow = t >> 3, sslot = t & 7;
    const unsigned short* ksrc = K   + ((size_t)bh * LSEQ + kstart + srow) * HD
                                     + ((sslot ^ (srow & 7)) * 8);
    const unsigned short* vsrc = VTp + ((size_t)bh * HD + srow) * LSEQ + kstart
                                     + ((sslot ^ (srow & 7)) * 8);

    // Q fragments from global (L2-resident)
    bf16x8 qf[2][2];
    #pragma unroll
    for (int fr = 0; fr < 2; ++fr)
        #pragma unroll
        for (int kk = 0; kk < 2; ++kk)
            qf[fr][kk] = *reinterpret_cast<const bf16x8*>(
                &Q[((size_t)bh * LSEQ + qr0 + wr + fr * 16 + lr) * HD + kk * 32 + hi * 8]);

    // mask bias preload (bf16; uniform part cancels in normalization)
    for (int i = t; i < nk; i += 512)
        kbl[i] = mask[b * LSEQ + kstart + i] ? f2bf(-1e30f) : f2bf(KB0);

    f32x4 zero = {0.f, 0.f, 0.f, 0.f};
    f32x4 acc[2][4];
    float lsum[2][4];
    #pragma unroll
    for (int fr = 0; fr < 2; ++fr) {
        #pragma unroll
        for (int j = 0; j < 4; ++j) acc[fr][j] = zero;
        #pragma unroll
        for (int r = 0; r < 4; ++r) lsum[fr][r] = 0.f;
    }

    // prologue stage tile 0
    gl_lds16(ksrc, KsS + t * 8);
    gl_lds16(vsrc, VsS + t * 8);
    __syncthreads();   // drains vmcnt + kbl writes (one-time)

    const int kxor = (lr & 7) * 8;
    for (int ti = 0; ti < nkt; ++ti) {
        if (ti + 1 < nkt) {
            const int off = (ti + 1) * 64;
            gl_lds16(ksrc + (size_t)off * HD, KsS + ((ti + 1) & 1) * 4096 + t * 8);
            gl_lds16(vsrc + off,              VsS + ((ti + 1) & 1) * 4096 + t * 8);
            asm volatile("s_waitcnt vmcnt(2)" ::: "memory");
        } else {
            asm volatile("s_waitcnt vmcnt(0)" ::: "memory");
        }
        __builtin_amdgcn_s_barrier();
        const unsigned short* ks = KsS + (ti & 1) * 4096;
        const unsigned short* vs = VsS + (ti & 1) * 4096;
        const int kg0 = ti * 64;

        // S = Q K^T over this wave's 32-key half
        f32x4 s[2][2];
        #pragma unroll
        for (int fr = 0; fr < 2; ++fr)
            #pragma unroll
            for (int j = 0; j < 2; ++j) s[fr][j] = zero;
        #pragma unroll
        for (int kk = 0; kk < 2; ++kk) {
            #pragma unroll
            for (int j = 0; j < 2; ++j) {
                bf16x8 bk = *reinterpret_cast<const bf16x8*>(
                    &ks[(kh * 32 + j * 16 + lr) * 64 + (((kk * 4 + hi) * 8) ^ kxor)]);
                s[0][j] = MFMA16(qf[0][kk], bk, s[0][j]);
                s[1][j] = MFMA16(qf[1][kk], bk, s[1][j]);
            }
        }
        // fixed-max softmax; P packed (key lr, key lr+16) -> uint at [row][kh*32+lr*2]
        const float kb0 = bf2f(kbl[kg0 + kh * 32 + lr]);
        const float kb1 = bf2f(kbl[kg0 + kh * 32 + 16 + lr]);
        #pragma unroll
        for (int fr = 0; fr < 2; ++fr) {
            #pragma unroll
            for (int r = 0; r < 4; ++r) {
                float p0 = __builtin_amdgcn_exp2f(fmaf(s[fr][0][r], C1, kb0));
                float p1 = __builtin_amdgcn_exp2f(fmaf(s[fr][1][r], C1, kb1));
                lsum[fr][r] += p0 + p1;
                const int row = wr + fr * 16 + hi * 4 + r;
                *reinterpret_cast<unsigned int*>(&PsS[row * 72 + kh * 32 + lr * 2]) =
                    cvt_pk_bf16(p0, p1);
            }
        }
        // O += P V over this wave's key half (wave-private P rows+cols)
        #pragma unroll
        for (int fr = 0; fr < 2; ++fr) {
            bf16x8 pa = *reinterpret_cast<const bf16x8*>(
                &PsS[(wr + fr * 16 + lr) * 72 + kh * 32 + hi * 8]);
            #pragma unroll
            for (int j = 0; j < 4; ++j) {
                bf16x8 bv = *reinterpret_cast<const bf16x8*>(
                    &vs[(j * 16 + lr) * 64 + (((kh * 4 + hi) * 8) ^ kxor)]);
                acc[fr][j] = MFMA16(pa, bv, acc[fr][j]);
            }
        }
        __builtin_amdgcn_s_barrier();
    }

    // cross-wave reduction: waves 4-7 hand partial acc+lsum to waves 0-3
    __syncthreads();
    const int rid = (w & 3) * 64 + lane;
    if (w >= 4) {
        #pragma unroll
        for (int fr = 0; fr < 2; ++fr)
            #pragma unroll
            for (int j = 0; j < 4; ++j)
                #pragma unroll
                for (int r = 0; r < 4; ++r)
                    red[((fr * 4 + j) * 4 + r) * 256 + rid] = acc[fr][j][r];
        #pragma unroll
        for (int fr = 0; fr < 2; ++fr)
            #pragma unroll
            for (int r = 0; r < 4; ++r)
                red[(32 + fr * 4 + r) * 256 + rid] = lsum[fr][r];
    }
    __syncthreads();
    if (w < 4) {
        #pragma unroll
        for (int fr = 0; fr < 2; ++fr)
            #pragma unroll
            for (int j = 0; j < 4; ++j)
                #pragma unroll
                for (int r = 0; r < 4; ++r)
                    acc[fr][j][r] += red[((fr * 4 + j) * 4 + r) * 256 + rid];
        #pragma unroll
        for (int fr = 0; fr < 2; ++fr)
            #pragma unroll
            for (int r = 0; r < 4; ++r)
                lsum[fr][r] += red[(32 + fr * 4 + r) * 256 + rid];

        float linv[2][4];
        #pragma unroll
        for (int fr = 0; fr < 2; ++fr)
            #pragma unroll
            for (int r = 0; r < 4; ++r) {
                float v = lsum[fr][r];
                v += __shfl_xor(v, 1, 16);
                v += __shfl_xor(v, 2, 16);
                v += __shfl_xor(v, 4, 16);
                v += __shfl_xor(v, 8, 16);
                linv[fr][r] = 1.0f / v;
            }
        #pragma unroll
        for (int fr = 0; fr < 2; ++fr)
            #pragma unroll
            for (int j = 0; j < 4; ++j)
                #pragma unroll
                for (int r = 0; r < 4; ++r) {
                    const int l = qr0 + wr + fr * 16 + hi * 4 + r;
                    const int d = j * 16 + lr;
                    out[((size_t)(b * LSEQ + l)) * EMBED + hh * HD + d] =
                        f2bf(acc[fr][j][r] * linv[fr][r]);
                }
    }
}

// ---------------- layernorm, one wave per row ----------------
__global__ __launch_bounds__(256) void ln_b2b(
    const unsigned short* __restrict__ in, const float* __restrict__ g,
    const float* __restrict__ bt, unsigned short* __restrict__ out)
{
    const int t = threadIdx.x, lane = t & 63;
    const int row = blockIdx.x * 4 + (t >> 6);
    uint4 raw = *reinterpret_cast<const uint4*>(&in[(size_t)row * EMBED + lane * 8]);
    float v[8];
    const unsigned int* rw = reinterpret_cast<const unsigned int*>(&raw);
    #pragma unroll
    for (int i = 0; i < 4; ++i) {
        v[2 * i]     = __uint_as_float(rw[i] << 16);
        v[2 * i + 1] = __uint_as_float(rw[i] & 0xffff0000u);
    }
    float s = 0.f, ss = 0.f;
    #pragma unroll
    for (int i = 0; i < 8; ++i) { s += v[i]; ss += v[i] * v[i]; }
    #pragma unroll
    for (int off = 1; off < 64; off <<= 1) {
        s  += __shfl_xor(s, off);
        ss += __shfl_xor(ss, off);
    }
    const float mu = s * (1.0f / EMBED);
    const float var = ss * (1.0f / EMBED) - mu * mu;
    const float rs = rsqrtf(var + 1e-5f);
    float4 g0 = *reinterpret_cast<const float4*>(&g[lane * 8]);
    float4 g1 = *reinterpret_cast<const float4*>(&g[lane * 8 + 4]);
    float4 b0 = *reinterpret_cast<const float4*>(&bt[lane * 8]);
    float4 b1 = *reinterpret_cast<const float4*>(&bt[lane * 8 + 4]);
    float gg[8] = {g0.x, g0.y, g0.z, g0.w, g1.x, g1.y, g1.z, g1.w};
    float bb[8] = {b0.x, b0.y, b0.z, b0.w, b1.x, b1.y, b1.z, b1.w};
    unsigned short o[8];
    #pragma unroll
    for (int i = 0; i < 8; ++i) o[i] = f2bf((v[i] - mu) * rs * gg[i] + bb[i]);
    *reinterpret_cast<uint4*>(&out[(size_t)row * EMBED + lane * 8]) =
        *reinterpret_cast<uint4*>(o);
}

__global__ __launch_bounds__(256) void ln_f2f(
    const float* __restrict__ in, const float* __restrict__ g,
    const float* __restrict__ bt, float* __restrict__ out)
{
    const int t = threadIdx.x, lane = t & 63;
    const int row = blockIdx.x * 4 + (t >> 6);
    const float* x = in + (size_t)row * EMBED + lane * 8;
    float4 a = *reinterpret_cast<const float4*>(x);
    float4 b2 = *reinterpret_cast<const float4*>(x + 4);
    float v[8] = {a.x, a.y, a.z, a.w, b2.x, b2.y, b2.z, b2.w};
    float s = 0.f, ss = 0.f;
    #pragma unroll
    for (int i = 0; i < 8; ++i) { s += v[i]; ss += v[i] * v[i]; }
    #pragma unroll
    for (int off = 1; off < 64; off <<= 1) {
        s  += __shfl_xor(s, off);
        ss += __shfl_xor(ss, off);
    }
    const float mu = s * (1.0f / EMBED);
    const float var = ss * (1.0f / EMBED) - mu * mu;
    const float rs = rsqrtf(var + 1e-5f);
    float4 g0 = *reinterpret_cast<const float4*>(&g[lane * 8]);
    float4 g1 = *reinterpret_cast<const float4*>(&g[lane * 8 + 4]);
    float4 b0 = *reinterpret_cast<const float4*>(&bt[lane * 8]);
    float4 b1 = *reinterpret_cast<const float4*>(&bt[lane * 8 + 4]);
    float gg[8] = {g0.x, g0.y, g0.z, g0.w, g1.x, g1.y, g1.z, g1.w};
    float bb[8] = {b0.x, b0.y, b0.z, b0.w, b1.x, b1.y, b1.z, b1.w};
    float o[8];
    #pragma unroll
    for (int i = 0; i < 8; ++i) o[i] = (v[i] - mu) * rs * gg[i] + bb[i];
    float* op = out + (size_t)row * EMBED + lane * 8;
    *reinterpret_cast<float4*>(op)     = make_float4(o[0], o[1], o[2], o[3]);
    *reinterpret_cast<float4*>(op + 4) = make_float4(o[4], o[5], o[6], o[7]);
}

extern "C" void kernel_launch(void* const* d_in, const int* in_sizes, int n_in,
                              void* d_out, int out_size, void* d_ws, size_t ws_size,
                              hipStream_t stream) {
    const float* x      = (const float*)d_in[0];
    const int*   mask   = (const int*)  d_in[1];
    const float* qkv_w  = (const float*)d_in[2];
    const float* qkv_b  = (const float*)d_in[3];
    const float* out_w  = (const float*)d_in[4];
    const float* out_b  = (const float*)d_in[5];
    const float* ffn_w1 = (const float*)d_in[6];
    const float* ffn_b1 = (const float*)d_in[7];
    const float* ffn_w2 = (const float*)d_in[8];
    const float* ffn_b2 = (const float*)d_in[9];
    const float* ln1_g  = (const float*)d_in[10];
    const float* ln1_b  = (const float*)d_in[11];
    const float* ln2_g  = (const float*)d_in[12];
    const float* ln2_b  = (const float*)d_in[13];

    char* wsb = (char*)d_ws;
    unsigned short* qkv_wT = (unsigned short*)(wsb + 0);          // 1.5 MB
    unsigned short* out_wT = (unsigned short*)(wsb + 1572864);    // 0.5 MB
    unsigned short* w1T    = (unsigned short*)(wsb + 2097152);    // 2 MB
    unsigned short* w2T    = (unsigned short*)(wsb + 4194304);    // 2 MB
    unsigned short* xb     = (unsigned short*)(wsb + 6291456);    // A: 8 MB
    unsigned short* qb     = (unsigned short*)(wsb + 14680064);   // B: 8 MB
    unsigned short* kbuf   = (unsigned short*)(wsb + 23068672);   // C: 8 MB
    unsigned short* vb     = (unsigned short*)(wsb + 31457280);   // D: 8 MB
    unsigned short* y      = (unsigned short*)(wsb + 39845888);   // E: 8 MB (bf16)
    unsigned short* vTp    = xb;     // A reused (xb dead after QKV gemm)
    unsigned short* am     = vb;     // D reused (v row-major dead after vtransp)
    unsigned short* xlnb   = xb;     // A reused (vTp dead after attn)
    unsigned short* h      = (unsigned short*)(wsb + 31457280);   // D+E: 32 MB (y dead post-LN1)
    float*          z      = (float*)(wsb + 65011712);            // 16 MB

    // 0) prep: x->bf16 + 4 weight transposes (merged)
    prep<<<5120, 256, 0, stream>>>(x, xb, qkv_w, qkv_wT, out_w, out_wT,
                                   ffn_w1, w1T, ffn_w2, w2T);
    // 1) QKV projection -> q,k,v head-major bf16
    gemm_bf16<0><<<dim3(1536 / 128, MROWS / 128), 256, 0, stream>>>(
        xb, qkv_wT, qkv_b, qb, kbuf, vb, MROWS, 1536, 512);
    // 2) V transpose+pos-permute per head
    vtransp<<<dim3(LSEQ / 64, BHN), 256, 0, stream>>>(vb, vTp);
    // 3) attention -> am (merged bf16)
    attn_mfma<<<dim3(LSEQ / 128, BHN), 512, 0, stream>>>(qb, kbuf, vTp, mask, am);
    // 4) out projection + residual(x fp32) -> y bf16
    gemm64<0><<<dim3(EMBED / 64, MROWS / 64), 256, 0, stream>>>(
        am, out_wT, out_b, x, y, MROWS, EMBED, 512);
    // 5) LN1 -> xlnb bf16
    ln_b2b<<<MROWS / 4, 256, 0, stream>>>(y, ln1_g, ln1_b, xlnb);
    // 6) FFN1 + GELU -> h bf16
    gemm_bf16<2><<<dim3(FFN_ / 128, MROWS / 128), 256, 0, stream>>>(
        xlnb, w1T, ffn_b1, h, nullptr, nullptr, MROWS, FFN_, 512);
    // 7) FFN2 + residual(xlnb bf16) -> z fp32
    gemm64<1><<<dim3(EMBED / 64, MROWS / 64), 256, 0, stream>>>(
        h, w2T, ffn_b2, xlnb, z, MROWS, EMBED, FFN_);
    // 8) LN2 -> out fp32
    ln_f2f<<<MROWS / 4, 256, 0, stream>>>(z, ln2_g, ln2_b, (float*)d_out);
}

// Round 9
// 239.029 us; speedup vs baseline: 6.7708x; 1.0848x over previous
//
#include <hip/hip_runtime.h>
#include <hip/hip_bf16.h>
#include <math.h>

#define EMBED 512
#define HEADS 8
#define HD    64
#define FFN_  2048
#define NB    4
#define LSEQ  2048
#define MROWS (NB*LSEQ)    // 8192
#define BHN   (NB*HEADS)   // 32

typedef __attribute__((ext_vector_type(8))) short bf16x8;
typedef __attribute__((ext_vector_type(4))) float f32x4;
#define MFMA16(a,b,c) __builtin_amdgcn_mfma_f32_16x16x32_bf16(a,b,c,0,0,0)

__device__ __forceinline__ unsigned short f2bf(float f) {
    unsigned int u = __float_as_uint(f);
    u += 0x7fff + ((u >> 16) & 1);          // round-to-nearest-even
    return (unsigned short)(u >> 16);
}
__device__ __forceinline__ float bf2f(unsigned short u) {
    return __uint_as_float(((unsigned int)u) << 16);
}
__device__ __forceinline__ unsigned int cvt_pk_bf16(float lo, float hi) {
    unsigned int r;
    asm("v_cvt_pk_bf16_f32 %0, %1, %2" : "=v"(r) : "v"(lo), "v"(hi));
    return r;
}
__device__ __forceinline__ void gl_lds16(const unsigned short* g, unsigned short* l) {
    __builtin_amdgcn_global_load_lds(
        (const __attribute__((address_space(1))) unsigned int*)g,
        (__attribute__((address_space(3))) unsigned int*)l, 16, 0, 0);
}
// fast tanh-gelu
__device__ __forceinline__ float gelu_f(float x) {
    float u = x * fmaf(x * x, 0.044715f, 1.0f) * 0.7978845608f;
    float a = fminf(fmaxf(u * 2.885390082f, -30.f), 30.f);   // 2*log2e*u
    float t = __builtin_amdgcn_exp2f(a);
    return x * t * __builtin_amdgcn_rcpf(t + 1.0f);
}
// bijective XCD swizzle (nwg % 8 == 0 everywhere here)
__device__ __forceinline__ void xcd_swz(int& bx, int& by, int gx, int gy) {
    int nwg = gx * gy;
    int lid = by * gx + bx;
    int cpx = nwg >> 3;
    int swz = (lid & 7) * cpx + (lid >> 3);
    bx = swz % gx;
    by = swz / gx;
}

// ---------------- merged prep kernel ----------------
__device__ __forceinline__ void wtrans_body(const float* __restrict__ in,
                                            unsigned short* __restrict__ out,
                                            int K, int N, int bx, int by,
                                            float (*tile)[33]) {
    const int k0 = by * 32, n0 = bx * 32;
    const int t = threadIdx.x;
    const int r = t >> 3, c = (t & 7) * 4;
    float4 v = *reinterpret_cast<const float4*>(&in[(size_t)(k0 + r) * N + n0 + c]);
    tile[r][c] = v.x; tile[r][c + 1] = v.y; tile[r][c + 2] = v.z; tile[r][c + 3] = v.w;
    __syncthreads();
    unsigned short tmp[4] = {f2bf(tile[c + 0][r]), f2bf(tile[c + 1][r]),
                             f2bf(tile[c + 2][r]), f2bf(tile[c + 3][r])};
    *reinterpret_cast<uint2*>(&out[(size_t)(n0 + r) * K + k0 + c]) =
        *reinterpret_cast<uint2*>(tmp);
}

__global__ __launch_bounds__(256) void prep(
    const float* __restrict__ x, unsigned short* __restrict__ xb,
    const float* __restrict__ qkv_w, unsigned short* __restrict__ qkv_wT,
    const float* __restrict__ out_w, unsigned short* __restrict__ out_wT,
    const float* __restrict__ w1, unsigned short* __restrict__ w1T,
    const float* __restrict__ w2, unsigned short* __restrict__ w2T)
{
    __shared__ float tile[32][33];
    const int blk = blockIdx.x;
    if (blk < 2048) {
        int i = (blk * 256 + threadIdx.x) * 8;
        float4 a = *reinterpret_cast<const float4*>(&x[i]);
        float4 b = *reinterpret_cast<const float4*>(&x[i + 4]);
        unsigned short t8[8] = {f2bf(a.x), f2bf(a.y), f2bf(a.z), f2bf(a.w),
                                f2bf(b.x), f2bf(b.y), f2bf(b.z), f2bf(b.w)};
        *reinterpret_cast<uint4*>(&xb[i]) = *reinterpret_cast<uint4*>(t8);
    } else if (blk < 2816) {
        int i = blk - 2048; wtrans_body(qkv_w, qkv_wT, 512, 1536, i % 48, i / 48, tile);
    } else if (blk < 3072) {
        int i = blk - 2816; wtrans_body(out_w, out_wT, 512, 512, i % 16, i / 16, tile);
    } else if (blk < 4096) {
        int i = blk - 3072; wtrans_body(w1, w1T, 512, 2048, i % 64, i / 64, tile);
    } else {
        int i = blk - 4096; wtrans_body(w2, w2T, 2048, 512, i % 16, i / 16, tile);
    }
}

// v bf16 [BH][L][HD] -> vTp [BH][HD][L], pos-permuted within each 64-tile for
// the split-softmax P layout: pos' = kh*32+p  ->  src key = kh*32 + (p>>1) + (p&1)*16
__global__ __launch_bounds__(256) void vtransp(const unsigned short* __restrict__ v,
                                               unsigned short* __restrict__ vT) {
    __shared__ unsigned short tile[64][72];
    const int bh = blockIdx.y, l0 = blockIdx.x * 64;
    const int t = threadIdx.x;
    #pragma unroll
    for (int u = 0; u < 2; ++u) {
        int id = t + u * 256; int r = id >> 3, c = (id & 7) * 8;
        *reinterpret_cast<uint4*>(&tile[r][c]) = *reinterpret_cast<const uint4*>(
            &v[((size_t)bh * LSEQ + l0 + r) * HD + c]);
    }
    __syncthreads();
    #pragma unroll
    for (int u = 0; u < 2; ++u) {
        int id = t + u * 256; int d = id >> 3, kc = (id & 7) * 8;
        unsigned short tmp[8];
        #pragma unroll
        for (int jj = 0; jj < 8; ++jj) {
            int posp = kc + jj;
            int kh = posp >> 5, p = posp & 31;
            tmp[jj] = tile[kh * 32 + (p >> 1) + (p & 1) * 16][d];
        }
        *reinterpret_cast<uint4*>(&vT[((size_t)bh * HD + d) * LSEQ + l0 + kc]) =
            *reinterpret_cast<uint4*>(tmp);
    }
}

// ---------------- bf16 MFMA GEMM, 128x128 tile, dbuf + T2 XOR swizzle ----
// LDS layout: linear [128][64] but column-slot XOR'd by (row&7); achieved by
// pre-swizzling the per-lane GLOBAL source column (dest stays linear).
template<int MODE>
__global__ __launch_bounds__(256) void gemm_bf16(
    const unsigned short* __restrict__ A, const unsigned short* __restrict__ WT,
    const float* __restrict__ bias,
    void* __restrict__ o0, void* __restrict__ o1, void* __restrict__ o2,
    int M, int N, int K)
{
    __shared__ unsigned short As[2][128 * 64];
    __shared__ unsigned short Bs[2][128 * 64];
    int bx = blockIdx.x, by = blockIdx.y;
    xcd_swz(bx, by, gridDim.x, gridDim.y);
    const int t = threadIdx.x;
    const int m0 = by * 128, n0 = bx * 128;
    const int w = t >> 6, lane = t & 63;
    const int wm = (w >> 1) * 64, wn = (w & 1) * 64;
    const int lr = lane & 15, lk = (lane >> 4) * 8;
    const int rb = (lane >> 4) * 4;
    const int srow = lane >> 3;
    const int scol = (((lane & 7) ^ (srow & 7)) * 8);   // pre-swizzled source col
    const int rxor = (lr & 7) * 8;                      // read-side XOR

    f32x4 zero = {0.f, 0.f, 0.f, 0.f};
    f32x4 acc[4][4];
    #pragma unroll
    for (int i = 0; i < 4; ++i)
        #pragma unroll
        for (int j = 0; j < 4; ++j) acc[i][j] = zero;

    auto stage = [&](int buf, int k0) {
        #pragma unroll
        for (int i = 0; i < 4; ++i) {
            const int seg = w * 4 + i;
            const int r = seg * 8 + srow;
            gl_lds16(A  + (size_t)(m0 + r) * K + k0 + scol, &As[buf][seg * 512 + lane * 8]);
            gl_lds16(WT + (size_t)(n0 + r) * K + k0 + scol, &Bs[buf][seg * 512 + lane * 8]);
        }
    };

    const int nk = K >> 6;
    stage(0, 0);
    for (int ti = 0; ti < nk; ++ti) {
        if (ti + 1 < nk) {
            stage((ti + 1) & 1, (ti + 1) << 6);
            asm volatile("s_waitcnt vmcnt(8)" ::: "memory");
        } else {
            asm volatile("s_waitcnt vmcnt(0)" ::: "memory");
        }
        __builtin_amdgcn_s_barrier();
        const unsigned short* as = As[ti & 1];
        const unsigned short* bs = Bs[ti & 1];
        #pragma unroll
        for (int kk = 0; kk < 2; ++kk) {
            bf16x8 a[4], b[4];
            #pragma unroll
            for (int i = 0; i < 4; ++i)
                a[i] = *reinterpret_cast<const bf16x8*>(
                    &as[(wm + i * 16 + lr) * 64 + ((kk * 32 + lk) ^ rxor)]);
            #pragma unroll
            for (int j = 0; j < 4; ++j)
                b[j] = *reinterpret_cast<const bf16x8*>(
                    &bs[(wn + j * 16 + lr) * 64 + ((kk * 32 + lk) ^ rxor)]);
            #pragma unroll
            for (int i = 0; i < 4; ++i)
                #pragma unroll
                for (int j = 0; j < 4; ++j)
                    acc[i][j] = MFMA16(a[i], b[j], acc[i][j]);
        }
        __builtin_amdgcn_s_barrier();
    }

    #pragma unroll
    for (int i = 0; i < 4; ++i) {
        #pragma unroll
        for (int j = 0; j < 4; ++j) {
            const int n = n0 + wn + j * 16 + lr;
            const float bv = bias[n];
            #pragma unroll
            for (int r = 0; r < 4; ++r) {
                const int m = m0 + wm + i * 16 + rb + r;
                float val = acc[i][j][r] + bv;
                if (MODE == 0) {
                    const int which = n >> 9, nn = n & 511, hs = nn >> 6, d = nn & 63;
                    const int bh = (m >> 11) * 8 + hs, l = m & 2047;
                    unsigned short* p = (which == 0) ? (unsigned short*)o0
                                      : (which == 1) ? (unsigned short*)o1
                                                     : (unsigned short*)o2;
                    p[((size_t)bh * LSEQ + l) * HD + d] = f2bf(val);
                } else {
                    size_t idx = (size_t)m * N + n;
                    ((unsigned short*)o0)[idx] = f2bf(gelu_f(val));
                }
            }
        }
    }
}

// ---------------- bf16 MFMA GEMM, 64x64 tile, dbuf + T2 swizzle, N=512 GEMMs ----
// res is bf16. MODE 0: out bf16 (out-proj + residual). MODE 1: out fp32 (FFN2).
template<int MODE>
__global__ __launch_bounds__(256) void gemm64(
    const unsigned short* __restrict__ A, const unsigned short* __restrict__ WT,
    const float* __restrict__ bias, const unsigned short* __restrict__ res,
    void* __restrict__ out, int M, int N, int K)
{
    __shared__ unsigned short As[2][64 * 64];
    __shared__ unsigned short Bs[2][64 * 64];
    int bx = blockIdx.x, by = blockIdx.y;
    xcd_swz(bx, by, gridDim.x, gridDim.y);
    const int t = threadIdx.x;
    const int m0 = by * 64, n0 = bx * 64;
    const int w = t >> 6, lane = t & 63;
    const int wm = (w >> 1) * 32, wn = (w & 1) * 32;
    const int lr = lane & 15, lk = (lane >> 4) * 8;
    const int rb = (lane >> 4) * 4;
    const int srow = t >> 3;
    const int scol = (((t & 7) ^ (srow & 7)) * 8);   // pre-swizzled source col
    const int rxor = (lr & 7) * 8;

    f32x4 zero = {0.f, 0.f, 0.f, 0.f};
    f32x4 acc[2][2];
    #pragma unroll
    for (int i = 0; i < 2; ++i)
        #pragma unroll
        for (int j = 0; j < 2; ++j) acc[i][j] = zero;

    auto stage = [&](int buf, int k0) {
        gl_lds16(A  + (size_t)(m0 + srow)      * K + k0 + scol, &As[buf][t * 8]);
        gl_lds16(A  + (size_t)(m0 + 32 + srow) * K + k0 + scol, &As[buf][2048 + t * 8]);
        gl_lds16(WT + (size_t)(n0 + srow)      * K + k0 + scol, &Bs[buf][t * 8]);
        gl_lds16(WT + (size_t)(n0 + 32 + srow) * K + k0 + scol, &Bs[buf][2048 + t * 8]);
    };

    const int nk = K >> 6;
    stage(0, 0);
    for (int ti = 0; ti < nk; ++ti) {
        if (ti + 1 < nk) {
            stage((ti + 1) & 1, (ti + 1) << 6);
            asm volatile("s_waitcnt vmcnt(4)" ::: "memory");
        } else {
            asm volatile("s_waitcnt vmcnt(0)" ::: "memory");
        }
        __builtin_amdgcn_s_barrier();
        const unsigned short* as = As[ti & 1];
        const unsigned short* bs = Bs[ti & 1];
        #pragma unroll
        for (int kk = 0; kk < 2; ++kk) {
            bf16x8 a[2], b[2];
            #pragma unroll
            for (int i = 0; i < 2; ++i)
                a[i] = *reinterpret_cast<const bf16x8*>(
                    &as[(wm + i * 16 + lr) * 64 + ((kk * 32 + lk) ^ rxor)]);
            #pragma unroll
            for (int j = 0; j < 2; ++j)
                b[j] = *reinterpret_cast<const bf16x8*>(
                    &bs[(wn + j * 16 + lr) * 64 + ((kk * 32 + lk) ^ rxor)]);
            #pragma unroll
            for (int i = 0; i < 2; ++i)
                #pragma unroll
                for (int j = 0; j < 2; ++j)
                    acc[i][j] = MFMA16(a[i], b[j], acc[i][j]);
        }
        __builtin_amdgcn_s_barrier();
    }

    #pragma unroll
    for (int i = 0; i < 2; ++i) {
        #pragma unroll
        for (int j = 0; j < 2; ++j) {
            const int n = n0 + wn + j * 16 + lr;
            const float bv = bias[n];
            #pragma unroll
            for (int r = 0; r < 4; ++r) {
                const int m = m0 + wm + i * 16 + rb + r;
                size_t idx = (size_t)m * N + n;
                float val = acc[i][j][r] + bv + bf2f(res[idx]);
                if (MODE == 0) ((unsigned short*)out)[idx] = f2bf(val);
                else           ((float*)out)[idx] = val;
            }
        }
    }
}

// ---------------- MFMA flash attention: key-split, 8 waves, 32 rows/wave ----
// grid (LSEQ/128, BHN), block 512. Waves 0-3: keys 0-31 of each tile; 4-7: keys 32-63.
__global__ __launch_bounds__(512) void attn_mfma(
    const unsigned short* __restrict__ Q, const unsigned short* __restrict__ K,
    const unsigned short* __restrict__ VTp, const int* __restrict__ mask,
    unsigned short* __restrict__ out)
{
    __shared__ __align__(16) char smem[54272];
    unsigned short* const KsS = (unsigned short*)smem;            // 2 x 4096 shorts (16KB)
    unsigned short* const VsS = (unsigned short*)(smem + 16384);  // 2 x 4096 shorts (16KB)
    unsigned short* const PsS = (unsigned short*)(smem + 32768);  // 128 x 72 shorts (18KB)
    unsigned short* const kbl = (unsigned short*)(smem + 51200);  // 1536 bf16 (3KB)
    float* const red = (float*)smem;                              // 40KB reduction (overlaps dead K/V/Ps)

    int bx = blockIdx.x, by = blockIdx.y;
    xcd_swz(bx, by, 16, 32);
    const int qt = bx, bh = by;
    const int b = bh >> 3, hh = bh & 7;
    const int t = threadIdx.x, w = t >> 6, lane = t & 63;
    const int lr = lane & 15, hi = lane >> 4;
    const int kh = w >> 2, wr = (w & 3) * 32;   // key-half, row offset
    const int qr0 = qt * 128;
    const int c = qr0 >> 9;
    const int kstart = max(0, (c - 1) * 512), kend = min(LSEQ, (c + 2) * 512);
    const int nk = kend - kstart, nkt = nk >> 6;

    const float C1  = 0.18033688f;   // 0.125 * log2(e)
    const float KB0 = -14.4269504f;  // -MFIX(=10) * log2(e)

    const int srow = t >> 3, sslot = t & 7;
    const unsigned short* ksrc = K   + ((size_t)bh * LSEQ + kstart + srow) * HD
                                     + ((sslot ^ (srow & 7)) * 8);
    const unsigned short* vsrc = VTp + ((size_t)bh * HD + srow) * LSEQ + kstart
                                     + ((sslot ^ (srow & 7)) * 8);

    bf16x8 qf[2][2];
    #pragma unroll
    for (int fr = 0; fr < 2; ++fr)
        #pragma unroll
        for (int kk = 0; kk < 2; ++kk)
            qf[fr][kk] = *reinterpret_cast<const bf16x8*>(
                &Q[((size_t)bh * LSEQ + qr0 + wr + fr * 16 + lr) * HD + kk * 32 + hi * 8]);

    for (int i = t; i < nk; i += 512)
        kbl[i] = mask[b * LSEQ + kstart + i] ? f2bf(-1e30f) : f2bf(KB0);

    f32x4 zero = {0.f, 0.f, 0.f, 0.f};
    f32x4 acc[2][4];
    float lsum[2][4];
    #pragma unroll
    for (int fr = 0; fr < 2; ++fr) {
        #pragma unroll
        for (int j = 0; j < 4; ++j) acc[fr][j] = zero;
        #pragma unroll
        for (int r = 0; r < 4; ++r) lsum[fr][r] = 0.f;
    }

    gl_lds16(ksrc, KsS + t * 8);
    gl_lds16(vsrc, VsS + t * 8);
    __syncthreads();

    const int kxor = (lr & 7) * 8;
    for (int ti = 0; ti < nkt; ++ti) {
        if (ti + 1 < nkt) {
            const int off = (ti + 1) * 64;
            gl_lds16(ksrc + (size_t)off * HD, KsS + ((ti + 1) & 1) * 4096 + t * 8);
            gl_lds16(vsrc + off,              VsS + ((ti + 1) & 1) * 4096 + t * 8);
            asm volatile("s_waitcnt vmcnt(2)" ::: "memory");
        } else {
            asm volatile("s_waitcnt vmcnt(0)" ::: "memory");
        }
        __builtin_amdgcn_s_barrier();
        const unsigned short* ks = KsS + (ti & 1) * 4096;
        const unsigned short* vs = VsS + (ti & 1) * 4096;
        const int kg0 = ti * 64;

        f32x4 s[2][2];
        #pragma unroll
        for (int fr = 0; fr < 2; ++fr)
            #pragma unroll
            for (int j = 0; j < 2; ++j) s[fr][j] = zero;
        #pragma unroll
        for (int kk = 0; kk < 2; ++kk) {
            #pragma unroll
            for (int j = 0; j < 2; ++j) {
                bf16x8 bk = *reinterpret_cast<const bf16x8*>(
                    &ks[(kh * 32 + j * 16 + lr) * 64 + (((kk * 4 + hi) * 8) ^ kxor)]);
                s[0][j] = MFMA16(qf[0][kk], bk, s[0][j]);
                s[1][j] = MFMA16(qf[1][kk], bk, s[1][j]);
            }
        }
        const float kb0 = bf2f(kbl[kg0 + kh * 32 + lr]);
        const float kb1 = bf2f(kbl[kg0 + kh * 32 + 16 + lr]);
        #pragma unroll
        for (int fr = 0; fr < 2; ++fr) {
            #pragma unroll
            for (int r = 0; r < 4; ++r) {
                float p0 = __builtin_amdgcn_exp2f(fmaf(s[fr][0][r], C1, kb0));
                float p1 = __builtin_amdgcn_exp2f(fmaf(s[fr][1][r], C1, kb1));
                lsum[fr][r] += p0 + p1;
                const int row = wr + fr * 16 + hi * 4 + r;
                *reinterpret_cast<unsigned int*>(&PsS[row * 72 + kh * 32 + lr * 2]) =
                    cvt_pk_bf16(p0, p1);
            }
        }
        #pragma unroll
        for (int fr = 0; fr < 2; ++fr) {
            bf16x8 pa = *reinterpret_cast<const bf16x8*>(
                &PsS[(wr + fr * 16 + lr) * 72 + kh * 32 + hi * 8]);
            #pragma unroll
            for (int j = 0; j < 4; ++j) {
                bf16x8 bv = *reinterpret_cast<const bf16x8*>(
                    &vs[(j * 16 + lr) * 64 + (((kh * 4 + hi) * 8) ^ kxor)]);
                acc[fr][j] = MFMA16(pa, bv, acc[fr][j]);
            }
        }
        __builtin_amdgcn_s_barrier();
    }

    __syncthreads();
    const int rid = (w & 3) * 64 + lane;
    if (w >= 4) {
        #pragma unroll
        for (int fr = 0; fr < 2; ++fr)
            #pragma unroll
            for (int j = 0; j < 4; ++j)
                #pragma unroll
                for (int r = 0; r < 4; ++r)
                    red[((fr * 4 + j) * 4 + r) * 256 + rid] = acc[fr][j][r];
        #pragma unroll
        for (int fr = 0; fr < 2; ++fr)
            #pragma unroll
            for (int r = 0; r < 4; ++r)
                red[(32 + fr * 4 + r) * 256 + rid] = lsum[fr][r];
    }
    __syncthreads();
    if (w < 4) {
        #pragma unroll
        for (int fr = 0; fr < 2; ++fr)
            #pragma unroll
            for (int j = 0; j < 4; ++j)
                #pragma unroll
                for (int r = 0; r < 4; ++r)
                    acc[fr][j][r] += red[((fr * 4 + j) * 4 + r) * 256 + rid];
        #pragma unroll
        for (int fr = 0; fr < 2; ++fr)
            #pragma unroll
            for (int r = 0; r < 4; ++r)
                lsum[fr][r] += red[(32 + fr * 4 + r) * 256 + rid];

        float linv[2][4];
        #pragma unroll
        for (int fr = 0; fr < 2; ++fr)
            #pragma unroll
            for (int r = 0; r < 4; ++r) {
                float v = lsum[fr][r];
                v += __shfl_xor(v, 1, 16);
                v += __shfl_xor(v, 2, 16);
                v += __shfl_xor(v, 4, 16);
                v += __shfl_xor(v, 8, 16);
                linv[fr][r] = 1.0f / v;
            }
        #pragma unroll
        for (int fr = 0; fr < 2; ++fr)
            #pragma unroll
            for (int j = 0; j < 4; ++j)
                #pragma unroll
                for (int r = 0; r < 4; ++r) {
                    const int l = qr0 + wr + fr * 16 + hi * 4 + r;
                    const int d = j * 16 + lr;
                    out[((size_t)(b * LSEQ + l)) * EMBED + hh * HD + d] =
                        f2bf(acc[fr][j][r] * linv[fr][r]);
                }
    }
}

// ---------------- layernorm, one wave per row ----------------
__global__ __launch_bounds__(256) void ln_b2b(
    const unsigned short* __restrict__ in, const float* __restrict__ g,
    const float* __restrict__ bt, unsigned short* __restrict__ out)
{
    const int t = threadIdx.x, lane = t & 63;
    const int row = blockIdx.x * 4 + (t >> 6);
    uint4 raw = *reinterpret_cast<const uint4*>(&in[(size_t)row * EMBED + lane * 8]);
    float v[8];
    const unsigned int* rw = reinterpret_cast<const unsigned int*>(&raw);
    #pragma unroll
    for (int i = 0; i < 4; ++i) {
        v[2 * i]     = __uint_as_float(rw[i] << 16);
        v[2 * i + 1] = __uint_as_float(rw[i] & 0xffff0000u);
    }
    float s = 0.f, ss = 0.f;
    #pragma unroll
    for (int i = 0; i < 8; ++i) { s += v[i]; ss += v[i] * v[i]; }
    #pragma unroll
    for (int off = 1; off < 64; off <<= 1) {
        s  += __shfl_xor(s, off);
        ss += __shfl_xor(ss, off);
    }
    const float mu = s * (1.0f / EMBED);
    const float var = ss * (1.0f / EMBED) - mu * mu;
    const float rs = rsqrtf(var + 1e-5f);
    float4 g0 = *reinterpret_cast<const float4*>(&g[lane * 8]);
    float4 g1 = *reinterpret_cast<const float4*>(&g[lane * 8 + 4]);
    float4 b0 = *reinterpret_cast<const float4*>(&bt[lane * 8]);
    float4 b1 = *reinterpret_cast<const float4*>(&bt[lane * 8 + 4]);
    float gg[8] = {g0.x, g0.y, g0.z, g0.w, g1.x, g1.y, g1.z, g1.w};
    float bb[8] = {b0.x, b0.y, b0.z, b0.w, b1.x, b1.y, b1.z, b1.w};
    unsigned short o[8];
    #pragma unroll
    for (int i = 0; i < 8; ++i) o[i] = f2bf((v[i] - mu) * rs * gg[i] + bb[i]);
    *reinterpret_cast<uint4*>(&out[(size_t)row * EMBED + lane * 8]) =
        *reinterpret_cast<uint4*>(o);
}

__global__ __launch_bounds__(256) void ln_f2f(
    const float* __restrict__ in, const float* __restrict__ g,
    const float* __restrict__ bt, float* __restrict__ out)
{
    const int t = threadIdx.x, lane = t & 63;
    const int row = blockIdx.x * 4 + (t >> 6);
    const float* x = in + (size_t)row * EMBED + lane * 8;
    float4 a = *reinterpret_cast<const float4*>(x);
    float4 b2 = *reinterpret_cast<const float4*>(x + 4);
    float v[8] = {a.x, a.y, a.z, a.w, b2.x, b2.y, b2.z, b2.w};
    float s = 0.f, ss = 0.f;
    #pragma unroll
    for (int i = 0; i < 8; ++i) { s += v[i]; ss += v[i] * v[i]; }
    #pragma unroll
    for (int off = 1; off < 64; off <<= 1) {
        s  += __shfl_xor(s, off);
        ss += __shfl_xor(ss, off);
    }
    const float mu = s * (1.0f / EMBED);
    const float var = ss * (1.0f / EMBED) - mu * mu;
    const float rs = rsqrtf(var + 1e-5f);
    float4 g0 = *reinterpret_cast<const float4*>(&g[lane * 8]);
    float4 g1 = *reinterpret_cast<const float4*>(&g[lane * 8 + 4]);
    float4 b0 = *reinterpret_cast<const float4*>(&bt[lane * 8]);
    float4 b1 = *reinterpret_cast<const float4*>(&bt[lane * 8 + 4]);
    float gg[8] = {g0.x, g0.y, g0.z, g0.w, g1.x, g1.y, g1.z, g1.w};
    float bb[8] = {b0.x, b0.y, b0.z, b0.w, b1.x, b1.y, b1.z, b1.w};
    float o[8];
    #pragma unroll
    for (int i = 0; i < 8; ++i) o[i] = (v[i] - mu) * rs * gg[i] + bb[i];
    float* op = out + (size_t)row * EMBED + lane * 8;
    *reinterpret_cast<float4*>(op)     = make_float4(o[0], o[1], o[2], o[3]);
    *reinterpret_cast<float4*>(op + 4) = make_float4(o[4], o[5], o[6], o[7]);
}

extern "C" void kernel_launch(void* const* d_in, const int* in_sizes, int n_in,
                              void* d_out, int out_size, void* d_ws, size_t ws_size,
                              hipStream_t stream) {
    const float* x      = (const float*)d_in[0];
    const int*   mask   = (const int*)  d_in[1];
    const float* qkv_w  = (const float*)d_in[2];
    const float* qkv_b  = (const float*)d_in[3];
    const float* out_w  = (const float*)d_in[4];
    const float* out_b  = (const float*)d_in[5];
    const float* ffn_w1 = (const float*)d_in[6];
    const float* ffn_b1 = (const float*)d_in[7];
    const float* ffn_w2 = (const float*)d_in[8];
    const float* ffn_b2 = (const float*)d_in[9];
    const float* ln1_g  = (const float*)d_in[10];
    const float* ln1_b  = (const float*)d_in[11];
    const float* ln2_g  = (const float*)d_in[12];
    const float* ln2_b  = (const float*)d_in[13];

    char* wsb = (char*)d_ws;
    unsigned short* qkv_wT = (unsigned short*)(wsb + 0);          // 1.5 MB
    unsigned short* out_wT = (unsigned short*)(wsb + 1572864);    // 0.5 MB
    unsigned short* w1T    = (unsigned short*)(wsb + 2097152);    // 2 MB
    unsigned short* w2T    = (unsigned short*)(wsb + 4194304);    // 2 MB
    unsigned short* xb     = (unsigned short*)(wsb + 6291456);    // A: 8 MB
    unsigned short* qb     = (unsigned short*)(wsb + 14680064);   // B: 8 MB
    unsigned short* kbuf   = (unsigned short*)(wsb + 23068672);   // C: 8 MB
    unsigned short* vb     = (unsigned short*)(wsb + 31457280);   // D: 8 MB
    unsigned short* y      = (unsigned short*)(wsb + 39845888);   // E: 8 MB (bf16)
    unsigned short* vTp    = xb;     // A reused during attn phase only... see note
    unsigned short* am     = vb;     // D reused (v row-major dead after vtransp)
    unsigned short* h      = (unsigned short*)(wsb + 47185920);   // F: 32 MB
    float*          z      = (float*)(wsb + 80740352);            // 16 MB
    // NOTE: xb must stay alive through out-proj (residual) -> vTp gets its own slot
    unsigned short* vTp2   = (unsigned short*)(wsb + 97058816);   // G: 8 MB
    unsigned short* xlnb   = vTp2;   // reuse G after attn (vTp dead post-attn)... but
    // keep it simple & safe: xlnb shares G only after attn completes (stream order).

    // 0) prep: x->bf16 + 4 weight transposes (merged)
    prep<<<5120, 256, 0, stream>>>(x, xb, qkv_w, qkv_wT, out_w, out_wT,
                                   ffn_w1, w1T, ffn_w2, w2T);
    // 1) QKV projection -> q,k,v head-major bf16
    gemm_bf16<0><<<dim3(1536 / 128, MROWS / 128), 256, 0, stream>>>(
        xb, qkv_wT, qkv_b, qb, kbuf, vb, MROWS, 1536, 512);
    // 2) V transpose+pos-permute per head
    vtransp<<<dim3(LSEQ / 64, BHN), 256, 0, stream>>>(vb, vTp2);
    // 3) attention -> am (merged bf16)
    attn_mfma<<<dim3(LSEQ / 128, BHN), 512, 0, stream>>>(qb, kbuf, vTp2, mask, am);
    // 4) out projection + residual(xb bf16) -> y bf16
    gemm64<0><<<dim3(EMBED / 64, MROWS / 64), 256, 0, stream>>>(
        am, out_wT, out_b, xb, y, MROWS, EMBED, 512);
    // 5) LN1 -> xlnb bf16
    ln_b2b<<<MROWS / 4, 256, 0, stream>>>(y, ln1_g, ln1_b, xlnb);
    // 6) FFN1 + GELU -> h bf16
    gemm_bf16<2><<<dim3(FFN_ / 128, MROWS / 128), 256, 0, stream>>>(
        xlnb, w1T, ffn_b1, h, nullptr, nullptr, MROWS, FFN_, 512);
    // 7) FFN2 + residual(xlnb bf16) -> z fp32
    gemm64<1><<<dim3(EMBED / 64, MROWS / 64), 256, 0, stream>>>(
        h, w2T, ffn_b2, xlnb, z, MROWS, EMBED, FFN_);
    // 8) LN2 -> out fp32
    ln_f2f<<<MROWS / 4, 256, 0, stream>>>(z, ln2_g, ln2_b, (float*)d_out);
}